// Round 4
// baseline (5480.097 us; speedup 1.0000x reference)
//
#include <hip/hip_runtime.h>
#include <cmath>

#define NU 100000
#define NI 50000
#define NALL 150000
#define DIM 64
#define NE 4800000

#define BSH 7                 // bucket = row >> 7  (128 rows/bucket)
#define BROWS 128
#define NBUCK ((NALL + BROWS - 1) / BROWS)   // 1172
#define NCB 1172              // column bins (col >> 7)
#define EPT 16
#define CHUNK (256 * EPT)     // 4096 edges per binning block
#define COLMASK 0x3FFFF       // 18 bits, NALL < 2^18

// ---------------- edge sort: row-bucket grouping, column-sorted inside ----------------

__global__ void bucket_hist_kernel(const int* __restrict__ rows, int* __restrict__ bcnt) {
    __shared__ int h[NBUCK];
    for (int i = threadIdx.x; i < NBUCK; i += 256) h[i] = 0;
    __syncthreads();
    int base = blockIdx.x * CHUNK;
    #pragma unroll
    for (int i = 0; i < EPT; i++) {
        int e = base + threadIdx.x + i * 256;
        if (e < NE) atomicAdd(&h[rows[e] >> BSH], 1);
    }
    __syncthreads();
    for (int i = threadIdx.x; i < NBUCK; i += 256)
        if (h[i]) atomicAdd(&bcnt[i], h[i]);
}

__global__ void bucket_scan_kernel(const int* __restrict__ bcnt, int* __restrict__ bptr) {
    __shared__ int s[1024];
    int t = threadIdx.x;
    const int chunk = (NBUCK + 1023) / 1024;   // 2
    int lo = t * chunk, hi = lo + chunk;
    if (hi > NBUCK) hi = NBUCK;
    int sum = 0;
    for (int i = lo; i < hi; ++i) sum += bcnt[i];
    s[t] = sum;
    __syncthreads();
    for (int off = 1; off < 1024; off <<= 1) {
        int v = (t >= off) ? s[t - off] : 0;
        __syncthreads();
        s[t] += v;
        __syncthreads();
    }
    int run = s[t] - sum;
    for (int i = lo; i < hi; ++i) { bptr[i] = run; run += bcnt[i]; }
    if (t == 1023) bptr[NBUCK] = s[1023];
}

// Coarse scatter: group edges by row-bucket in LDS, append grouped runs to bucket regions.
__global__ void binned_scatter_kernel(const int* __restrict__ rows, const int* __restrict__ cols,
                                      const float* __restrict__ vals, const int* __restrict__ bptr,
                                      int* __restrict__ bfill, int2* __restrict__ tmp) {
    __shared__ int lcnt[NBUCK];
    __shared__ int lbase[NBUCK];
    for (int i = threadIdx.x; i < NBUCK; i += 256) lcnt[i] = 0;
    __syncthreads();
    int base = blockIdx.x * CHUNK;
    int bk[EPT], rk[EPT];
    #pragma unroll
    for (int i = 0; i < EPT; i++) {
        int e = base + threadIdx.x + i * 256;
        if (e < NE) {
            bk[i] = rows[e] >> BSH;
            rk[i] = atomicAdd(&lcnt[bk[i]], 1);
        } else bk[i] = -1;
    }
    __syncthreads();
    for (int i = threadIdx.x; i < NBUCK; i += 256) {
        int c = lcnt[i];
        lbase[i] = c ? atomicAdd(&bfill[i], c) : 0;
    }
    __syncthreads();
    #pragma unroll
    for (int i = 0; i < EPT; i++) {
        int e = base + threadIdx.x + i * 256;
        if (e < NE) {
            int r = rows[e];
            int key = ((r & (BROWS - 1)) << 18) | cols[e];
            tmp[bptr[bk[i]] + lbase[bk[i]] + rk[i]] = make_int2(key, __float_as_int(vals[e]));
        }
    }
}

// Within-bucket counting sort by column bin (col>>7): gives streaming gather order.
__global__ void bucket_colsort_kernel(const int* __restrict__ bptr, const int2* __restrict__ tmp,
                                      int2* __restrict__ sedges) {
    __shared__ int h[NCB], base[NCB], f[NCB];
    __shared__ int psum[256];
    int b = blockIdx.x, t = threadIdx.x;
    int s0 = bptr[b], s1 = bptr[b + 1];
    for (int i = t; i < NCB; i += 256) { h[i] = 0; f[i] = 0; }
    __syncthreads();
    for (int i = s0 + t; i < s1; i += 256) atomicAdd(&h[(tmp[i].x & COLMASK) >> 7], 1);
    __syncthreads();
    const int chunk = (NCB + 255) / 256;   // 5
    int lo = t * chunk, hi = lo + chunk;
    if (hi > NCB) hi = NCB;
    int s = 0;
    for (int i = lo; i < hi; ++i) s += h[i];
    psum[t] = s;
    __syncthreads();
    for (int off = 1; off < 256; off <<= 1) {
        int v = (t >= off) ? psum[t - off] : 0;
        __syncthreads();
        psum[t] += v;
        __syncthreads();
    }
    int run = psum[t] - s;
    for (int i = lo; i < hi; ++i) { base[i] = run; run += h[i]; }
    __syncthreads();
    for (int i = s0 + t; i < s1; i += 256) {
        int2 ed = tmp[i];
        int bin = (ed.x & COLMASK) >> 7;
        int p = atomicAdd(&f[bin], 1);
        sedges[s0 + base[bin] + p] = ed;
    }
}

// ---------------- embedding passes ----------------

__global__ void concat_init_kernel(const float* __restrict__ u, const float* __restrict__ it,
                                   float* __restrict__ w0, float* __restrict__ out) {
    int idx = blockIdx.x * blockDim.x + threadIdx.x;
    const int total = NALL * DIM;
    if (idx >= total) return;
    const int nue = NU * DIM;
    float v = (idx < nue) ? u[idx] : it[idx - nue];
    w0[idx] = v;
    int row = idx >> 6, d = idx & 63;
    out[(size_t)row * 128 + d] = v;   // running band-stop sum := e0
}

// One block per 128-row bucket: LDS y-tile, column-streamed gather, ds_add accumulate,
// fused Jacobi combine + band-stop sum in the epilogue. All 1172 blocks co-resident
// (32KB LDS, 5/CU) => GPU-wide gathers sweep a narrow column window that fits L2.
__global__ __launch_bounds__(256) void spmm_lds_combine_kernel(
        const int* __restrict__ bptr, const int2* __restrict__ sedges,
        const float* __restrict__ x,
        const float* __restrict__ ekm1, const float* __restrict__ ekm2,
        float t1, float t2, float t3,
        float* __restrict__ ek_out, float* __restrict__ out) {
    __shared__ float y[BROWS][DIM];   // 32 KB
    int b = blockIdx.x, t = threadIdx.x;
    int lane = t & 63, w = t >> 6;
    for (int i = t; i < BROWS * DIM; i += 256) ((float*)y)[i] = 0.f;
    __syncthreads();
    int s0 = bptr[b], s1 = bptr[b + 1];
    #pragma unroll 4
    for (int i = s0 + w; i < s1; i += 4) {         // 4 waves interleave -> order preserved
        int2 ed = sedges[i];
        int col = ed.x & COLMASK;
        int lr  = ed.x >> 18;
        float xv = x[(size_t)col * DIM + lane];
        atomicAdd(&y[lr][lane], __int_as_float(ed.y) * xv);
    }
    __syncthreads();
    int r0 = b * BROWS;
    for (int i = t; i < BROWS * DIM; i += 256) {
        int lr = i >> 6, d = i & 63;
        int row = r0 + lr;
        if (row >= NALL) break;
        size_t o = (size_t)row * DIM + d;
        float ek = t1 * y[lr][d] + t2 * ekm1[o] - t3 * ekm2[o];
        ek_out[o] = ek;
        out[(size_t)row * 128 + d] += ek;
    }
}

__global__ void finalize_kernel(const float* __restrict__ u, const float* __restrict__ it,
                                float* __restrict__ out) {
    int idx = blockIdx.x * blockDim.x + threadIdx.x;
    const int total = NALL * DIM;
    if (idx >= total) return;
    const int nue = NU * DIM;
    float v = (idx < nue) ? u[idx] : it[idx - nue];
    int row = idx >> 6, d = idx & 63;
    size_t o = (size_t)row * 128 + d;
    float bs = out[o] * 0.25f;
    float bp = tanhf(0.1f * v - bs);
    out[o] = bs;
    out[o + DIM] = bp;
}

// ---------------- fallback (atomic scatter) ----------------

__global__ void spmm_atomic_kernel(const int* __restrict__ rows, const int* __restrict__ cols,
                                   const float* __restrict__ vals, const float* __restrict__ x,
                                   float* __restrict__ y) {
    int gid = blockIdx.x * blockDim.x + threadIdx.x;
    int e = gid >> 6;
    if (e >= NE) return;
    int lane = threadIdx.x & 63;
    atomicAdd(&y[(size_t)rows[e] * DIM + lane], vals[e] * x[(size_t)cols[e] * DIM + lane]);
}

__global__ void combine3_kernel(float* __restrict__ t, const float* __restrict__ ekm1,
                                const float* __restrict__ ekm2, float t1, float t2, float t3,
                                float* __restrict__ out) {
    int idx = blockIdx.x * blockDim.x + threadIdx.x;
    const int total = NALL * DIM;
    if (idx >= total) return;
    float ek = t1 * t[idx] + t2 * ekm1[idx] - t3 * ekm2[idx];
    t[idx] = ek;
    int row = idx >> 6, d = idx & 63;
    out[(size_t)row * 128 + d] += ek;
}

// ---------------- launch ----------------

extern "C" void kernel_launch(void* const* d_in, const int* in_sizes, int n_in,
                              void* d_out, int out_size, void* d_ws, size_t ws_size,
                              hipStream_t stream) {
    const float* user_emb = (const float*)d_in[0];
    const float* item_emb = (const float*)d_in[1];
    const int*   rows     = (const int*)d_in[2];
    const int*   cols     = (const int*)d_in[3];
    const float* vals     = (const float*)d_in[4];
    float* out = (float*)d_out;

    const size_t nbuf = (size_t)NALL * DIM;            // 9.6M floats = 38.4 MB
    float* W0 = (float*)d_ws;
    float* W1 = W0 + nbuf;
    float* W2 = W1 + nbuf;
    int2*  tmp     = (int2*)W1;                        // alias: dead before propagation
    int2*  sedges  = (int2*)(W2 + nbuf);               // NE * 8 B
    int*   bcnt    = (int*)(sedges + NE);              // NBUCK
    int*   bptr    = bcnt + NBUCK;                     // NBUCK+1
    int*   bfill   = bptr + (NBUCK + 1);               // NBUCK
    size_t need = (size_t)((char*)(bfill + NBUCK) - (char*)d_ws);

    // Jacobi coefficients (A=B=1 here, computed generically)
    const double A = 1.0, B = 1.0, ab = A + B;
    float c0 = (float)((A - B) / 2.0);
    float c1 = (float)((A + B) / 2.0);
    float th1[4], th2[4], th3[4];
    for (int k = 2; k <= 3; k++) {
        th1[k] = (float)((2.0*k+ab)*(2.0*k+ab-1.0)/((k+ab)*2.0*k));
        th2[k] = (float)((2.0*k+ab-1.0)*(A*A-B*B)/((2.0*k+ab-2.0)*(k+ab)*2.0*k));
        th3[k] = (float)((k+A-1.0)*(k+B-1.0)*(2.0*k+ab)/(k*(ab+k)*(2.0*k+ab-2.0)));
    }

    const int total = NALL * DIM;
    dim3 blk(256);
    dim3 grdE((total + 255) / 256);
    dim3 grdBin((NE + CHUNK - 1) / CHUNK);             // 1172
    dim3 grdBuck(NBUCK);                               // 1172

    if (ws_size >= need) {
        // ---- edge sort: row-bucket grouped, column-sorted within bucket ----
        hipMemsetAsync(bcnt, 0, NBUCK * sizeof(int), stream);
        hipMemsetAsync(bfill, 0, NBUCK * sizeof(int), stream);
        bucket_hist_kernel<<<grdBin, blk, 0, stream>>>(rows, bcnt);
        bucket_scan_kernel<<<1, 1024, 0, stream>>>(bcnt, bptr);
        binned_scatter_kernel<<<grdBin, blk, 0, stream>>>(rows, cols, vals, bptr, bfill, tmp);
        bucket_colsort_kernel<<<grdBuck, blk, 0, stream>>>(bptr, tmp, sedges);

        // ---- propagation (3 SpMMs, fused combine) ----
        concat_init_kernel<<<grdE, blk, 0, stream>>>(user_emb, item_emb, W0, out);
        spmm_lds_combine_kernel<<<grdBuck, blk, 0, stream>>>(bptr, sedges, W0, W0, W0,
                                                             c1, c0, 0.0f, W1, out);
        spmm_lds_combine_kernel<<<grdBuck, blk, 0, stream>>>(bptr, sedges, W1, W1, W0,
                                                             th1[2], th2[2], th3[2], W2, out);
        spmm_lds_combine_kernel<<<grdBuck, blk, 0, stream>>>(bptr, sedges, W2, W2, W1,
                                                             th1[3], th2[3], th3[3], W0, out);
        finalize_kernel<<<grdE, blk, 0, stream>>>(user_emb, item_emb, out);
    } else {
        // ---- fallback: atomic path ----
        long long spmm_threads = (long long)NE * 64;
        dim3 grdS((unsigned)((spmm_threads + 255) / 256));
        concat_init_kernel<<<grdE, blk, 0, stream>>>(user_emb, item_emb, W0, out);
        hipMemsetAsync(W1, 0, nbuf * sizeof(float), stream);
        spmm_atomic_kernel<<<grdS, blk, 0, stream>>>(rows, cols, vals, W0, W1);
        combine3_kernel<<<grdE, blk, 0, stream>>>(W1, W0, W0, c1, c0, 0.0f, out);
        hipMemsetAsync(W2, 0, nbuf * sizeof(float), stream);
        spmm_atomic_kernel<<<grdS, blk, 0, stream>>>(rows, cols, vals, W1, W2);
        combine3_kernel<<<grdE, blk, 0, stream>>>(W2, W1, W0, th1[2], th2[2], th3[2], out);
        hipMemsetAsync(W0, 0, nbuf * sizeof(float), stream);
        spmm_atomic_kernel<<<grdS, blk, 0, stream>>>(rows, cols, vals, W2, W0);
        combine3_kernel<<<grdE, blk, 0, stream>>>(W0, W2, W1, th1[3], th2[3], th3[3], out);
        finalize_kernel<<<grdE, blk, 0, stream>>>(user_emb, item_emb, out);
    }
}

// Round 5
// 876.057 us; speedup vs baseline: 6.2554x; 6.2554x over previous
//
#include <hip/hip_runtime.h>
#include <hip/hip_fp16.h>
#include <cmath>

#define NU 100000
#define NI 50000
#define NALL 150000
#define DIM 64
#define NE 4800000

#define BSH 7                 // bucket = row >> 7  (128 rows/bucket)
#define BROWS 128
#define NBUCK ((NALL + BROWS - 1) / BROWS)   // 1172
#define EPT 16
#define CHUNK (256 * EPT)     // 4096 edges per binning block
#define COLMASK 0x3FFFF      // 18 bits, NALL < 2^18

// ---------------- CSR build (round-3 proven path) ----------------

__global__ void bucket_hist_kernel(const int* __restrict__ rows, int* __restrict__ bcnt) {
    __shared__ int h[NBUCK];
    for (int i = threadIdx.x; i < NBUCK; i += 256) h[i] = 0;
    __syncthreads();
    int base = blockIdx.x * CHUNK;
    #pragma unroll
    for (int i = 0; i < EPT; i++) {
        int e = base + threadIdx.x + i * 256;
        if (e < NE) atomicAdd(&h[rows[e] >> BSH], 1);
    }
    __syncthreads();
    for (int i = threadIdx.x; i < NBUCK; i += 256)
        if (h[i]) atomicAdd(&bcnt[i], h[i]);
}

__global__ void bucket_scan_kernel(const int* __restrict__ bcnt, int* __restrict__ bptr) {
    __shared__ int s[1024];
    int t = threadIdx.x;
    const int chunk = (NBUCK + 1023) / 1024;   // 2
    int lo = t * chunk, hi = lo + chunk;
    if (hi > NBUCK) hi = NBUCK;
    int sum = 0;
    for (int i = lo; i < hi; ++i) sum += bcnt[i];
    s[t] = sum;
    __syncthreads();
    for (int off = 1; off < 1024; off <<= 1) {
        int v = (t >= off) ? s[t - off] : 0;
        __syncthreads();
        s[t] += v;
        __syncthreads();
    }
    int run = s[t] - sum;
    for (int i = lo; i < hi; ++i) { bptr[i] = run; run += bcnt[i]; }
    if (t == 1023) bptr[NBUCK] = s[1023];
}

__global__ void binned_scatter_kernel(const int* __restrict__ rows, const int* __restrict__ cols,
                                      const float* __restrict__ vals, const int* __restrict__ bptr,
                                      int* __restrict__ bfill, int2* __restrict__ tmp) {
    __shared__ int lcnt[NBUCK];
    __shared__ int lbase[NBUCK];
    for (int i = threadIdx.x; i < NBUCK; i += 256) lcnt[i] = 0;
    __syncthreads();
    int base = blockIdx.x * CHUNK;
    int bk[EPT], rk[EPT];
    #pragma unroll
    for (int i = 0; i < EPT; i++) {
        int e = base + threadIdx.x + i * 256;
        if (e < NE) {
            bk[i] = rows[e] >> BSH;
            rk[i] = atomicAdd(&lcnt[bk[i]], 1);
        } else bk[i] = -1;
    }
    __syncthreads();
    for (int i = threadIdx.x; i < NBUCK; i += 256) {
        int c = lcnt[i];
        lbase[i] = c ? atomicAdd(&bfill[i], c) : 0;
    }
    __syncthreads();
    #pragma unroll
    for (int i = 0; i < EPT; i++) {
        int e = base + threadIdx.x + i * 256;
        if (e < NE) {
            int r = rows[e];
            int key = ((r & (BROWS - 1)) << 18) | cols[e];
            tmp[bptr[bk[i]] + lbase[bk[i]] + rk[i]] = make_int2(key, __float_as_int(vals[e]));
        }
    }
}

// Exact within-bucket counting sort by local row; emits row_ptr.
__global__ void bucket_sort_kernel(const int* __restrict__ bptr, const int2* __restrict__ tmp,
                                   int2* __restrict__ sedges, int* __restrict__ row_ptr) {
    __shared__ int h[BROWS], f[BROWS], sc[BROWS];
    int b = blockIdx.x, t = threadIdx.x;
    int s0 = bptr[b], s1 = bptr[b + 1];
    if (t < BROWS) { h[t] = 0; f[t] = 0; }
    __syncthreads();
    for (int i = s0 + t; i < s1; i += 256) atomicAdd(&h[tmp[i].x >> 18], 1);
    __syncthreads();
    if (t < BROWS) sc[t] = h[t];
    __syncthreads();
    for (int off = 1; off < BROWS; off <<= 1) {
        int v = 0;
        if (t < BROWS && t >= off) v = sc[t - off];
        __syncthreads();
        if (t < BROWS) sc[t] += v;
        __syncthreads();
    }
    if (t < BROWS) {
        int row = b * BROWS + t;
        if (row < NALL) row_ptr[row] = s0 + sc[t] - h[t];
    }
    if (b == NBUCK - 1 && t == 0) row_ptr[NALL] = s1;
    __syncthreads();
    for (int i = s0 + t; i < s1; i += 256) {
        int2 ed = tmp[i];
        int rl = ed.x >> 18;
        int r = atomicAdd(&f[rl], 1);
        sedges[s0 + sc[rl] - h[rl] + r] = ed;
    }
}

// ---------------- embedding passes ----------------

__global__ void concat_init_kernel(const float* __restrict__ u, const float* __restrict__ it,
                                   float* __restrict__ w0, __half* __restrict__ w0h,
                                   float* __restrict__ out) {
    int idx = blockIdx.x * blockDim.x + threadIdx.x;
    const int total = NALL * DIM;
    if (idx >= total) return;
    const int nue = NU * DIM;
    float v = (idx < nue) ? u[idx] : it[idx - nue];
    w0[idx] = v;
    if (w0h) w0h[idx] = __float2half(v);
    int row = idx >> 6, d = idx & 63;
    out[(size_t)row * 128 + d] = v;   // running band-stop sum := e0
}

// Wave-per-row, fp16 gather, 4-wide MLP unroll; fused Jacobi combine + band-stop sum.
__global__ void spmm_combine_f16_kernel(const int* __restrict__ row_ptr,
                                        const int2* __restrict__ sedges,
                                        const __half* __restrict__ xh,
                                        const float* __restrict__ ekm1,
                                        const float* __restrict__ ekm2,
                                        float t1, float t2, float t3,
                                        float* __restrict__ ek_out,
                                        __half* __restrict__ ekh_out,
                                        float* __restrict__ out) {
    int wid = (blockIdx.x * blockDim.x + threadIdx.x) >> 6;
    if (wid >= NALL) return;
    int lane = threadIdx.x & 63;
    int s = row_ptr[wid], e = row_ptr[wid + 1];
    float acc = 0.f;
    int i = s;
    for (; i + 4 <= e; i += 4) {
        int2 ea = sedges[i], eb = sedges[i + 1], ec = sedges[i + 2], ed = sedges[i + 3];
        float xa = __half2float(xh[(size_t)(ea.x & COLMASK) * DIM + lane]);
        float xb = __half2float(xh[(size_t)(eb.x & COLMASK) * DIM + lane]);
        float xc = __half2float(xh[(size_t)(ec.x & COLMASK) * DIM + lane]);
        float xd = __half2float(xh[(size_t)(ed.x & COLMASK) * DIM + lane]);
        acc += __int_as_float(ea.y) * xa;
        acc += __int_as_float(eb.y) * xb;
        acc += __int_as_float(ec.y) * xc;
        acc += __int_as_float(ed.y) * xd;
    }
    for (; i < e; ++i) {
        int2 ed = sedges[i];
        acc += __int_as_float(ed.y) * __half2float(xh[(size_t)(ed.x & COLMASK) * DIM + lane]);
    }
    size_t o = (size_t)wid * DIM + lane;
    float ek = t1 * acc + t2 * ekm1[o] - t3 * ekm2[o];
    ek_out[o] = ek;
    if (ekh_out) ekh_out[o] = __float2half(ek);
    out[(size_t)wid * 128 + lane] += ek;
}

// Exact fp32-gather variant (used when ws can't hold fp16 mirrors).
__global__ void spmm_combine_kernel(const int* __restrict__ row_ptr,
                                    const int2* __restrict__ sedges,
                                    const float* __restrict__ x,
                                    const float* __restrict__ ekm1,
                                    const float* __restrict__ ekm2,
                                    float t1, float t2, float t3,
                                    float* __restrict__ ek_out,
                                    float* __restrict__ out) {
    int wid = (blockIdx.x * blockDim.x + threadIdx.x) >> 6;
    if (wid >= NALL) return;
    int lane = threadIdx.x & 63;
    int s = row_ptr[wid], e = row_ptr[wid + 1];
    float acc = 0.f;
    int i = s;
    for (; i + 4 <= e; i += 4) {
        int2 ea = sedges[i], eb = sedges[i + 1], ec = sedges[i + 2], ed = sedges[i + 3];
        float xa = x[(size_t)(ea.x & COLMASK) * DIM + lane];
        float xb = x[(size_t)(eb.x & COLMASK) * DIM + lane];
        float xc = x[(size_t)(ec.x & COLMASK) * DIM + lane];
        float xd = x[(size_t)(ed.x & COLMASK) * DIM + lane];
        acc += __int_as_float(ea.y) * xa;
        acc += __int_as_float(eb.y) * xb;
        acc += __int_as_float(ec.y) * xc;
        acc += __int_as_float(ed.y) * xd;
    }
    for (; i < e; ++i) {
        int2 ed = sedges[i];
        acc += __int_as_float(ed.y) * x[(size_t)(ed.x & COLMASK) * DIM + lane];
    }
    size_t o = (size_t)wid * DIM + lane;
    float ek = t1 * acc + t2 * ekm1[o] - t3 * ekm2[o];
    ek_out[o] = ek;
    out[(size_t)wid * 128 + lane] += ek;
}

__global__ void finalize_kernel(const float* __restrict__ u, const float* __restrict__ it,
                                float* __restrict__ out) {
    int idx = blockIdx.x * blockDim.x + threadIdx.x;
    const int total = NALL * DIM;
    if (idx >= total) return;
    const int nue = NU * DIM;
    float v = (idx < nue) ? u[idx] : it[idx - nue];
    int row = idx >> 6, d = idx & 63;
    size_t o = (size_t)row * 128 + d;
    float bs = out[o] * 0.25f;
    float bp = tanhf(0.1f * v - bs);
    out[o] = bs;
    out[o + DIM] = bp;
}

// ---------------- fallback (atomic scatter) ----------------

__global__ void spmm_atomic_kernel(const int* __restrict__ rows, const int* __restrict__ cols,
                                   const float* __restrict__ vals, const float* __restrict__ x,
                                   float* __restrict__ y) {
    int gid = blockIdx.x * blockDim.x + threadIdx.x;
    int e = gid >> 6;
    if (e >= NE) return;
    int lane = threadIdx.x & 63;
    atomicAdd(&y[(size_t)rows[e] * DIM + lane], vals[e] * x[(size_t)cols[e] * DIM + lane]);
}

__global__ void combine3_kernel(float* __restrict__ t, const float* __restrict__ ekm1,
                                const float* __restrict__ ekm2, float t1, float t2, float t3,
                                float* __restrict__ out) {
    int idx = blockIdx.x * blockDim.x + threadIdx.x;
    const int total = NALL * DIM;
    if (idx >= total) return;
    float ek = t1 * t[idx] + t2 * ekm1[idx] - t3 * ekm2[idx];
    t[idx] = ek;
    int row = idx >> 6, d = idx & 63;
    out[(size_t)row * 128 + d] += ek;
}

// ---------------- launch ----------------

extern "C" void kernel_launch(void* const* d_in, const int* in_sizes, int n_in,
                              void* d_out, int out_size, void* d_ws, size_t ws_size,
                              hipStream_t stream) {
    const float* user_emb = (const float*)d_in[0];
    const float* item_emb = (const float*)d_in[1];
    const int*   rows     = (const int*)d_in[2];
    const int*   cols     = (const int*)d_in[3];
    const float* vals     = (const float*)d_in[4];
    float* out = (float*)d_out;

    const size_t nbuf = (size_t)NALL * DIM;            // 9.6M floats = 38.4 MB
    float* W0 = (float*)d_ws;
    float* W1 = W0 + nbuf;
    float* W2 = W1 + nbuf;
    int2*  tmp     = (int2*)W1;                        // alias: dead before propagation
    int2*  sedges  = (int2*)(W2 + nbuf);               // NE * 8 B
    int*   row_ptr = (int*)(sedges + NE);              // NALL+1
    int*   bcnt    = row_ptr + (NALL + 1);             // NBUCK
    int*   bptr    = bcnt + NBUCK;                     // NBUCK+1
    int*   bfill   = bptr + (NBUCK + 1);               // NBUCK
    __half* HA     = (__half*)(bfill + NBUCK);         // fp16 mirror A (nbuf halves)
    __half* HB     = HA + nbuf;                        // fp16 mirror B
    size_t need_basic = (size_t)((char*)HA - (char*)d_ws);
    size_t need_full  = (size_t)((char*)(HB + nbuf) - (char*)d_ws);

    // Jacobi coefficients (A=B=1 here, computed generically)
    const double A = 1.0, B = 1.0, ab = A + B;
    float c0 = (float)((A - B) / 2.0);
    float c1 = (float)((A + B) / 2.0);
    float th1[4], th2[4], th3[4];
    for (int k = 2; k <= 3; k++) {
        th1[k] = (float)((2.0*k+ab)*(2.0*k+ab-1.0)/((k+ab)*2.0*k));
        th2[k] = (float)((2.0*k+ab-1.0)*(A*A-B*B)/((2.0*k+ab-2.0)*(k+ab)*2.0*k));
        th3[k] = (float)((k+A-1.0)*(k+B-1.0)*(2.0*k+ab)/(k*(ab+k)*(2.0*k+ab-2.0)));
    }

    const int total = NALL * DIM;
    dim3 blk(256);
    dim3 grdE((total + 255) / 256);
    dim3 grdBin((NE + CHUNK - 1) / CHUNK);             // 1172
    dim3 grdBuck(NBUCK);                               // 1172
    dim3 grdRow((NALL * 64 + 255) / 256);              // wave-per-row

    if (ws_size >= need_basic) {
        // ---- edge sort: row-bucket grouping, exact in-bucket row sort ----
        hipMemsetAsync(bcnt, 0, NBUCK * sizeof(int), stream);
        hipMemsetAsync(bfill, 0, NBUCK * sizeof(int), stream);
        bucket_hist_kernel<<<grdBin, blk, 0, stream>>>(rows, bcnt);
        bucket_scan_kernel<<<1, 1024, 0, stream>>>(bcnt, bptr);
        binned_scatter_kernel<<<grdBin, blk, 0, stream>>>(rows, cols, vals, bptr, bfill, tmp);
        bucket_sort_kernel<<<grdBuck, blk, 0, stream>>>(bptr, tmp, sedges, row_ptr);

        if (ws_size >= need_full) {
            // ---- fp16-gather path ----
            concat_init_kernel<<<grdE, blk, 0, stream>>>(user_emb, item_emb, W0, HA, out);
            spmm_combine_f16_kernel<<<grdRow, blk, 0, stream>>>(row_ptr, sedges, HA, W0, W0,
                                                                c1, c0, 0.0f, W1, HB, out);
            spmm_combine_f16_kernel<<<grdRow, blk, 0, stream>>>(row_ptr, sedges, HB, W1, W0,
                                                                th1[2], th2[2], th3[2], W2, HA, out);
            spmm_combine_f16_kernel<<<grdRow, blk, 0, stream>>>(row_ptr, sedges, HA, W2, W1,
                                                                th1[3], th2[3], th3[3], W0, nullptr, out);
        } else {
            // ---- exact fp32-gather path ----
            concat_init_kernel<<<grdE, blk, 0, stream>>>(user_emb, item_emb, W0, nullptr, out);
            spmm_combine_kernel<<<grdRow, blk, 0, stream>>>(row_ptr, sedges, W0, W0, W0,
                                                            c1, c0, 0.0f, W1, out);
            spmm_combine_kernel<<<grdRow, blk, 0, stream>>>(row_ptr, sedges, W1, W1, W0,
                                                            th1[2], th2[2], th3[2], W2, out);
            spmm_combine_kernel<<<grdRow, blk, 0, stream>>>(row_ptr, sedges, W2, W2, W1,
                                                            th1[3], th2[3], th3[3], W0, out);
        }
        finalize_kernel<<<grdE, blk, 0, stream>>>(user_emb, item_emb, out);
    } else {
        // ---- fallback: atomic path ----
        long long spmm_threads = (long long)NE * 64;
        dim3 grdS((unsigned)((spmm_threads + 255) / 256));
        concat_init_kernel<<<grdE, blk, 0, stream>>>(user_emb, item_emb, W0, nullptr, out);
        hipMemsetAsync(W1, 0, nbuf * sizeof(float), stream);
        spmm_atomic_kernel<<<grdS, blk, 0, stream>>>(rows, cols, vals, W0, W1);
        combine3_kernel<<<grdE, blk, 0, stream>>>(W1, W0, W0, c1, c0, 0.0f, out);
        hipMemsetAsync(W2, 0, nbuf * sizeof(float), stream);
        spmm_atomic_kernel<<<grdS, blk, 0, stream>>>(rows, cols, vals, W1, W2);
        combine3_kernel<<<grdE, blk, 0, stream>>>(W2, W1, W0, th1[2], th2[2], th3[2], out);
        hipMemsetAsync(W0, 0, nbuf * sizeof(float), stream);
        spmm_atomic_kernel<<<grdS, blk, 0, stream>>>(rows, cols, vals, W2, W0);
        combine3_kernel<<<grdE, blk, 0, stream>>>(W0, W2, W1, th1[3], th2[3], th3[3], out);
        finalize_kernel<<<grdE, blk, 0, stream>>>(user_emb, item_emb, out);
    }
}

// Round 6
// 732.413 us; speedup vs baseline: 7.4823x; 1.1961x over previous
//
#include <hip/hip_runtime.h>
#include <hip/hip_fp16.h>
#include <cmath>
#include <cstdint>

#define NU 100000
#define NI 50000
#define NALL 150000
#define DIM 64
#define NE 4800000

#define BSH 7                 // bucket = row >> 7  (128 rows/bucket)
#define BROWS 128
#define NBUCK ((NALL + BROWS - 1) / BROWS)   // 1172
#define EPT 16
#define CHUNK (256 * EPT)     // 4096 edges per binning block
#define COLMASK 0x3FFFF       // 18 bits, NALL < 2^18

// ---------------- CSR build (proven round-3 path) ----------------

__global__ void bucket_hist_kernel(const int* __restrict__ rows, int* __restrict__ bcnt) {
    __shared__ int h[NBUCK];
    for (int i = threadIdx.x; i < NBUCK; i += 256) h[i] = 0;
    __syncthreads();
    int base = blockIdx.x * CHUNK;
    #pragma unroll
    for (int i = 0; i < EPT; i++) {
        int e = base + threadIdx.x + i * 256;
        if (e < NE) atomicAdd(&h[rows[e] >> BSH], 1);
    }
    __syncthreads();
    for (int i = threadIdx.x; i < NBUCK; i += 256)
        if (h[i]) atomicAdd(&bcnt[i], h[i]);
}

__global__ void bucket_scan_kernel(const int* __restrict__ bcnt, int* __restrict__ bptr) {
    __shared__ int s[1024];
    int t = threadIdx.x;
    const int chunk = (NBUCK + 1023) / 1024;   // 2
    int lo = t * chunk, hi = lo + chunk;
    if (hi > NBUCK) hi = NBUCK;
    int sum = 0;
    for (int i = lo; i < hi; ++i) sum += bcnt[i];
    s[t] = sum;
    __syncthreads();
    for (int off = 1; off < 1024; off <<= 1) {
        int v = (t >= off) ? s[t - off] : 0;
        __syncthreads();
        s[t] += v;
        __syncthreads();
    }
    int run = s[t] - sum;
    for (int i = lo; i < hi; ++i) { bptr[i] = run; run += bcnt[i]; }
    if (t == 1023) bptr[NBUCK] = s[1023];
}

__global__ void binned_scatter_kernel(const int* __restrict__ rows, const int* __restrict__ cols,
                                      const float* __restrict__ vals, const int* __restrict__ bptr,
                                      int* __restrict__ bfill, int2* __restrict__ tmp) {
    __shared__ int lcnt[NBUCK];
    __shared__ int lbase[NBUCK];
    for (int i = threadIdx.x; i < NBUCK; i += 256) lcnt[i] = 0;
    __syncthreads();
    int base = blockIdx.x * CHUNK;
    int bk[EPT], rk[EPT];
    #pragma unroll
    for (int i = 0; i < EPT; i++) {
        int e = base + threadIdx.x + i * 256;
        if (e < NE) {
            bk[i] = rows[e] >> BSH;
            rk[i] = atomicAdd(&lcnt[bk[i]], 1);
        } else bk[i] = -1;
    }
    __syncthreads();
    for (int i = threadIdx.x; i < NBUCK; i += 256) {
        int c = lcnt[i];
        lbase[i] = c ? atomicAdd(&bfill[i], c) : 0;
    }
    __syncthreads();
    #pragma unroll
    for (int i = 0; i < EPT; i++) {
        int e = base + threadIdx.x + i * 256;
        if (e < NE) {
            int r = rows[e];
            int key = ((r & (BROWS - 1)) << 18) | cols[e];
            tmp[bptr[bk[i]] + lbase[bk[i]] + rk[i]] = make_int2(key, __float_as_int(vals[e]));
        }
    }
}

// Exact within-bucket counting sort by local row; emits row_ptr.
__global__ void bucket_sort_kernel(const int* __restrict__ bptr, const int2* __restrict__ tmp,
                                   int2* __restrict__ sedges, int* __restrict__ row_ptr) {
    __shared__ int h[BROWS], f[BROWS], sc[BROWS];
    int b = blockIdx.x, t = threadIdx.x;
    int s0 = bptr[b], s1 = bptr[b + 1];
    if (t < BROWS) { h[t] = 0; f[t] = 0; }
    __syncthreads();
    for (int i = s0 + t; i < s1; i += 256) atomicAdd(&h[tmp[i].x >> 18], 1);
    __syncthreads();
    if (t < BROWS) sc[t] = h[t];
    __syncthreads();
    for (int off = 1; off < BROWS; off <<= 1) {
        int v = 0;
        if (t < BROWS && t >= off) v = sc[t - off];
        __syncthreads();
        if (t < BROWS) sc[t] += v;
        __syncthreads();
    }
    if (t < BROWS) {
        int row = b * BROWS + t;
        if (row < NALL) row_ptr[row] = s0 + sc[t] - h[t];
    }
    if (b == NBUCK - 1 && t == 0) row_ptr[NALL] = s1;
    __syncthreads();
    for (int i = s0 + t; i < s1; i += 256) {
        int2 ed = tmp[i];
        int rl = ed.x >> 18;
        int r = atomicAdd(&f[rl], 1);
        sedges[s0 + sc[rl] - h[rl] + r] = ed;
    }
}

// ---------------- embedding passes ----------------

__global__ void concat_init_kernel(const float* __restrict__ u, const float* __restrict__ it,
                                   float* __restrict__ w0, __half* __restrict__ w0h,
                                   float* __restrict__ out) {
    int idx = blockIdx.x * blockDim.x + threadIdx.x;
    const int total = NALL * DIM;
    if (idx >= total) return;
    const int nue = NU * DIM;
    float v = (idx < nue) ? u[idx] : it[idx - nue];
    w0[idx] = v;
    if (w0h) w0h[idx] = __float2half(v);
    int row = idx >> 6, d = idx & 63;
    out[(size_t)row * 128 + d] = v;   // running band-stop sum := e0
}

__device__ __forceinline__ float4 fma_h4(uint2 p, float v, float4 acc) {
    __half2 a = *(__half2*)&p.x;
    __half2 b = *(__half2*)&p.y;
    float2 fa = __half22float2(a);
    float2 fb = __half22float2(b);
    acc.x += v * fa.x; acc.y += v * fa.y;
    acc.z += v * fb.x; acc.w += v * fb.y;
    return acc;
}

// Wave-per-row; 4 x 16-lane groups each take every 4th edge; one gather instruction
// covers 4 edges (4 x 128B segments) -> 4x memory-level parallelism per vmcnt slot.
// Unroll 2 => 8 edges / iteration, 2 gathers in flight. Cross-group shfl reduction,
// float4 epilogue (Jacobi combine + band-stop sum + fp16 mirror) on lanes 0-15.
__global__ __launch_bounds__(256) void spmm4_combine_f16_kernel(
        const int* __restrict__ row_ptr, const int2* __restrict__ sedges,
        const __half* __restrict__ xh,
        const float* __restrict__ ekm1, const float* __restrict__ ekm2,
        float t1, float t2, float t3,
        float* __restrict__ ek_out, __half* __restrict__ ekh_out,
        float* __restrict__ out) {
    int wid = (blockIdx.x * blockDim.x + threadIdx.x) >> 6;
    if (wid >= NALL) return;
    int lane = threadIdx.x & 63;
    int g = lane >> 4, l16 = lane & 15;
    int s = row_ptr[wid], e = row_ptr[wid + 1];
    const uint2* xv = (const uint2*)xh;          // 8B units; one row = 16 uint2
    float4 acc = make_float4(0.f, 0.f, 0.f, 0.f);
    for (int i = s + g; i < e; i += 8) {
        int2 e0 = sedges[i];
        int i1 = i + 4;
        uint2 p0 = xv[(size_t)(e0.x & COLMASK) * 16 + l16];
        if (i1 < e) {
            int2 e1 = sedges[i1];
            uint2 p1 = xv[(size_t)(e1.x & COLMASK) * 16 + l16];
            acc = fma_h4(p0, __int_as_float(e0.y), acc);
            acc = fma_h4(p1, __int_as_float(e1.y), acc);
        } else {
            acc = fma_h4(p0, __int_as_float(e0.y), acc);
        }
    }
    // reduce across the 4 lane-groups (lanes differing in bits 4,5)
    #pragma unroll
    for (int off = 16; off < 64; off <<= 1) {
        acc.x += __shfl_xor(acc.x, off);
        acc.y += __shfl_xor(acc.y, off);
        acc.z += __shfl_xor(acc.z, off);
        acc.w += __shfl_xor(acc.w, off);
    }
    if (g == 0) {
        size_t o4 = (size_t)wid * 16 + l16;      // float4 index into 64-dim row
        float4 m1 = ((const float4*)ekm1)[o4];
        float4 m2 = ((const float4*)ekm2)[o4];
        float4 ek;
        ek.x = t1 * acc.x + t2 * m1.x - t3 * m2.x;
        ek.y = t1 * acc.y + t2 * m1.y - t3 * m2.y;
        ek.z = t1 * acc.z + t2 * m1.z - t3 * m2.z;
        ek.w = t1 * acc.w + t2 * m1.w - t3 * m2.w;
        ((float4*)ek_out)[o4] = ek;
        if (ekh_out) {
            __half2 h01 = __floats2half2_rn(ek.x, ek.y);
            __half2 h23 = __floats2half2_rn(ek.z, ek.w);
            uint2 ph;
            ph.x = *(unsigned*)&h01;
            ph.y = *(unsigned*)&h23;
            ((uint2*)ekh_out)[o4] = ph;
        }
        size_t ob = (size_t)wid * 32 + l16;      // out row = 128 floats = 32 float4
        float4 ov = ((float4*)out)[ob];
        ov.x += ek.x; ov.y += ek.y; ov.z += ek.z; ov.w += ek.w;
        ((float4*)out)[ob] = ov;
    }
}

// Exact fp32-gather variant (used when ws can't hold fp16 mirrors).
__global__ void spmm_combine_kernel(const int* __restrict__ row_ptr,
                                    const int2* __restrict__ sedges,
                                    const float* __restrict__ x,
                                    const float* __restrict__ ekm1,
                                    const float* __restrict__ ekm2,
                                    float t1, float t2, float t3,
                                    float* __restrict__ ek_out,
                                    float* __restrict__ out) {
    int wid = (blockIdx.x * blockDim.x + threadIdx.x) >> 6;
    if (wid >= NALL) return;
    int lane = threadIdx.x & 63;
    int s = row_ptr[wid], e = row_ptr[wid + 1];
    float acc = 0.f;
    int i = s;
    for (; i + 4 <= e; i += 4) {
        int2 ea = sedges[i], eb = sedges[i + 1], ec = sedges[i + 2], ed = sedges[i + 3];
        float xa = x[(size_t)(ea.x & COLMASK) * DIM + lane];
        float xb = x[(size_t)(eb.x & COLMASK) * DIM + lane];
        float xc = x[(size_t)(ec.x & COLMASK) * DIM + lane];
        float xd = x[(size_t)(ed.x & COLMASK) * DIM + lane];
        acc += __int_as_float(ea.y) * xa;
        acc += __int_as_float(eb.y) * xb;
        acc += __int_as_float(ec.y) * xc;
        acc += __int_as_float(ed.y) * xd;
    }
    for (; i < e; ++i) {
        int2 ed = sedges[i];
        acc += __int_as_float(ed.y) * x[(size_t)(ed.x & COLMASK) * DIM + lane];
    }
    size_t o = (size_t)wid * DIM + lane;
    float ek = t1 * acc + t2 * ekm1[o] - t3 * ekm2[o];
    ek_out[o] = ek;
    out[(size_t)wid * 128 + lane] += ek;
}

__global__ void finalize_kernel(const float* __restrict__ u, const float* __restrict__ it,
                                float* __restrict__ out) {
    int idx = blockIdx.x * blockDim.x + threadIdx.x;
    const int total = NALL * DIM;
    if (idx >= total) return;
    const int nue = NU * DIM;
    float v = (idx < nue) ? u[idx] : it[idx - nue];
    int row = idx >> 6, d = idx & 63;
    size_t o = (size_t)row * 128 + d;
    float bs = out[o] * 0.25f;
    float bp = tanhf(0.1f * v - bs);
    out[o] = bs;
    out[o + DIM] = bp;
}

// ---------------- fallback (atomic scatter) ----------------

__global__ void spmm_atomic_kernel(const int* __restrict__ rows, const int* __restrict__ cols,
                                   const float* __restrict__ vals, const float* __restrict__ x,
                                   float* __restrict__ y) {
    int gid = blockIdx.x * blockDim.x + threadIdx.x;
    int e = gid >> 6;
    if (e >= NE) return;
    int lane = threadIdx.x & 63;
    atomicAdd(&y[(size_t)rows[e] * DIM + lane], vals[e] * x[(size_t)cols[e] * DIM + lane]);
}

__global__ void combine3_kernel(float* __restrict__ t, const float* __restrict__ ekm1,
                                const float* __restrict__ ekm2, float t1, float t2, float t3,
                                float* __restrict__ out) {
    int idx = blockIdx.x * blockDim.x + threadIdx.x;
    const int total = NALL * DIM;
    if (idx >= total) return;
    float ek = t1 * t[idx] + t2 * ekm1[idx] - t3 * ekm2[idx];
    t[idx] = ek;
    int row = idx >> 6, d = idx & 63;
    out[(size_t)row * 128 + d] += ek;
}

// ---------------- launch ----------------

extern "C" void kernel_launch(void* const* d_in, const int* in_sizes, int n_in,
                              void* d_out, int out_size, void* d_ws, size_t ws_size,
                              hipStream_t stream) {
    const float* user_emb = (const float*)d_in[0];
    const float* item_emb = (const float*)d_in[1];
    const int*   rows     = (const int*)d_in[2];
    const int*   cols     = (const int*)d_in[3];
    const float* vals     = (const float*)d_in[4];
    float* out = (float*)d_out;

    const size_t nbuf = (size_t)NALL * DIM;            // 9.6M floats = 38.4 MB
    float* W0 = (float*)d_ws;
    float* W1 = W0 + nbuf;
    float* W2 = W1 + nbuf;
    int2*  tmp     = (int2*)W1;                        // alias: dead before propagation
    int2*  sedges  = (int2*)(W2 + nbuf);               // NE * 8 B
    int*   row_ptr = (int*)(sedges + NE);              // NALL+1
    int*   bcnt    = row_ptr + (NALL + 1);             // NBUCK
    int*   bptr    = bcnt + NBUCK;                     // NBUCK+1
    int*   bfill   = bptr + (NBUCK + 1);               // NBUCK
    char*  pHA     = (char*)(bfill + NBUCK);
    pHA = (char*)(((uintptr_t)pHA + 255) & ~(uintptr_t)255);   // 256B-align mirrors
    __half* HA     = (__half*)pHA;                     // fp16 mirror A (nbuf halves)
    __half* HB     = HA + nbuf;                        // fp16 mirror B
    size_t need_basic = (size_t)((char*)HA - (char*)d_ws);
    size_t need_full  = (size_t)((char*)(HB + nbuf) - (char*)d_ws);

    // Jacobi coefficients (A=B=1 here, computed generically)
    const double A = 1.0, B = 1.0, ab = A + B;
    float c0 = (float)((A - B) / 2.0);
    float c1 = (float)((A + B) / 2.0);
    float th1[4], th2[4], th3[4];
    for (int k = 2; k <= 3; k++) {
        th1[k] = (float)((2.0*k+ab)*(2.0*k+ab-1.0)/((k+ab)*2.0*k));
        th2[k] = (float)((2.0*k+ab-1.0)*(A*A-B*B)/((2.0*k+ab-2.0)*(k+ab)*2.0*k));
        th3[k] = (float)((k+A-1.0)*(k+B-1.0)*(2.0*k+ab)/(k*(ab+k)*(2.0*k+ab-2.0)));
    }

    const int total = NALL * DIM;
    dim3 blk(256);
    dim3 grdE((total + 255) / 256);
    dim3 grdBin((NE + CHUNK - 1) / CHUNK);             // 1172
    dim3 grdBuck(NBUCK);                               // 1172
    dim3 grdRow((NALL * 64 + 255) / 256);              // wave-per-row

    if (ws_size >= need_basic) {
        // ---- edge sort: row-bucket grouping, exact in-bucket row sort ----
        hipMemsetAsync(bcnt, 0, NBUCK * sizeof(int), stream);
        hipMemsetAsync(bfill, 0, NBUCK * sizeof(int), stream);
        bucket_hist_kernel<<<grdBin, blk, 0, stream>>>(rows, bcnt);
        bucket_scan_kernel<<<1, 1024, 0, stream>>>(bcnt, bptr);
        binned_scatter_kernel<<<grdBin, blk, 0, stream>>>(rows, cols, vals, bptr, bfill, tmp);
        bucket_sort_kernel<<<grdBuck, blk, 0, stream>>>(bptr, tmp, sedges, row_ptr);

        if (ws_size >= need_full) {
            // ---- fp16-gather path, 4-edges-per-instruction ----
            concat_init_kernel<<<grdE, blk, 0, stream>>>(user_emb, item_emb, W0, HA, out);
            spmm4_combine_f16_kernel<<<grdRow, blk, 0, stream>>>(row_ptr, sedges, HA, W0, W0,
                                                                 c1, c0, 0.0f, W1, HB, out);
            spmm4_combine_f16_kernel<<<grdRow, blk, 0, stream>>>(row_ptr, sedges, HB, W1, W0,
                                                                 th1[2], th2[2], th3[2], W2, HA, out);
            spmm4_combine_f16_kernel<<<grdRow, blk, 0, stream>>>(row_ptr, sedges, HA, W2, W1,
                                                                 th1[3], th2[3], th3[3], W0, nullptr, out);
        } else {
            // ---- exact fp32-gather path ----
            concat_init_kernel<<<grdE, blk, 0, stream>>>(user_emb, item_emb, W0, nullptr, out);
            spmm_combine_kernel<<<grdRow, blk, 0, stream>>>(row_ptr, sedges, W0, W0, W0,
                                                            c1, c0, 0.0f, W1, out);
            spmm_combine_kernel<<<grdRow, blk, 0, stream>>>(row_ptr, sedges, W1, W1, W0,
                                                            th1[2], th2[2], th3[2], W2, out);
            spmm_combine_kernel<<<grdRow, blk, 0, stream>>>(row_ptr, sedges, W2, W2, W1,
                                                            th1[3], th2[3], th3[3], W0, out);
        }
        finalize_kernel<<<grdE, blk, 0, stream>>>(user_emb, item_emb, out);
    } else {
        // ---- fallback: atomic path ----
        long long spmm_threads = (long long)NE * 64;
        dim3 grdS((unsigned)((spmm_threads + 255) / 256));
        concat_init_kernel<<<grdE, blk, 0, stream>>>(user_emb, item_emb, W0, nullptr, out);
        hipMemsetAsync(W1, 0, nbuf * sizeof(float), stream);
        spmm_atomic_kernel<<<grdS, blk, 0, stream>>>(rows, cols, vals, W0, W1);
        combine3_kernel<<<grdE, blk, 0, stream>>>(W1, W0, W0, c1, c0, 0.0f, out);
        hipMemsetAsync(W2, 0, nbuf * sizeof(float), stream);
        spmm_atomic_kernel<<<grdS, blk, 0, stream>>>(rows, cols, vals, W1, W2);
        combine3_kernel<<<grdE, blk, 0, stream>>>(W2, W1, W0, th1[2], th2[2], th3[2], out);
        hipMemsetAsync(W0, 0, nbuf * sizeof(float), stream);
        spmm_atomic_kernel<<<grdS, blk, 0, stream>>>(rows, cols, vals, W2, W0);
        combine3_kernel<<<grdE, blk, 0, stream>>>(W0, W2, W1, th1[3], th2[3], th3[3], out);
        finalize_kernel<<<grdE, blk, 0, stream>>>(user_emb, item_emb, out);
    }
}

// Round 7
// 676.430 us; speedup vs baseline: 8.1015x; 1.0828x over previous
//
#include <hip/hip_runtime.h>
#include <hip/hip_fp16.h>
#include <cmath>
#include <cstdint>

#define NU 100000
#define NI 50000
#define NALL 150000
#define DIM 64
#define NE 4800000

#define BSH 7                 // bucket = row >> 7  (128 rows/bucket)
#define BROWS 128
#define NBUCK ((NALL + BROWS - 1) / BROWS)   // 1172
#define EPT 16
#define CHUNK (256 * EPT)     // 4096 edges per binning block
#define COLMASK 0x3FFFF       // 18 bits, NALL < 2^18
#define BCAP 4608             // bucket capacity for staged sort (mean 4096 + 8 sigma)

// ---------------- CSR build ----------------

__global__ void bucket_hist_kernel(const int* __restrict__ rows, int* __restrict__ bcnt) {
    __shared__ int h[NBUCK];
    for (int i = threadIdx.x; i < NBUCK; i += 256) h[i] = 0;
    __syncthreads();
    int base = blockIdx.x * CHUNK;
    #pragma unroll
    for (int i = 0; i < EPT; i++) {
        int e = base + threadIdx.x + i * 256;
        if (e < NE) atomicAdd(&h[rows[e] >> BSH], 1);
    }
    __syncthreads();
    for (int i = threadIdx.x; i < NBUCK; i += 256)
        if (h[i]) atomicAdd(&bcnt[i], h[i]);
}

__global__ void bucket_scan_kernel(const int* __restrict__ bcnt, int* __restrict__ bptr) {
    __shared__ int s[1024];
    int t = threadIdx.x;
    const int chunk = (NBUCK + 1023) / 1024;   // 2
    int lo = t * chunk, hi = lo + chunk;
    if (hi > NBUCK) hi = NBUCK;
    int sum = 0;
    for (int i = lo; i < hi; ++i) sum += bcnt[i];
    s[t] = sum;
    __syncthreads();
    for (int off = 1; off < 1024; off <<= 1) {
        int v = (t >= off) ? s[t - off] : 0;
        __syncthreads();
        s[t] += v;
        __syncthreads();
    }
    int run = s[t] - sum;
    for (int i = lo; i < hi; ++i) { bptr[i] = run; run += bcnt[i]; }
    if (t == 1023) bptr[NBUCK] = s[1023];
}

// LDS-presorted binned scatter: rank -> scan -> LDS scatter -> sequential writeout.
// Wave stores span ~18 bucket regions instead of ~62 -> ~3.5x fewer L2 transactions.
__global__ __launch_bounds__(256) void binned_scatter_kernel(
        const int* __restrict__ rows, const int* __restrict__ cols,
        const float* __restrict__ vals, const int* __restrict__ bptr,
        int* __restrict__ bfill, int2* __restrict__ tmp) {
    __shared__ int2 eLDS[CHUNK];          // 32 KB
    __shared__ int lcnt[NBUCK];
    __shared__ int lofs[NBUCK + 1];
    __shared__ int ldst[NBUCK];
    __shared__ int psum[256];
    int t = threadIdx.x;
    int base = blockIdx.x * CHUNK;
    int cnt = NE - base; if (cnt > CHUNK) cnt = CHUNK;
    for (int i = t; i < NBUCK; i += 256) lcnt[i] = 0;
    __syncthreads();
    int2 ed[EPT]; int mcb[EPT]; int mrk[EPT];
    #pragma unroll
    for (int k = 0; k < EPT; k++) {
        int p = t + k * 256;
        mcb[k] = -1;
        if (p < cnt) {
            int e = base + p;
            int r = rows[e];
            int cb = r >> BSH;
            mcb[k] = cb;
            mrk[k] = atomicAdd(&lcnt[cb], 1);
            ed[k] = make_int2(((r & (BROWS - 1)) << 18) | cols[e], __float_as_int(vals[e]));
        }
    }
    __syncthreads();
    // exclusive scan of lcnt into lofs (two-level over 256 threads)
    const int cpt = (NBUCK + 255) / 256;   // 5
    int lo = t * cpt, hi = lo + cpt;
    if (hi > NBUCK) hi = NBUCK;
    int s = 0;
    for (int i = lo; i < hi; ++i) s += lcnt[i];
    psum[t] = s;
    __syncthreads();
    for (int off = 1; off < 256; off <<= 1) {
        int v = (t >= off) ? psum[t - off] : 0;
        __syncthreads();
        psum[t] += v;
        __syncthreads();
    }
    int run = psum[t] - s;
    for (int i = lo; i < hi; ++i) { lofs[i] = run; run += lcnt[i]; }
    if (t == 255) lofs[NBUCK] = cnt;
    __syncthreads();
    // reserve global space per bucket; ldst[b] = global_base - local_base
    for (int i = t; i < NBUCK; i += 256) {
        int c = lcnt[i];
        int g = c ? atomicAdd(&bfill[i], c) : 0;
        ldst[i] = bptr[i] + g - lofs[i];
    }
    __syncthreads();
    // LDS scatter: bucket-sorted order
    #pragma unroll
    for (int k = 0; k < EPT; k++)
        if (mcb[k] >= 0) eLDS[lofs[mcb[k]] + mrk[k]] = ed[k];
    __syncthreads();
    // sequential writeout; bucket of position p via binsearch on lofs
    for (int p = t; p < cnt; p += 256) {
        int a = 0, b2 = NBUCK;             // lofs[a] <= p < lofs[b2]
        while (b2 - a > 1) {
            int m = (a + b2) >> 1;
            if (lofs[m] <= p) a = m; else b2 = m;
        }
        tmp[ldst[a] + p] = eLDS[p];
    }
}

// Staged within-bucket counting sort by local row; emits row_ptr.
// Reads coalesced, LDS scatter, fully sequential writeout.
__global__ __launch_bounds__(256) void bucket_sort_kernel(
        const int* __restrict__ bptr, const int2* __restrict__ tmp,
        int2* __restrict__ sedges, int* __restrict__ row_ptr) {
    __shared__ int2 eLDS[BCAP];           // 36.9 KB
    __shared__ int h[BROWS], sc[BROWS], f[BROWS];
    int b = blockIdx.x, t = threadIdx.x;
    int s0 = bptr[b], s1 = bptr[b + 1];
    int cnt = s1 - s0;
    if (t < BROWS) { h[t] = 0; f[t] = 0; }
    if (b == NBUCK - 1 && t == 0) row_ptr[NALL] = s1;
    __syncthreads();
    if (cnt <= BCAP) {                    // uniform branch
        int2 ed[18]; int mrl[18]; int mrk[18];   // BCAP/256 = 18
        #pragma unroll
        for (int k = 0; k < 18; k++) {
            int p = t + k * 256;
            mrl[k] = -1;
            if (p < cnt) {
                int2 E = tmp[s0 + p];
                int rl = E.x >> 18;
                mrl[k] = rl;
                mrk[k] = atomicAdd(&h[rl], 1);
                ed[k] = E;
            }
        }
        __syncthreads();
        if (t < BROWS) sc[t] = h[t];
        __syncthreads();
        for (int off = 1; off < BROWS; off <<= 1) {
            int v = 0;
            if (t < BROWS && t >= off) v = sc[t - off];
            __syncthreads();
            if (t < BROWS) sc[t] += v;
            __syncthreads();
        }
        if (t < BROWS) {
            int row = b * BROWS + t;
            if (row < NALL) row_ptr[row] = s0 + sc[t] - h[t];
        }
        __syncthreads();
        #pragma unroll
        for (int k = 0; k < 18; k++)
            if (mrl[k] >= 0) eLDS[sc[mrl[k]] - h[mrl[k]] + mrk[k]] = ed[k];
        __syncthreads();
        for (int p = t; p < cnt; p += 256) sedges[s0 + p] = eLDS[p];
    } else {
        // legacy unstaged fallback (capacity overflow, never expected)
        for (int i = s0 + t; i < s1; i += 256) atomicAdd(&h[tmp[i].x >> 18], 1);
        __syncthreads();
        if (t < BROWS) sc[t] = h[t];
        __syncthreads();
        for (int off = 1; off < BROWS; off <<= 1) {
            int v = 0;
            if (t < BROWS && t >= off) v = sc[t - off];
            __syncthreads();
            if (t < BROWS) sc[t] += v;
            __syncthreads();
        }
        if (t < BROWS) {
            int row = b * BROWS + t;
            if (row < NALL) row_ptr[row] = s0 + sc[t] - h[t];
        }
        __syncthreads();
        for (int i = s0 + t; i < s1; i += 256) {
            int2 E = tmp[i];
            int rl = E.x >> 18;
            int r = atomicAdd(&f[rl], 1);
            sedges[s0 + sc[rl] - h[rl] + r] = E;
        }
    }
}

// ---------------- embedding passes ----------------

__global__ void concat_init_kernel(const float* __restrict__ u, const float* __restrict__ it,
                                   float* __restrict__ w0, __half* __restrict__ w0h,
                                   float* __restrict__ out) {
    int idx = blockIdx.x * blockDim.x + threadIdx.x;
    const int total = NALL * DIM;
    if (idx >= total) return;
    const int nue = NU * DIM;
    float v = (idx < nue) ? u[idx] : it[idx - nue];
    w0[idx] = v;
    if (w0h) w0h[idx] = __float2half(v);
    int row = idx >> 6, d = idx & 63;
    out[(size_t)row * 128 + d] = v;   // running band-stop sum := e0
}

__device__ __forceinline__ float4 fma_h4(uint2 p, float v, float4 acc) {
    __half2 a = *(__half2*)&p.x;
    __half2 b = *(__half2*)&p.y;
    float2 fa = __half22float2(a);
    float2 fb = __half22float2(b);
    acc.x += v * fa.x; acc.y += v * fa.y;
    acc.z += v * fb.x; acc.w += v * fb.y;
    return acc;
}

// Wave-per-row; 4 x 16-lane groups each take every 4th edge; one gather instruction
// covers 4 edges (4 x 128B segments). Unroll 2 => 2 gathers in flight.
__global__ __launch_bounds__(256) void spmm4_combine_f16_kernel(
        const int* __restrict__ row_ptr, const int2* __restrict__ sedges,
        const __half* __restrict__ xh,
        const float* __restrict__ ekm1, const float* __restrict__ ekm2,
        float t1, float t2, float t3,
        float* __restrict__ ek_out, __half* __restrict__ ekh_out,
        float* __restrict__ out) {
    int wid = (blockIdx.x * blockDim.x + threadIdx.x) >> 6;
    if (wid >= NALL) return;
    int lane = threadIdx.x & 63;
    int g = lane >> 4, l16 = lane & 15;
    int s = row_ptr[wid], e = row_ptr[wid + 1];
    const uint2* xv = (const uint2*)xh;          // 8B units; one row = 16 uint2
    float4 acc = make_float4(0.f, 0.f, 0.f, 0.f);
    for (int i = s + g; i < e; i += 8) {
        int2 e0 = sedges[i];
        int i1 = i + 4;
        uint2 p0 = xv[(size_t)(e0.x & COLMASK) * 16 + l16];
        if (i1 < e) {
            int2 e1 = sedges[i1];
            uint2 p1 = xv[(size_t)(e1.x & COLMASK) * 16 + l16];
            acc = fma_h4(p0, __int_as_float(e0.y), acc);
            acc = fma_h4(p1, __int_as_float(e1.y), acc);
        } else {
            acc = fma_h4(p0, __int_as_float(e0.y), acc);
        }
    }
    #pragma unroll
    for (int off = 16; off < 64; off <<= 1) {
        acc.x += __shfl_xor(acc.x, off);
        acc.y += __shfl_xor(acc.y, off);
        acc.z += __shfl_xor(acc.z, off);
        acc.w += __shfl_xor(acc.w, off);
    }
    if (g == 0) {
        size_t o4 = (size_t)wid * 16 + l16;
        float4 m1 = ((const float4*)ekm1)[o4];
        float4 m2 = ((const float4*)ekm2)[o4];
        float4 ek;
        ek.x = t1 * acc.x + t2 * m1.x - t3 * m2.x;
        ek.y = t1 * acc.y + t2 * m1.y - t3 * m2.y;
        ek.z = t1 * acc.z + t2 * m1.z - t3 * m2.z;
        ek.w = t1 * acc.w + t2 * m1.w - t3 * m2.w;
        ((float4*)ek_out)[o4] = ek;
        if (ekh_out) {
            __half2 h01 = __floats2half2_rn(ek.x, ek.y);
            __half2 h23 = __floats2half2_rn(ek.z, ek.w);
            uint2 ph;
            ph.x = *(unsigned*)&h01;
            ph.y = *(unsigned*)&h23;
            ((uint2*)ekh_out)[o4] = ph;
        }
        size_t ob = (size_t)wid * 32 + l16;
        float4 ov = ((float4*)out)[ob];
        ov.x += ek.x; ov.y += ek.y; ov.z += ek.z; ov.w += ek.w;
        ((float4*)out)[ob] = ov;
    }
}

// Exact fp32-gather variant (used when ws can't hold fp16 mirrors).
__global__ void spmm_combine_kernel(const int* __restrict__ row_ptr,
                                    const int2* __restrict__ sedges,
                                    const float* __restrict__ x,
                                    const float* __restrict__ ekm1,
                                    const float* __restrict__ ekm2,
                                    float t1, float t2, float t3,
                                    float* __restrict__ ek_out,
                                    float* __restrict__ out) {
    int wid = (blockIdx.x * blockDim.x + threadIdx.x) >> 6;
    if (wid >= NALL) return;
    int lane = threadIdx.x & 63;
    int s = row_ptr[wid], e = row_ptr[wid + 1];
    float acc = 0.f;
    int i = s;
    for (; i + 4 <= e; i += 4) {
        int2 ea = sedges[i], eb = sedges[i + 1], ec = sedges[i + 2], ed = sedges[i + 3];
        float xa = x[(size_t)(ea.x & COLMASK) * DIM + lane];
        float xb = x[(size_t)(eb.x & COLMASK) * DIM + lane];
        float xc = x[(size_t)(ec.x & COLMASK) * DIM + lane];
        float xd = x[(size_t)(ed.x & COLMASK) * DIM + lane];
        acc += __int_as_float(ea.y) * xa;
        acc += __int_as_float(eb.y) * xb;
        acc += __int_as_float(ec.y) * xc;
        acc += __int_as_float(ed.y) * xd;
    }
    for (; i < e; ++i) {
        int2 ed = sedges[i];
        acc += __int_as_float(ed.y) * x[(size_t)(ed.x & COLMASK) * DIM + lane];
    }
    size_t o = (size_t)wid * DIM + lane;
    float ek = t1 * acc + t2 * ekm1[o] - t3 * ekm2[o];
    ek_out[o] = ek;
    out[(size_t)wid * 128 + lane] += ek;
}

__global__ void finalize_kernel(const float* __restrict__ u, const float* __restrict__ it,
                                float* __restrict__ out) {
    int idx = blockIdx.x * blockDim.x + threadIdx.x;
    const int total = NALL * DIM;
    if (idx >= total) return;
    const int nue = NU * DIM;
    float v = (idx < nue) ? u[idx] : it[idx - nue];
    int row = idx >> 6, d = idx & 63;
    size_t o = (size_t)row * 128 + d;
    float bs = out[o] * 0.25f;
    float bp = tanhf(0.1f * v - bs);
    out[o] = bs;
    out[o + DIM] = bp;
}

// ---------------- fallback (atomic scatter) ----------------

__global__ void spmm_atomic_kernel(const int* __restrict__ rows, const int* __restrict__ cols,
                                   const float* __restrict__ vals, const float* __restrict__ x,
                                   float* __restrict__ y) {
    int gid = blockIdx.x * blockDim.x + threadIdx.x;
    int e = gid >> 6;
    if (e >= NE) return;
    int lane = threadIdx.x & 63;
    atomicAdd(&y[(size_t)rows[e] * DIM + lane], vals[e] * x[(size_t)cols[e] * DIM + lane]);
}

__global__ void combine3_kernel(float* __restrict__ t, const float* __restrict__ ekm1,
                                const float* __restrict__ ekm2, float t1, float t2, float t3,
                                float* __restrict__ out) {
    int idx = blockIdx.x * blockDim.x + threadIdx.x;
    const int total = NALL * DIM;
    if (idx >= total) return;
    float ek = t1 * t[idx] + t2 * ekm1[idx] - t3 * ekm2[idx];
    t[idx] = ek;
    int row = idx >> 6, d = idx & 63;
    out[(size_t)row * 128 + d] += ek;
}

// ---------------- launch ----------------

extern "C" void kernel_launch(void* const* d_in, const int* in_sizes, int n_in,
                              void* d_out, int out_size, void* d_ws, size_t ws_size,
                              hipStream_t stream) {
    const float* user_emb = (const float*)d_in[0];
    const float* item_emb = (const float*)d_in[1];
    const int*   rows     = (const int*)d_in[2];
    const int*   cols     = (const int*)d_in[3];
    const float* vals     = (const float*)d_in[4];
    float* out = (float*)d_out;

    const size_t nbuf = (size_t)NALL * DIM;            // 9.6M floats = 38.4 MB
    float* W0 = (float*)d_ws;
    float* W1 = W0 + nbuf;
    float* W2 = W1 + nbuf;
    int2*  tmp     = (int2*)W1;                        // alias: dead before propagation
    int2*  sedges  = (int2*)(W2 + nbuf);               // NE * 8 B
    int*   row_ptr = (int*)(sedges + NE);              // NALL+1
    int*   bcnt    = row_ptr + (NALL + 1);             // NBUCK
    int*   bptr    = bcnt + NBUCK;                     // NBUCK+1
    int*   bfill   = bptr + (NBUCK + 1);               // NBUCK
    char*  pHA     = (char*)(bfill + NBUCK);
    pHA = (char*)(((uintptr_t)pHA + 255) & ~(uintptr_t)255);   // 256B-align mirrors
    __half* HA     = (__half*)pHA;                     // fp16 mirror A (nbuf halves)
    __half* HB     = HA + nbuf;                        // fp16 mirror B
    size_t need_basic = (size_t)((char*)HA - (char*)d_ws);
    size_t need_full  = (size_t)((char*)(HB + nbuf) - (char*)d_ws);

    // Jacobi coefficients (A=B=1 here, computed generically)
    const double A = 1.0, B = 1.0, ab = A + B;
    float c0 = (float)((A - B) / 2.0);
    float c1 = (float)((A + B) / 2.0);
    float th1[4], th2[4], th3[4];
    for (int k = 2; k <= 3; k++) {
        th1[k] = (float)((2.0*k+ab)*(2.0*k+ab-1.0)/((k+ab)*2.0*k));
        th2[k] = (float)((2.0*k+ab-1.0)*(A*A-B*B)/((2.0*k+ab-2.0)*(k+ab)*2.0*k));
        th3[k] = (float)((k+A-1.0)*(k+B-1.0)*(2.0*k+ab)/(k*(ab+k)*(2.0*k+ab-2.0)));
    }

    const int total = NALL * DIM;
    dim3 blk(256);
    dim3 grdE((total + 255) / 256);
    dim3 grdBin((NE + CHUNK - 1) / CHUNK);             // 1172
    dim3 grdBuck(NBUCK);                               // 1172
    dim3 grdRow((NALL * 64 + 255) / 256);              // wave-per-row

    if (ws_size >= need_basic) {
        // ---- edge sort: row-bucket grouping (LDS-presorted), exact in-bucket sort ----
        hipMemsetAsync(bcnt, 0, NBUCK * sizeof(int), stream);
        hipMemsetAsync(bfill, 0, NBUCK * sizeof(int), stream);
        bucket_hist_kernel<<<grdBin, blk, 0, stream>>>(rows, bcnt);
        bucket_scan_kernel<<<1, 1024, 0, stream>>>(bcnt, bptr);
        binned_scatter_kernel<<<grdBin, blk, 0, stream>>>(rows, cols, vals, bptr, bfill, tmp);
        bucket_sort_kernel<<<grdBuck, blk, 0, stream>>>(bptr, tmp, sedges, row_ptr);

        if (ws_size >= need_full) {
            // ---- fp16-gather path, 4-edges-per-instruction ----
            concat_init_kernel<<<grdE, blk, 0, stream>>>(user_emb, item_emb, W0, HA, out);
            spmm4_combine_f16_kernel<<<grdRow, blk, 0, stream>>>(row_ptr, sedges, HA, W0, W0,
                                                                 c1, c0, 0.0f, W1, HB, out);
            spmm4_combine_f16_kernel<<<grdRow, blk, 0, stream>>>(row_ptr, sedges, HB, W1, W0,
                                                                 th1[2], th2[2], th3[2], W2, HA, out);
            spmm4_combine_f16_kernel<<<grdRow, blk, 0, stream>>>(row_ptr, sedges, HA, W2, W1,
                                                                 th1[3], th2[3], th3[3], W0, nullptr, out);
        } else {
            // ---- exact fp32-gather path ----
            concat_init_kernel<<<grdE, blk, 0, stream>>>(user_emb, item_emb, W0, nullptr, out);
            spmm_combine_kernel<<<grdRow, blk, 0, stream>>>(row_ptr, sedges, W0, W0, W0,
                                                            c1, c0, 0.0f, W1, out);
            spmm_combine_kernel<<<grdRow, blk, 0, stream>>>(row_ptr, sedges, W1, W1, W0,
                                                            th1[2], th2[2], th3[2], W2, out);
            spmm_combine_kernel<<<grdRow, blk, 0, stream>>>(row_ptr, sedges, W2, W2, W1,
                                                            th1[3], th2[3], th3[3], W0, out);
        }
        finalize_kernel<<<grdE, blk, 0, stream>>>(user_emb, item_emb, out);
    } else {
        // ---- fallback: atomic path ----
        long long spmm_threads = (long long)NE * 64;
        dim3 grdS((unsigned)((spmm_threads + 255) / 256));
        concat_init_kernel<<<grdE, blk, 0, stream>>>(user_emb, item_emb, W0, nullptr, out);
        hipMemsetAsync(W1, 0, nbuf * sizeof(float), stream);
        spmm_atomic_kernel<<<grdS, blk, 0, stream>>>(rows, cols, vals, W0, W1);
        combine3_kernel<<<grdE, blk, 0, stream>>>(W1, W0, W0, c1, c0, 0.0f, out);
        hipMemsetAsync(W2, 0, nbuf * sizeof(float), stream);
        spmm_atomic_kernel<<<grdS, blk, 0, stream>>>(rows, cols, vals, W1, W2);
        combine3_kernel<<<grdE, blk, 0, stream>>>(W2, W1, W0, th1[2], th2[2], th3[2], out);
        hipMemsetAsync(W0, 0, nbuf * sizeof(float), stream);
        spmm_atomic_kernel<<<grdS, blk, 0, stream>>>(rows, cols, vals, W2, W0);
        combine3_kernel<<<grdE, blk, 0, stream>>>(W0, W2, W1, th1[3], th2[3], th3[3], out);
        finalize_kernel<<<grdE, blk, 0, stream>>>(user_emb, item_emb, out);
    }
}

// Round 8
// 569.777 us; speedup vs baseline: 9.6180x; 1.1872x over previous
//
#include <hip/hip_runtime.h>
#include <hip/hip_fp16.h>
#include <cmath>
#include <cstdint>

#define NU 100000
#define NI 50000
#define NALL 150000
#define DIM 64
#define NE 4800000

#define BSH 7                 // bucket = row >> 7  (128 rows/bucket)
#define BROWS 128
#define NBUCK ((NALL + BROWS - 1) / BROWS)   // 1172
#define EPT 16
#define CHUNK (256 * EPT)     // 4096 edges per binning block
#define COLMASK 0x3FFFF       // 18 bits, NALL < 2^18
#define BCAP 4608             // bucket capacity for staged sort (mean 4096 + 8 sigma)

// ---------------- CSR build (round-7 proven path, unchanged) ----------------

__global__ void bucket_hist_kernel(const int* __restrict__ rows, int* __restrict__ bcnt) {
    __shared__ int h[NBUCK];
    for (int i = threadIdx.x; i < NBUCK; i += 256) h[i] = 0;
    __syncthreads();
    int base = blockIdx.x * CHUNK;
    #pragma unroll
    for (int i = 0; i < EPT; i++) {
        int e = base + threadIdx.x + i * 256;
        if (e < NE) atomicAdd(&h[rows[e] >> BSH], 1);
    }
    __syncthreads();
    for (int i = threadIdx.x; i < NBUCK; i += 256)
        if (h[i]) atomicAdd(&bcnt[i], h[i]);
}

__global__ void bucket_scan_kernel(const int* __restrict__ bcnt, int* __restrict__ bptr) {
    __shared__ int s[1024];
    int t = threadIdx.x;
    const int chunk = (NBUCK + 1023) / 1024;   // 2
    int lo = t * chunk, hi = lo + chunk;
    if (hi > NBUCK) hi = NBUCK;
    int sum = 0;
    for (int i = lo; i < hi; ++i) sum += bcnt[i];
    s[t] = sum;
    __syncthreads();
    for (int off = 1; off < 1024; off <<= 1) {
        int v = (t >= off) ? s[t - off] : 0;
        __syncthreads();
        s[t] += v;
        __syncthreads();
    }
    int run = s[t] - sum;
    for (int i = lo; i < hi; ++i) { bptr[i] = run; run += bcnt[i]; }
    if (t == 1023) bptr[NBUCK] = s[1023];
}

__global__ __launch_bounds__(256) void binned_scatter_kernel(
        const int* __restrict__ rows, const int* __restrict__ cols,
        const float* __restrict__ vals, const int* __restrict__ bptr,
        int* __restrict__ bfill, int2* __restrict__ tmp) {
    __shared__ int2 eLDS[CHUNK];          // 32 KB
    __shared__ int lcnt[NBUCK];
    __shared__ int lofs[NBUCK + 1];
    __shared__ int ldst[NBUCK];
    __shared__ int psum[256];
    int t = threadIdx.x;
    int base = blockIdx.x * CHUNK;
    int cnt = NE - base; if (cnt > CHUNK) cnt = CHUNK;
    for (int i = t; i < NBUCK; i += 256) lcnt[i] = 0;
    __syncthreads();
    int2 ed[EPT]; int mcb[EPT]; int mrk[EPT];
    #pragma unroll
    for (int k = 0; k < EPT; k++) {
        int p = t + k * 256;
        mcb[k] = -1;
        if (p < cnt) {
            int e = base + p;
            int r = rows[e];
            int cb = r >> BSH;
            mcb[k] = cb;
            mrk[k] = atomicAdd(&lcnt[cb], 1);
            ed[k] = make_int2(((r & (BROWS - 1)) << 18) | cols[e], __float_as_int(vals[e]));
        }
    }
    __syncthreads();
    const int cpt = (NBUCK + 255) / 256;   // 5
    int lo = t * cpt, hi = lo + cpt;
    if (hi > NBUCK) hi = NBUCK;
    int s = 0;
    for (int i = lo; i < hi; ++i) s += lcnt[i];
    psum[t] = s;
    __syncthreads();
    for (int off = 1; off < 256; off <<= 1) {
        int v = (t >= off) ? psum[t - off] : 0;
        __syncthreads();
        psum[t] += v;
        __syncthreads();
    }
    int run = psum[t] - s;
    for (int i = lo; i < hi; ++i) { lofs[i] = run; run += lcnt[i]; }
    if (t == 255) lofs[NBUCK] = cnt;
    __syncthreads();
    for (int i = t; i < NBUCK; i += 256) {
        int c = lcnt[i];
        int g = c ? atomicAdd(&bfill[i], c) : 0;
        ldst[i] = bptr[i] + g - lofs[i];
    }
    __syncthreads();
    #pragma unroll
    for (int k = 0; k < EPT; k++)
        if (mcb[k] >= 0) eLDS[lofs[mcb[k]] + mrk[k]] = ed[k];
    __syncthreads();
    for (int p = t; p < cnt; p += 256) {
        int a = 0, b2 = NBUCK;
        while (b2 - a > 1) {
            int m = (a + b2) >> 1;
            if (lofs[m] <= p) a = m; else b2 = m;
        }
        tmp[ldst[a] + p] = eLDS[p];
    }
}

__global__ __launch_bounds__(256) void bucket_sort_kernel(
        const int* __restrict__ bptr, const int2* __restrict__ tmp,
        int2* __restrict__ sedges, int* __restrict__ row_ptr) {
    __shared__ int2 eLDS[BCAP];           // 36.9 KB
    __shared__ int h[BROWS], sc[BROWS], f[BROWS];
    int b = blockIdx.x, t = threadIdx.x;
    int s0 = bptr[b], s1 = bptr[b + 1];
    int cnt = s1 - s0;
    if (t < BROWS) { h[t] = 0; f[t] = 0; }
    if (b == NBUCK - 1 && t == 0) row_ptr[NALL] = s1;
    __syncthreads();
    if (cnt <= BCAP) {
        int2 ed[18]; int mrl[18]; int mrk[18];
        #pragma unroll
        for (int k = 0; k < 18; k++) {
            int p = t + k * 256;
            mrl[k] = -1;
            if (p < cnt) {
                int2 E = tmp[s0 + p];
                int rl = E.x >> 18;
                mrl[k] = rl;
                mrk[k] = atomicAdd(&h[rl], 1);
                ed[k] = E;
            }
        }
        __syncthreads();
        if (t < BROWS) sc[t] = h[t];
        __syncthreads();
        for (int off = 1; off < BROWS; off <<= 1) {
            int v = 0;
            if (t < BROWS && t >= off) v = sc[t - off];
            __syncthreads();
            if (t < BROWS) sc[t] += v;
            __syncthreads();
        }
        if (t < BROWS) {
            int row = b * BROWS + t;
            if (row < NALL) row_ptr[row] = s0 + sc[t] - h[t];
        }
        __syncthreads();
        #pragma unroll
        for (int k = 0; k < 18; k++)
            if (mrl[k] >= 0) eLDS[sc[mrl[k]] - h[mrl[k]] + mrk[k]] = ed[k];
        __syncthreads();
        for (int p = t; p < cnt; p += 256) sedges[s0 + p] = eLDS[p];
    } else {
        for (int i = s0 + t; i < s1; i += 256) atomicAdd(&h[tmp[i].x >> 18], 1);
        __syncthreads();
        if (t < BROWS) sc[t] = h[t];
        __syncthreads();
        for (int off = 1; off < BROWS; off <<= 1) {
            int v = 0;
            if (t < BROWS && t >= off) v = sc[t - off];
            __syncthreads();
            if (t < BROWS) sc[t] += v;
            __syncthreads();
        }
        if (t < BROWS) {
            int row = b * BROWS + t;
            if (row < NALL) row_ptr[row] = s0 + sc[t] - h[t];
        }
        __syncthreads();
        for (int i = s0 + t; i < s1; i += 256) {
            int2 E = tmp[i];
            int rl = E.x >> 18;
            int r = atomicAdd(&f[rl], 1);
            sedges[s0 + sc[rl] - h[rl] + r] = E;
        }
    }
}

// ---------------- embedding passes ----------------

// float4-vectorized concat; fp16 mirror + (optional, fallback-only) out init.
__global__ void concat_init_kernel(const float4* __restrict__ u4, const float4* __restrict__ it4,
                                   float4* __restrict__ w0, uint2* __restrict__ w0h,
                                   float4* __restrict__ out4) {
    int idx = blockIdx.x * blockDim.x + threadIdx.x;
    const int total4 = NALL * 16;
    if (idx >= total4) return;
    const int nu4 = NU * 16;
    float4 v = (idx < nu4) ? u4[idx] : it4[idx - nu4];
    w0[idx] = v;
    if (w0h) {
        __half2 a = __floats2half2_rn(v.x, v.y), b = __floats2half2_rn(v.z, v.w);
        w0h[idx] = make_uint2(*(unsigned*)&a, *(unsigned*)&b);
    }
    if (out4) {
        int row = idx >> 4, q = idx & 15;
        out4[(size_t)row * 32 + q] = v;
    }
}

__device__ __forceinline__ void fma_h8(float* acc, uint4 p, float v) {
    __half2* h = (__half2*)&p;
    #pragma unroll
    for (int j = 0; j < 4; j++) {
        float2 f = __half22float2(h[j]);
        acc[2 * j]     += v * f.x;
        acc[2 * j + 1] += v * f.y;
    }
}

// Wave-per-row; 8 x 8-lane groups, each lane loads 16B -> one gather instruction
// covers 8 edges' full 128B rows. Unroll 2 => 16 edges/iter, 2 gathers in flight.
// No band-stop accumulation here (deferred to finalize).
__global__ __launch_bounds__(256) void spmm8_combine_f16_kernel(
        const int* __restrict__ row_ptr, const int2* __restrict__ sedges,
        const __half* __restrict__ xh,
        const float* __restrict__ ekm1, const float* __restrict__ ekm2,
        float t1, float t2, float t3,
        float* __restrict__ ek_out, __half* __restrict__ ekh_out) {
    int wid = (blockIdx.x * blockDim.x + threadIdx.x) >> 6;
    if (wid >= NALL) return;
    int lane = threadIdx.x & 63;
    int g = lane >> 3, l8 = lane & 7;
    int s = row_ptr[wid], e = row_ptr[wid + 1];
    const uint4* xv = (const uint4*)xh;          // 16B units; one row = 8 uint4
    float acc[8];
    #pragma unroll
    for (int j = 0; j < 8; j++) acc[j] = 0.f;
    for (int i = s + g; i < e; i += 16) {
        int2 e0 = sedges[i];
        uint4 p0 = xv[(size_t)(e0.x & COLMASK) * 8 + l8];
        int i1 = i + 8;
        if (i1 < e) {
            int2 e1 = sedges[i1];
            uint4 p1 = xv[(size_t)(e1.x & COLMASK) * 8 + l8];
            fma_h8(acc, p0, __int_as_float(e0.y));
            fma_h8(acc, p1, __int_as_float(e1.y));
        } else {
            fma_h8(acc, p0, __int_as_float(e0.y));
        }
    }
    #pragma unroll
    for (int off = 8; off < 64; off <<= 1) {
        #pragma unroll
        for (int j = 0; j < 8; j++) acc[j] += __shfl_xor(acc[j], off);
    }
    if (g == 0) {
        size_t o4 = (size_t)wid * 16 + l8 * 2;   // float4 index; lane covers dims [l8*8, l8*8+8)
        float4 m1a = ((const float4*)ekm1)[o4], m1b = ((const float4*)ekm1)[o4 + 1];
        float4 m2a = ((const float4*)ekm2)[o4], m2b = ((const float4*)ekm2)[o4 + 1];
        float4 ea, eb;
        ea.x = t1 * acc[0] + t2 * m1a.x - t3 * m2a.x;
        ea.y = t1 * acc[1] + t2 * m1a.y - t3 * m2a.y;
        ea.z = t1 * acc[2] + t2 * m1a.z - t3 * m2a.z;
        ea.w = t1 * acc[3] + t2 * m1a.w - t3 * m2a.w;
        eb.x = t1 * acc[4] + t2 * m1b.x - t3 * m2b.x;
        eb.y = t1 * acc[5] + t2 * m1b.y - t3 * m2b.y;
        eb.z = t1 * acc[6] + t2 * m1b.z - t3 * m2b.z;
        eb.w = t1 * acc[7] + t2 * m1b.w - t3 * m2b.w;
        ((float4*)ek_out)[o4] = ea;
        ((float4*)ek_out)[o4 + 1] = eb;
        if (ekh_out) {
            __half2 h0 = __floats2half2_rn(ea.x, ea.y);
            __half2 h1 = __floats2half2_rn(ea.z, ea.w);
            __half2 h2 = __floats2half2_rn(eb.x, eb.y);
            __half2 h3 = __floats2half2_rn(eb.z, eb.w);
            uint4 ph;
            ph.x = *(unsigned*)&h0; ph.y = *(unsigned*)&h1;
            ph.z = *(unsigned*)&h2; ph.w = *(unsigned*)&h3;
            ((uint4*)ekh_out)[(size_t)wid * 8 + l8] = ph;
        }
    }
}

// Main-path finalize: bs = (e0+e1+e2+e3)/4 from fp32 buffers; bp = tanh(0.1*e0 - bs).
__global__ void finalize_split_kernel(const float4* __restrict__ u4, const float4* __restrict__ it4,
                                      const float4* __restrict__ e1, const float4* __restrict__ e2,
                                      const float4* __restrict__ e3, float4* __restrict__ out4) {
    int idx = blockIdx.x * blockDim.x + threadIdx.x;
    const int total4 = NALL * 16;
    if (idx >= total4) return;
    const int nu4 = NU * 16;
    float4 v = (idx < nu4) ? u4[idx] : it4[idx - nu4];
    float4 a = e1[idx], b = e2[idx], c = e3[idx];
    float4 bs, bp;
    bs.x = 0.25f * (v.x + a.x + b.x + c.x);
    bs.y = 0.25f * (v.y + a.y + b.y + c.y);
    bs.z = 0.25f * (v.z + a.z + b.z + c.z);
    bs.w = 0.25f * (v.w + a.w + b.w + c.w);
    bp.x = tanhf(0.1f * v.x - bs.x);
    bp.y = tanhf(0.1f * v.y - bs.y);
    bp.z = tanhf(0.1f * v.z - bs.z);
    bp.w = tanhf(0.1f * v.w - bs.w);
    int row = idx >> 4, q = idx & 15;
    out4[(size_t)row * 32 + q] = bs;
    out4[(size_t)row * 32 + 16 + q] = bp;
}

// ---------------- fallback kernels (ws-constrained paths) ----------------

__global__ void spmm_combine_kernel(const int* __restrict__ row_ptr,
                                    const int2* __restrict__ sedges,
                                    const float* __restrict__ x,
                                    const float* __restrict__ ekm1,
                                    const float* __restrict__ ekm2,
                                    float t1, float t2, float t3,
                                    float* __restrict__ ek_out,
                                    float* __restrict__ out) {
    int wid = (blockIdx.x * blockDim.x + threadIdx.x) >> 6;
    if (wid >= NALL) return;
    int lane = threadIdx.x & 63;
    int s = row_ptr[wid], e = row_ptr[wid + 1];
    float acc = 0.f;
    int i = s;
    for (; i + 4 <= e; i += 4) {
        int2 ea = sedges[i], eb = sedges[i + 1], ec = sedges[i + 2], ed = sedges[i + 3];
        acc += __int_as_float(ea.y) * x[(size_t)(ea.x & COLMASK) * DIM + lane];
        acc += __int_as_float(eb.y) * x[(size_t)(eb.x & COLMASK) * DIM + lane];
        acc += __int_as_float(ec.y) * x[(size_t)(ec.x & COLMASK) * DIM + lane];
        acc += __int_as_float(ed.y) * x[(size_t)(ed.x & COLMASK) * DIM + lane];
    }
    for (; i < e; ++i) {
        int2 ed = sedges[i];
        acc += __int_as_float(ed.y) * x[(size_t)(ed.x & COLMASK) * DIM + lane];
    }
    size_t o = (size_t)wid * DIM + lane;
    float ek = t1 * acc + t2 * ekm1[o] - t3 * ekm2[o];
    ek_out[o] = ek;
    out[(size_t)wid * 128 + lane] += ek;
}

__global__ void finalize_kernel(const float* __restrict__ u, const float* __restrict__ it,
                                float* __restrict__ out) {
    int idx = blockIdx.x * blockDim.x + threadIdx.x;
    const int total = NALL * DIM;
    if (idx >= total) return;
    const int nue = NU * DIM;
    float v = (idx < nue) ? u[idx] : it[idx - nue];
    int row = idx >> 6, d = idx & 63;
    size_t o = (size_t)row * 128 + d;
    float bs = out[o] * 0.25f;
    float bp = tanhf(0.1f * v - bs);
    out[o] = bs;
    out[o + DIM] = bp;
}

__global__ void spmm_atomic_kernel(const int* __restrict__ rows, const int* __restrict__ cols,
                                   const float* __restrict__ vals, const float* __restrict__ x,
                                   float* __restrict__ y) {
    int gid = blockIdx.x * blockDim.x + threadIdx.x;
    int e = gid >> 6;
    if (e >= NE) return;
    int lane = threadIdx.x & 63;
    atomicAdd(&y[(size_t)rows[e] * DIM + lane], vals[e] * x[(size_t)cols[e] * DIM + lane]);
}

__global__ void combine3_kernel(float* __restrict__ t, const float* __restrict__ ekm1,
                                const float* __restrict__ ekm2, float t1, float t2, float t3,
                                float* __restrict__ out) {
    int idx = blockIdx.x * blockDim.x + threadIdx.x;
    const int total = NALL * DIM;
    if (idx >= total) return;
    float ek = t1 * t[idx] + t2 * ekm1[idx] - t3 * ekm2[idx];
    t[idx] = ek;
    int row = idx >> 6, d = idx & 63;
    out[(size_t)row * 128 + d] += ek;
}

// ---------------- launch ----------------

extern "C" void kernel_launch(void* const* d_in, const int* in_sizes, int n_in,
                              void* d_out, int out_size, void* d_ws, size_t ws_size,
                              hipStream_t stream) {
    const float* user_emb = (const float*)d_in[0];
    const float* item_emb = (const float*)d_in[1];
    const int*   rows     = (const int*)d_in[2];
    const int*   cols     = (const int*)d_in[3];
    const float* vals     = (const float*)d_in[4];
    float* out = (float*)d_out;

    const size_t nbuf = (size_t)NALL * DIM;            // 9.6M floats = 38.4 MB
    float* W0 = (float*)d_ws;
    float* W1 = W0 + nbuf;
    float* W2 = W1 + nbuf;
    int2*  tmp     = (int2*)W1;                        // alias: dead before propagation
    int2*  sedges  = (int2*)(W2 + nbuf);               // NE * 8 B
    int*   row_ptr = (int*)(sedges + NE);              // NALL+1
    int*   bcnt    = row_ptr + (NALL + 1);             // NBUCK
    int*   bptr    = bcnt + NBUCK;                     // NBUCK+1
    int*   bfill   = bptr + (NBUCK + 1);               // NBUCK
    char*  pHA     = (char*)(bfill + NBUCK);
    pHA = (char*)(((uintptr_t)pHA + 255) & ~(uintptr_t)255);   // 256B-align mirrors
    __half* HA     = (__half*)pHA;                     // fp16 mirror A (nbuf halves)
    __half* HB     = HA + nbuf;                        // fp16 mirror B
    size_t need_basic = (size_t)((char*)HA - (char*)d_ws);
    size_t need_full  = (size_t)((char*)(HB + nbuf) - (char*)d_ws);

    // Jacobi coefficients (A=B=1 here, computed generically)
    const double A = 1.0, B = 1.0, ab = A + B;
    float c0 = (float)((A - B) / 2.0);
    float c1 = (float)((A + B) / 2.0);
    float th1[4], th2[4], th3[4];
    for (int k = 2; k <= 3; k++) {
        th1[k] = (float)((2.0*k+ab)*(2.0*k+ab-1.0)/((k+ab)*2.0*k));
        th2[k] = (float)((2.0*k+ab-1.0)*(A*A-B*B)/((2.0*k+ab-2.0)*(k+ab)*2.0*k));
        th3[k] = (float)((k+A-1.0)*(k+B-1.0)*(2.0*k+ab)/(k*(ab+k)*(2.0*k+ab-2.0)));
    }

    const int total = NALL * DIM;
    const int total4 = NALL * 16;
    dim3 blk(256);
    dim3 grdE((total + 255) / 256);
    dim3 grd4((total4 + 255) / 256);                   // float4-vectorized elementwise
    dim3 grdBin((NE + CHUNK - 1) / CHUNK);             // 1172
    dim3 grdBuck(NBUCK);                               // 1172
    dim3 grdRow((NALL * 64 + 255) / 256);              // wave-per-row

    const float4* u4  = (const float4*)user_emb;
    const float4* it4 = (const float4*)item_emb;

    if (ws_size >= need_basic) {
        // ---- edge sort ----
        hipMemsetAsync(bcnt, 0, NBUCK * sizeof(int), stream);
        hipMemsetAsync(bfill, 0, NBUCK * sizeof(int), stream);
        bucket_hist_kernel<<<grdBin, blk, 0, stream>>>(rows, bcnt);
        bucket_scan_kernel<<<1, 1024, 0, stream>>>(bcnt, bptr);
        binned_scatter_kernel<<<grdBin, blk, 0, stream>>>(rows, cols, vals, bptr, bfill, tmp);
        bucket_sort_kernel<<<grdBuck, blk, 0, stream>>>(bptr, tmp, sedges, row_ptr);

        if (ws_size >= need_full) {
            // ---- fp16-gather path, 8-edges-per-instruction, deferred band-stop ----
            concat_init_kernel<<<grd4, blk, 0, stream>>>(u4, it4, (float4*)W0, (uint2*)HA, nullptr);
            spmm8_combine_f16_kernel<<<grdRow, blk, 0, stream>>>(row_ptr, sedges, HA, W0, W0,
                                                                 c1, c0, 0.0f, W1, HB);
            spmm8_combine_f16_kernel<<<grdRow, blk, 0, stream>>>(row_ptr, sedges, HB, W1, W0,
                                                                 th1[2], th2[2], th3[2], W2, HA);
            spmm8_combine_f16_kernel<<<grdRow, blk, 0, stream>>>(row_ptr, sedges, HA, W2, W1,
                                                                 th1[3], th2[3], th3[3], W0, nullptr);
            finalize_split_kernel<<<grd4, blk, 0, stream>>>(u4, it4, (const float4*)W1,
                                                            (const float4*)W2, (const float4*)W0,
                                                            (float4*)out);
        } else {
            // ---- exact fp32-gather path (legacy accumulate-into-out) ----
            concat_init_kernel<<<grd4, blk, 0, stream>>>(u4, it4, (float4*)W0, nullptr, (float4*)out);
            spmm_combine_kernel<<<grdRow, blk, 0, stream>>>(row_ptr, sedges, W0, W0, W0,
                                                            c1, c0, 0.0f, W1, out);
            spmm_combine_kernel<<<grdRow, blk, 0, stream>>>(row_ptr, sedges, W1, W1, W0,
                                                            th1[2], th2[2], th3[2], W2, out);
            spmm_combine_kernel<<<grdRow, blk, 0, stream>>>(row_ptr, sedges, W2, W2, W1,
                                                            th1[3], th2[3], th3[3], W0, out);
            finalize_kernel<<<grdE, blk, 0, stream>>>(user_emb, item_emb, out);
        }
    } else {
        // ---- fallback: atomic path ----
        long long spmm_threads = (long long)NE * 64;
        dim3 grdS((unsigned)((spmm_threads + 255) / 256));
        concat_init_kernel<<<grd4, blk, 0, stream>>>(u4, it4, (float4*)W0, nullptr, (float4*)out);
        hipMemsetAsync(W1, 0, nbuf * sizeof(float), stream);
        spmm_atomic_kernel<<<grdS, blk, 0, stream>>>(rows, cols, vals, W0, W1);
        combine3_kernel<<<grdE, blk, 0, stream>>>(W1, W0, W0, c1, c0, 0.0f, out);
        hipMemsetAsync(W2, 0, nbuf * sizeof(float), stream);
        spmm_atomic_kernel<<<grdS, blk, 0, stream>>>(rows, cols, vals, W1, W2);
        combine3_kernel<<<grdE, blk, 0, stream>>>(W2, W1, W0, th1[2], th2[2], th3[2], out);
        hipMemsetAsync(W0, 0, nbuf * sizeof(float), stream);
        spmm_atomic_kernel<<<grdS, blk, 0, stream>>>(rows, cols, vals, W2, W0);
        combine3_kernel<<<grdE, blk, 0, stream>>>(W0, W2, W1, th1[3], th2[3], th3[3], out);
        finalize_kernel<<<grdE, blk, 0, stream>>>(user_emb, item_emb, out);
    }
}

// Round 9
// 518.720 us; speedup vs baseline: 10.5647x; 1.0984x over previous
//
#include <hip/hip_runtime.h>
#include <hip/hip_fp16.h>
#include <cmath>
#include <cstdint>

#define NU 100000
#define NI 50000
#define NALL 150000
#define DIM 64
#define NE 4800000

#define BSH 7                 // bucket = row >> 7  (128 rows/bucket)
#define BROWS 128
#define NBUCK ((NALL + BROWS - 1) / BROWS)   // 1172
#define EPT 16
#define CHUNK (256 * EPT)     // 4096 edges per binning block
#define COLMASK 0x3FFFF       // 18 bits, NALL < 2^18
#define BCAP 4608             // bucket capacity for staged sort (mean 4096 + 8 sigma)

// ---------------- CSR build ----------------

__global__ void bucket_hist_kernel(const int* __restrict__ rows, int* __restrict__ bcnt) {
    __shared__ int h[NBUCK];
    for (int i = threadIdx.x; i < NBUCK; i += 256) h[i] = 0;
    __syncthreads();
    int base = blockIdx.x * CHUNK;
    #pragma unroll
    for (int i = 0; i < EPT; i++) {
        int e = base + threadIdx.x + i * 256;
        if (e < NE) atomicAdd(&h[rows[e] >> BSH], 1);
    }
    __syncthreads();
    for (int i = threadIdx.x; i < NBUCK; i += 256)
        if (h[i]) atomicAdd(&bcnt[i], h[i]);
}

__global__ void bucket_scan_kernel(const int* __restrict__ bcnt, int* __restrict__ bptr) {
    __shared__ int s[1024];
    int t = threadIdx.x;
    const int chunk = (NBUCK + 1023) / 1024;   // 2
    int lo = t * chunk, hi = lo + chunk;
    if (hi > NBUCK) hi = NBUCK;
    int sum = 0;
    for (int i = lo; i < hi; ++i) sum += bcnt[i];
    s[t] = sum;
    __syncthreads();
    for (int off = 1; off < 1024; off <<= 1) {
        int v = (t >= off) ? s[t - off] : 0;
        __syncthreads();
        s[t] += v;
        __syncthreads();
    }
    int run = s[t] - sum;
    for (int i = lo; i < hi; ++i) { bptr[i] = run; run += bcnt[i]; }
    if (t == 1023) bptr[NBUCK] = s[1023];
}

// LDS-presorted binned scatter. Round-9: bucket-id sidecar replaces the
// 11-step binsearch in the writeout; ldst folded into lcnt (LDS ~51 KB, 3 blk/CU).
__global__ __launch_bounds__(256) void binned_scatter_kernel(
        const int* __restrict__ rows, const int* __restrict__ cols,
        const float* __restrict__ vals, const int* __restrict__ bptr,
        int* __restrict__ bfill, int2* __restrict__ tmp) {
    __shared__ int2 eLDS[CHUNK];             // 32 KB
    __shared__ unsigned short bLDS[CHUNK];   // 8 KB bucket-id sidecar
    __shared__ int lcnt[NBUCK];              // ranks, then writeout delta (ldst)
    __shared__ int lofs[NBUCK + 1];
    __shared__ int psum[256];
    int t = threadIdx.x;
    int base = blockIdx.x * CHUNK;
    int cnt = NE - base; if (cnt > CHUNK) cnt = CHUNK;
    for (int i = t; i < NBUCK; i += 256) lcnt[i] = 0;
    __syncthreads();
    int2 ed[EPT]; int mcb[EPT]; int mrk[EPT];
    #pragma unroll
    for (int k = 0; k < EPT; k++) {
        int p = t + k * 256;
        mcb[k] = -1;
        if (p < cnt) {
            int e = base + p;
            int r = rows[e];
            int cb = r >> BSH;
            mcb[k] = cb;
            mrk[k] = atomicAdd(&lcnt[cb], 1);
            ed[k] = make_int2(((r & (BROWS - 1)) << 18) | cols[e], __float_as_int(vals[e]));
        }
    }
    __syncthreads();
    // exclusive scan of lcnt into lofs
    const int cpt = (NBUCK + 255) / 256;   // 5
    int lo = t * cpt, hi = lo + cpt;
    if (hi > NBUCK) hi = NBUCK;
    int s = 0;
    for (int i = lo; i < hi; ++i) s += lcnt[i];
    psum[t] = s;
    __syncthreads();
    for (int off = 1; off < 256; off <<= 1) {
        int v = (t >= off) ? psum[t - off] : 0;
        __syncthreads();
        psum[t] += v;
        __syncthreads();
    }
    int run = psum[t] - s;
    for (int i = lo; i < hi; ++i) { lofs[i] = run; run += lcnt[i]; }
    if (t == 255) lofs[NBUCK] = cnt;
    __syncthreads();
    // reserve global space per bucket; overwrite lcnt with (global_base - local_base)
    for (int i = t; i < NBUCK; i += 256) {
        int c = lcnt[i];
        int g = c ? atomicAdd(&bfill[i], c) : 0;
        lcnt[i] = bptr[i] + g - lofs[i];
    }
    // LDS scatter (bucket-sorted order) + sidecar
    #pragma unroll
    for (int k = 0; k < EPT; k++)
        if (mcb[k] >= 0) {
            int pos = lofs[mcb[k]] + mrk[k];
            eLDS[pos] = ed[k];
            bLDS[pos] = (unsigned short)mcb[k];
        }
    __syncthreads();
    // sequential writeout: direct bucket lookup, no binsearch
    for (int p = t; p < cnt; p += 256)
        tmp[lcnt[bLDS[p]] + p] = eLDS[p];
}

__global__ __launch_bounds__(256) void bucket_sort_kernel(
        const int* __restrict__ bptr, const int2* __restrict__ tmp,
        int2* __restrict__ sedges, int* __restrict__ row_ptr) {
    __shared__ int2 eLDS[BCAP];           // 36.9 KB
    __shared__ int h[BROWS], sc[BROWS], f[BROWS];
    int b = blockIdx.x, t = threadIdx.x;
    int s0 = bptr[b], s1 = bptr[b + 1];
    int cnt = s1 - s0;
    if (t < BROWS) { h[t] = 0; f[t] = 0; }
    if (b == NBUCK - 1 && t == 0) row_ptr[NALL] = s1;
    __syncthreads();
    if (cnt <= BCAP) {
        int2 ed[18]; int mrl[18]; int mrk[18];
        #pragma unroll
        for (int k = 0; k < 18; k++) {
            int p = t + k * 256;
            mrl[k] = -1;
            if (p < cnt) {
                int2 E = tmp[s0 + p];
                int rl = E.x >> 18;
                mrl[k] = rl;
                mrk[k] = atomicAdd(&h[rl], 1);
                ed[k] = E;
            }
        }
        __syncthreads();
        if (t < BROWS) sc[t] = h[t];
        __syncthreads();
        for (int off = 1; off < BROWS; off <<= 1) {
            int v = 0;
            if (t < BROWS && t >= off) v = sc[t - off];
            __syncthreads();
            if (t < BROWS) sc[t] += v;
            __syncthreads();
        }
        if (t < BROWS) {
            int row = b * BROWS + t;
            if (row < NALL) row_ptr[row] = s0 + sc[t] - h[t];
        }
        __syncthreads();
        #pragma unroll
        for (int k = 0; k < 18; k++)
            if (mrl[k] >= 0) eLDS[sc[mrl[k]] - h[mrl[k]] + mrk[k]] = ed[k];
        __syncthreads();
        for (int p = t; p < cnt; p += 256) sedges[s0 + p] = eLDS[p];
    } else {
        for (int i = s0 + t; i < s1; i += 256) atomicAdd(&h[tmp[i].x >> 18], 1);
        __syncthreads();
        if (t < BROWS) sc[t] = h[t];
        __syncthreads();
        for (int off = 1; off < BROWS; off <<= 1) {
            int v = 0;
            if (t < BROWS && t >= off) v = sc[t - off];
            __syncthreads();
            if (t < BROWS) sc[t] += v;
            __syncthreads();
        }
        if (t < BROWS) {
            int row = b * BROWS + t;
            if (row < NALL) row_ptr[row] = s0 + sc[t] - h[t];
        }
        __syncthreads();
        for (int i = s0 + t; i < s1; i += 256) {
            int2 E = tmp[i];
            int rl = E.x >> 18;
            int r = atomicAdd(&f[rl], 1);
            sedges[s0 + sc[rl] - h[rl] + r] = E;
        }
    }
}

// ---------------- embedding passes ----------------

__global__ void concat_init_kernel(const float4* __restrict__ u4, const float4* __restrict__ it4,
                                   float4* __restrict__ w0, uint2* __restrict__ w0h,
                                   float4* __restrict__ out4) {
    int idx = blockIdx.x * blockDim.x + threadIdx.x;
    const int total4 = NALL * 16;
    if (idx >= total4) return;
    const int nu4 = NU * 16;
    float4 v = (idx < nu4) ? u4[idx] : it4[idx - nu4];
    w0[idx] = v;
    if (w0h) {
        __half2 a = __floats2half2_rn(v.x, v.y), b = __floats2half2_rn(v.z, v.w);
        w0h[idx] = make_uint2(*(unsigned*)&a, *(unsigned*)&b);
    }
    if (out4) {
        int row = idx >> 4, q = idx & 15;
        out4[(size_t)row * 32 + q] = v;
    }
}

__device__ __forceinline__ void fma_h8(float* acc, uint4 p, float v) {
    __half2* h = (__half2*)&p;
    #pragma unroll
    for (int j = 0; j < 4; j++) {
        float2 f = __half22float2(h[j]);
        acc[2 * j]     += v * f.x;
        acc[2 * j + 1] += v * f.y;
    }
}

// Wave-per-row; 8 x 8-lane groups, each lane loads 16B -> one gather instruction
// covers 8 edges' full 128B rows. Unroll 4 => 32 edges/iter, 4 gathers in flight.
// Jacobi terms with exactly-zero coefficients are skipped (uniform branch).
__global__ __launch_bounds__(256) void spmm8_combine_f16_kernel(
        const int* __restrict__ row_ptr, const int2* __restrict__ sedges,
        const __half* __restrict__ xh,
        const float* __restrict__ ekm1, const float* __restrict__ ekm2,
        float t1, float t2, float t3,
        float* __restrict__ ek_out, __half* __restrict__ ekh_out) {
    int wid = (blockIdx.x * blockDim.x + threadIdx.x) >> 6;
    if (wid >= NALL) return;
    int lane = threadIdx.x & 63;
    int g = lane >> 3, l8 = lane & 7;
    int s = row_ptr[wid], e = row_ptr[wid + 1];
    const uint4* xv = (const uint4*)xh;          // 16B units; one row = 8 uint4
    float acc[8];
    #pragma unroll
    for (int j = 0; j < 8; j++) acc[j] = 0.f;
    int i = s + g;
    for (; i + 24 < e; i += 32) {
        int2 e0 = sedges[i],      e1 = sedges[i + 8];
        int2 e2 = sedges[i + 16], e3 = sedges[i + 24];
        uint4 p0 = xv[(size_t)(e0.x & COLMASK) * 8 + l8];
        uint4 p1 = xv[(size_t)(e1.x & COLMASK) * 8 + l8];
        uint4 p2 = xv[(size_t)(e2.x & COLMASK) * 8 + l8];
        uint4 p3 = xv[(size_t)(e3.x & COLMASK) * 8 + l8];
        fma_h8(acc, p0, __int_as_float(e0.y));
        fma_h8(acc, p1, __int_as_float(e1.y));
        fma_h8(acc, p2, __int_as_float(e2.y));
        fma_h8(acc, p3, __int_as_float(e3.y));
    }
    for (; i < e; i += 8) {
        int2 e0 = sedges[i];
        uint4 p0 = xv[(size_t)(e0.x & COLMASK) * 8 + l8];
        fma_h8(acc, p0, __int_as_float(e0.y));
    }
    #pragma unroll
    for (int off = 8; off < 64; off <<= 1) {
        #pragma unroll
        for (int j = 0; j < 8; j++) acc[j] += __shfl_xor(acc[j], off);
    }
    if (g == 0) {
        size_t o4 = (size_t)wid * 16 + l8 * 2;   // float4 index; lane covers dims [l8*8, l8*8+8)
        float4 ea, eb;
        ea.x = t1 * acc[0]; ea.y = t1 * acc[1]; ea.z = t1 * acc[2]; ea.w = t1 * acc[3];
        eb.x = t1 * acc[4]; eb.y = t1 * acc[5]; eb.z = t1 * acc[6]; eb.w = t1 * acc[7];
        if (t2 != 0.f) {                         // uniform; dead load skipped when A==B
            float4 m1a = ((const float4*)ekm1)[o4], m1b = ((const float4*)ekm1)[o4 + 1];
            ea.x += t2 * m1a.x; ea.y += t2 * m1a.y; ea.z += t2 * m1a.z; ea.w += t2 * m1a.w;
            eb.x += t2 * m1b.x; eb.y += t2 * m1b.y; eb.z += t2 * m1b.z; eb.w += t2 * m1b.w;
        }
        if (t3 != 0.f) {
            float4 m2a = ((const float4*)ekm2)[o4], m2b = ((const float4*)ekm2)[o4 + 1];
            ea.x -= t3 * m2a.x; ea.y -= t3 * m2a.y; ea.z -= t3 * m2a.z; ea.w -= t3 * m2a.w;
            eb.x -= t3 * m2b.x; eb.y -= t3 * m2b.y; eb.z -= t3 * m2b.z; eb.w -= t3 * m2b.w;
        }
        ((float4*)ek_out)[o4] = ea;
        ((float4*)ek_out)[o4 + 1] = eb;
        if (ekh_out) {
            __half2 h0 = __floats2half2_rn(ea.x, ea.y);
            __half2 h1 = __floats2half2_rn(ea.z, ea.w);
            __half2 h2 = __floats2half2_rn(eb.x, eb.y);
            __half2 h3 = __floats2half2_rn(eb.z, eb.w);
            uint4 ph;
            ph.x = *(unsigned*)&h0; ph.y = *(unsigned*)&h1;
            ph.z = *(unsigned*)&h2; ph.w = *(unsigned*)&h3;
            ((uint4*)ekh_out)[(size_t)wid * 8 + l8] = ph;
        }
    }
}

// Main-path finalize: bs = (e0+e1+e2+e3)/4 from fp32 buffers; bp = tanh(0.1*e0 - bs).
__global__ void finalize_split_kernel(const float4* __restrict__ u4, const float4* __restrict__ it4,
                                      const float4* __restrict__ e1, const float4* __restrict__ e2,
                                      const float4* __restrict__ e3, float4* __restrict__ out4) {
    int idx = blockIdx.x * blockDim.x + threadIdx.x;
    const int total4 = NALL * 16;
    if (idx >= total4) return;
    const int nu4 = NU * 16;
    float4 v = (idx < nu4) ? u4[idx] : it4[idx - nu4];
    float4 a = e1[idx], b = e2[idx], c = e3[idx];
    float4 bs, bp;
    bs.x = 0.25f * (v.x + a.x + b.x + c.x);
    bs.y = 0.25f * (v.y + a.y + b.y + c.y);
    bs.z = 0.25f * (v.z + a.z + b.z + c.z);
    bs.w = 0.25f * (v.w + a.w + b.w + c.w);
    bp.x = tanhf(0.1f * v.x - bs.x);
    bp.y = tanhf(0.1f * v.y - bs.y);
    bp.z = tanhf(0.1f * v.z - bs.z);
    bp.w = tanhf(0.1f * v.w - bs.w);
    int row = idx >> 4, q = idx & 15;
    out4[(size_t)row * 32 + q] = bs;
    out4[(size_t)row * 32 + 16 + q] = bp;
}

// ---------------- fallback kernels (ws-constrained paths) ----------------

__global__ void spmm_combine_kernel(const int* __restrict__ row_ptr,
                                    const int2* __restrict__ sedges,
                                    const float* __restrict__ x,
                                    const float* __restrict__ ekm1,
                                    const float* __restrict__ ekm2,
                                    float t1, float t2, float t3,
                                    float* __restrict__ ek_out,
                                    float* __restrict__ out) {
    int wid = (blockIdx.x * blockDim.x + threadIdx.x) >> 6;
    if (wid >= NALL) return;
    int lane = threadIdx.x & 63;
    int s = row_ptr[wid], e = row_ptr[wid + 1];
    float acc = 0.f;
    int i = s;
    for (; i + 4 <= e; i += 4) {
        int2 ea = sedges[i], eb = sedges[i + 1], ec = sedges[i + 2], ed = sedges[i + 3];
        acc += __int_as_float(ea.y) * x[(size_t)(ea.x & COLMASK) * DIM + lane];
        acc += __int_as_float(eb.y) * x[(size_t)(eb.x & COLMASK) * DIM + lane];
        acc += __int_as_float(ec.y) * x[(size_t)(ec.x & COLMASK) * DIM + lane];
        acc += __int_as_float(ed.y) * x[(size_t)(ed.x & COLMASK) * DIM + lane];
    }
    for (; i < e; ++i) {
        int2 ed = sedges[i];
        acc += __int_as_float(ed.y) * x[(size_t)(ed.x & COLMASK) * DIM + lane];
    }
    size_t o = (size_t)wid * DIM + lane;
    float ek = t1 * acc + t2 * ekm1[o] - t3 * ekm2[o];
    ek_out[o] = ek;
    out[(size_t)wid * 128 + lane] += ek;
}

__global__ void finalize_kernel(const float* __restrict__ u, const float* __restrict__ it,
                                float* __restrict__ out) {
    int idx = blockIdx.x * blockDim.x + threadIdx.x;
    const int total = NALL * DIM;
    if (idx >= total) return;
    const int nue = NU * DIM;
    float v = (idx < nue) ? u[idx] : it[idx - nue];
    int row = idx >> 6, d = idx & 63;
    size_t o = (size_t)row * 128 + d;
    float bs = out[o] * 0.25f;
    float bp = tanhf(0.1f * v - bs);
    out[o] = bs;
    out[o + DIM] = bp;
}

__global__ void spmm_atomic_kernel(const int* __restrict__ rows, const int* __restrict__ cols,
                                   const float* __restrict__ vals, const float* __restrict__ x,
                                   float* __restrict__ y) {
    int gid = blockIdx.x * blockDim.x + threadIdx.x;
    int e = gid >> 6;
    if (e >= NE) return;
    int lane = threadIdx.x & 63;
    atomicAdd(&y[(size_t)rows[e] * DIM + lane], vals[e] * x[(size_t)cols[e] * DIM + lane]);
}

__global__ void combine3_kernel(float* __restrict__ t, const float* __restrict__ ekm1,
                                const float* __restrict__ ekm2, float t1, float t2, float t3,
                                float* __restrict__ out) {
    int idx = blockIdx.x * blockDim.x + threadIdx.x;
    const int total = NALL * DIM;
    if (idx >= total) return;
    float ek = t1 * t[idx] + t2 * ekm1[idx] - t3 * ekm2[idx];
    t[idx] = ek;
    int row = idx >> 6, d = idx & 63;
    out[(size_t)row * 128 + d] += ek;
}

// ---------------- launch ----------------

extern "C" void kernel_launch(void* const* d_in, const int* in_sizes, int n_in,
                              void* d_out, int out_size, void* d_ws, size_t ws_size,
                              hipStream_t stream) {
    const float* user_emb = (const float*)d_in[0];
    const float* item_emb = (const float*)d_in[1];
    const int*   rows     = (const int*)d_in[2];
    const int*   cols     = (const int*)d_in[3];
    const float* vals     = (const float*)d_in[4];
    float* out = (float*)d_out;

    const size_t nbuf = (size_t)NALL * DIM;            // 9.6M floats = 38.4 MB
    float* W0 = (float*)d_ws;
    float* W1 = W0 + nbuf;
    float* W2 = W1 + nbuf;
    int2*  tmp     = (int2*)W1;                        // alias: dead before propagation
    int2*  sedges  = (int2*)(W2 + nbuf);               // NE * 8 B
    int*   row_ptr = (int*)(sedges + NE);              // NALL+1
    int*   bcnt    = row_ptr + (NALL + 1);             // NBUCK
    int*   bptr    = bcnt + NBUCK;                     // NBUCK+1
    int*   bfill   = bptr + (NBUCK + 1);               // NBUCK
    char*  pHA     = (char*)(bfill + NBUCK);
    pHA = (char*)(((uintptr_t)pHA + 255) & ~(uintptr_t)255);   // 256B-align mirrors
    __half* HA     = (__half*)pHA;                     // fp16 mirror A (nbuf halves)
    __half* HB     = HA + nbuf;                        // fp16 mirror B
    size_t need_basic = (size_t)((char*)HA - (char*)d_ws);
    size_t need_full  = (size_t)((char*)(HB + nbuf) - (char*)d_ws);

    // Jacobi coefficients (A=B=1 here, computed generically)
    const double A = 1.0, B = 1.0, ab = A + B;
    float c0 = (float)((A - B) / 2.0);
    float c1 = (float)((A + B) / 2.0);
    float th1[4], th2[4], th3[4];
    for (int k = 2; k <= 3; k++) {
        th1[k] = (float)((2.0*k+ab)*(2.0*k+ab-1.0)/((k+ab)*2.0*k));
        th2[k] = (float)((2.0*k+ab-1.0)*(A*A-B*B)/((2.0*k+ab-2.0)*(k+ab)*2.0*k));
        th3[k] = (float)((k+A-1.0)*(k+B-1.0)*(2.0*k+ab)/(k*(ab+k)*(2.0*k+ab-2.0)));
    }

    const int total = NALL * DIM;
    const int total4 = NALL * 16;
    dim3 blk(256);
    dim3 grdE((total + 255) / 256);
    dim3 grd4((total4 + 255) / 256);                   // float4-vectorized elementwise
    dim3 grdBin((NE + CHUNK - 1) / CHUNK);             // 1172
    dim3 grdBuck(NBUCK);                               // 1172
    dim3 grdRow((NALL * 64 + 255) / 256);              // wave-per-row

    const float4* u4  = (const float4*)user_emb;
    const float4* it4 = (const float4*)item_emb;

    if (ws_size >= need_basic) {
        // ---- edge sort ----
        hipMemsetAsync(bcnt, 0, NBUCK * sizeof(int), stream);
        hipMemsetAsync(bfill, 0, NBUCK * sizeof(int), stream);
        bucket_hist_kernel<<<grdBin, blk, 0, stream>>>(rows, bcnt);
        bucket_scan_kernel<<<1, 1024, 0, stream>>>(bcnt, bptr);
        binned_scatter_kernel<<<grdBin, blk, 0, stream>>>(rows, cols, vals, bptr, bfill, tmp);
        bucket_sort_kernel<<<grdBuck, blk, 0, stream>>>(bptr, tmp, sedges, row_ptr);

        if (ws_size >= need_full) {
            // ---- fp16-gather path, 8-edges-per-instruction, deferred band-stop ----
            concat_init_kernel<<<grd4, blk, 0, stream>>>(u4, it4, (float4*)W0, (uint2*)HA, nullptr);
            spmm8_combine_f16_kernel<<<grdRow, blk, 0, stream>>>(row_ptr, sedges, HA, W0, W0,
                                                                 c1, c0, 0.0f, W1, HB);
            spmm8_combine_f16_kernel<<<grdRow, blk, 0, stream>>>(row_ptr, sedges, HB, W1, W0,
                                                                 th1[2], th2[2], th3[2], W2, HA);
            spmm8_combine_f16_kernel<<<grdRow, blk, 0, stream>>>(row_ptr, sedges, HA, W2, W1,
                                                                 th1[3], th2[3], th3[3], W0, nullptr);
            finalize_split_kernel<<<grd4, blk, 0, stream>>>(u4, it4, (const float4*)W1,
                                                            (const float4*)W2, (const float4*)W0,
                                                            (float4*)out);
        } else {
            // ---- exact fp32-gather path (legacy accumulate-into-out) ----
            concat_init_kernel<<<grd4, blk, 0, stream>>>(u4, it4, (float4*)W0, nullptr, (float4*)out);
            spmm_combine_kernel<<<grdRow, blk, 0, stream>>>(row_ptr, sedges, W0, W0, W0,
                                                            c1, c0, 0.0f, W1, out);
            spmm_combine_kernel<<<grdRow, blk, 0, stream>>>(row_ptr, sedges, W1, W1, W0,
                                                            th1[2], th2[2], th3[2], W2, out);
            spmm_combine_kernel<<<grdRow, blk, 0, stream>>>(row_ptr, sedges, W2, W2, W1,
                                                            th1[3], th2[3], th3[3], W0, out);
            finalize_kernel<<<grdE, blk, 0, stream>>>(user_emb, item_emb, out);
        }
    } else {
        // ---- fallback: atomic path ----
        long long spmm_threads = (long long)NE * 64;
        dim3 grdS((unsigned)((spmm_threads + 255) / 256));
        concat_init_kernel<<<grd4, blk, 0, stream>>>(u4, it4, (float4*)W0, nullptr, (float4*)out);
        hipMemsetAsync(W1, 0, nbuf * sizeof(float), stream);
        spmm_atomic_kernel<<<grdS, blk, 0, stream>>>(rows, cols, vals, W0, W1);
        combine3_kernel<<<grdE, blk, 0, stream>>>(W1, W0, W0, c1, c0, 0.0f, out);
        hipMemsetAsync(W2, 0, nbuf * sizeof(float), stream);
        spmm_atomic_kernel<<<grdS, blk, 0, stream>>>(rows, cols, vals, W1, W2);
        combine3_kernel<<<grdE, blk, 0, stream>>>(W2, W1, W0, th1[2], th2[2], th3[2], out);
        hipMemsetAsync(W0, 0, nbuf * sizeof(float), stream);
        spmm_atomic_kernel<<<grdS, blk, 0, stream>>>(rows, cols, vals, W2, W0);
        combine3_kernel<<<grdE, blk, 0, stream>>>(W0, W2, W1, th1[3], th2[3], th3[3], out);
        finalize_kernel<<<grdE, blk, 0, stream>>>(user_emb, item_emb, out);
    }
}

// Round 10
// 501.045 us; speedup vs baseline: 10.9373x; 1.0353x over previous
//
#include <hip/hip_runtime.h>
#include <hip/hip_fp16.h>
#include <cmath>
#include <cstdint>

#define NU 100000
#define NI 50000
#define NALL 150000
#define DIM 64
#define NE 4800000

#define BSH 7                 // bucket = row >> 7  (128 rows/bucket)
#define BROWS 128
#define NBUCK ((NALL + BROWS - 1) / BROWS)   // 1172
#define SBT 512               // sort-kernel block threads
#define EPT 8                 // edges per thread (512 * 8 = 4096 per block)
#define CHUNK (SBT * EPT)     // 4096 edges per binning block
#define COLMASK 0x3FFFF       // 18 bits, NALL < 2^18
#define BCAP 4608             // bucket capacity for staged sort (mean 4096 + 8 sigma)
#define SPT 9                 // staged regs per thread in bucket_sort (512*9=4608)

// ---------------- CSR build ----------------

__global__ __launch_bounds__(SBT) void bucket_hist_kernel(
        const int* __restrict__ rows, int* __restrict__ bcnt) {
    __shared__ int h[NBUCK];
    for (int i = threadIdx.x; i < NBUCK; i += SBT) h[i] = 0;
    __syncthreads();
    int base = blockIdx.x * CHUNK;
    #pragma unroll
    for (int i = 0; i < EPT; i++) {
        int e = base + threadIdx.x + i * SBT;
        if (e < NE) atomicAdd(&h[rows[e] >> BSH], 1);
    }
    __syncthreads();
    for (int i = threadIdx.x; i < NBUCK; i += SBT)
        if (h[i]) atomicAdd(&bcnt[i], h[i]);
}

__global__ void bucket_scan_kernel(const int* __restrict__ bcnt, int* __restrict__ bptr) {
    __shared__ int s[1024];
    int t = threadIdx.x;
    const int chunk = (NBUCK + 1023) / 1024;   // 2
    int lo = t * chunk, hi = lo + chunk;
    if (hi > NBUCK) hi = NBUCK;
    int sum = 0;
    for (int i = lo; i < hi; ++i) sum += bcnt[i];
    s[t] = sum;
    __syncthreads();
    for (int off = 1; off < 1024; off <<= 1) {
        int v = (t >= off) ? s[t - off] : 0;
        __syncthreads();
        s[t] += v;
        __syncthreads();
    }
    int run = s[t] - sum;
    for (int i = lo; i < hi; ++i) { bptr[i] = run; run += bcnt[i]; }
    if (t == 1023) bptr[NBUCK] = s[1023];
}

// LDS-presorted binned scatter; 512-thread blocks for occupancy (24 waves/CU @ 51KB LDS).
__global__ __launch_bounds__(SBT, 6) void binned_scatter_kernel(
        const int* __restrict__ rows, const int* __restrict__ cols,
        const float* __restrict__ vals, const int* __restrict__ bptr,
        int* __restrict__ bfill, int2* __restrict__ tmp) {
    __shared__ int2 eLDS[CHUNK];             // 32 KB
    __shared__ unsigned short bLDS[CHUNK];   // 8 KB bucket-id sidecar
    __shared__ int lcnt[NBUCK];              // ranks, then writeout delta (ldst)
    __shared__ int lofs[NBUCK + 1];
    __shared__ int psum[SBT];
    int t = threadIdx.x;
    int base = blockIdx.x * CHUNK;
    int cnt = NE - base; if (cnt > CHUNK) cnt = CHUNK;
    for (int i = t; i < NBUCK; i += SBT) lcnt[i] = 0;
    __syncthreads();
    int2 ed[EPT]; int mcb[EPT]; int mrk[EPT];
    #pragma unroll
    for (int k = 0; k < EPT; k++) {
        int p = t + k * SBT;
        mcb[k] = -1;
        if (p < cnt) {
            int e = base + p;
            int r = rows[e];
            int cb = r >> BSH;
            mcb[k] = cb;
            mrk[k] = atomicAdd(&lcnt[cb], 1);
            ed[k] = make_int2(((r & (BROWS - 1)) << 18) | cols[e], __float_as_int(vals[e]));
        }
    }
    __syncthreads();
    // exclusive scan of lcnt into lofs
    const int cpt = (NBUCK + SBT - 1) / SBT;   // 3
    int lo = t * cpt, hi = lo + cpt;
    if (lo > NBUCK) lo = NBUCK;
    if (hi > NBUCK) hi = NBUCK;
    int s = 0;
    for (int i = lo; i < hi; ++i) s += lcnt[i];
    psum[t] = s;
    __syncthreads();
    for (int off = 1; off < SBT; off <<= 1) {
        int v = (t >= off) ? psum[t - off] : 0;
        __syncthreads();
        psum[t] += v;
        __syncthreads();
    }
    int run = psum[t] - s;
    for (int i = lo; i < hi; ++i) { lofs[i] = run; run += lcnt[i]; }
    if (t == SBT - 1) lofs[NBUCK] = cnt;
    __syncthreads();
    // reserve global space per bucket; overwrite lcnt with (global_base - local_base)
    for (int i = t; i < NBUCK; i += SBT) {
        int c = lcnt[i];
        int g = c ? atomicAdd(&bfill[i], c) : 0;
        lcnt[i] = bptr[i] + g - lofs[i];
    }
    // LDS scatter (bucket-sorted order) + sidecar
    #pragma unroll
    for (int k = 0; k < EPT; k++)
        if (mcb[k] >= 0) {
            int pos = lofs[mcb[k]] + mrk[k];
            eLDS[pos] = ed[k];
            bLDS[pos] = (unsigned short)mcb[k];
        }
    __syncthreads();
    // sequential writeout: direct bucket lookup
    for (int p = t; p < cnt; p += SBT)
        tmp[lcnt[bLDS[p]] + p] = eLDS[p];
}

// Staged within-bucket counting sort; 512-thread blocks (up to 32 waves/CU @ 38KB LDS).
__global__ __launch_bounds__(SBT, 6) void bucket_sort_kernel(
        const int* __restrict__ bptr, const int2* __restrict__ tmp,
        int2* __restrict__ sedges, int* __restrict__ row_ptr) {
    __shared__ int2 eLDS[BCAP];           // 36.9 KB
    __shared__ int h[BROWS], sc[BROWS], f[BROWS];
    int b = blockIdx.x, t = threadIdx.x;
    int s0 = bptr[b], s1 = bptr[b + 1];
    int cnt = s1 - s0;
    if (t < BROWS) { h[t] = 0; f[t] = 0; }
    if (b == NBUCK - 1 && t == 0) row_ptr[NALL] = s1;
    __syncthreads();
    if (cnt <= BCAP) {
        int2 ed[SPT]; int mrl[SPT]; int mrk[SPT];
        #pragma unroll
        for (int k = 0; k < SPT; k++) {
            int p = t + k * SBT;
            mrl[k] = -1;
            if (p < cnt) {
                int2 E = tmp[s0 + p];
                int rl = E.x >> 18;
                mrl[k] = rl;
                mrk[k] = atomicAdd(&h[rl], 1);
                ed[k] = E;
            }
        }
        __syncthreads();
        if (t < BROWS) sc[t] = h[t];
        __syncthreads();
        for (int off = 1; off < BROWS; off <<= 1) {
            int v = 0;
            if (t < BROWS && t >= off) v = sc[t - off];
            __syncthreads();
            if (t < BROWS) sc[t] += v;
            __syncthreads();
        }
        if (t < BROWS) {
            int row = b * BROWS + t;
            if (row < NALL) row_ptr[row] = s0 + sc[t] - h[t];
        }
        __syncthreads();
        #pragma unroll
        for (int k = 0; k < SPT; k++)
            if (mrl[k] >= 0) eLDS[sc[mrl[k]] - h[mrl[k]] + mrk[k]] = ed[k];
        __syncthreads();
        for (int p = t; p < cnt; p += SBT) sedges[s0 + p] = eLDS[p];
    } else {
        for (int i = s0 + t; i < s1; i += SBT) atomicAdd(&h[tmp[i].x >> 18], 1);
        __syncthreads();
        if (t < BROWS) sc[t] = h[t];
        __syncthreads();
        for (int off = 1; off < BROWS; off <<= 1) {
            int v = 0;
            if (t < BROWS && t >= off) v = sc[t - off];
            __syncthreads();
            if (t < BROWS) sc[t] += v;
            __syncthreads();
        }
        if (t < BROWS) {
            int row = b * BROWS + t;
            if (row < NALL) row_ptr[row] = s0 + sc[t] - h[t];
        }
        __syncthreads();
        for (int i = s0 + t; i < s1; i += SBT) {
            int2 E = tmp[i];
            int rl = E.x >> 18;
            int r = atomicAdd(&f[rl], 1);
            sedges[s0 + sc[rl] - h[rl] + r] = E;
        }
    }
}

// ---------------- embedding passes ----------------

__global__ void concat_init_kernel(const float4* __restrict__ u4, const float4* __restrict__ it4,
                                   float4* __restrict__ w0, uint2* __restrict__ w0h,
                                   float4* __restrict__ out4) {
    int idx = blockIdx.x * blockDim.x + threadIdx.x;
    const int total4 = NALL * 16;
    if (idx >= total4) return;
    const int nu4 = NU * 16;
    float4 v = (idx < nu4) ? u4[idx] : it4[idx - nu4];
    w0[idx] = v;
    if (w0h) {
        __half2 a = __floats2half2_rn(v.x, v.y), b = __floats2half2_rn(v.z, v.w);
        w0h[idx] = make_uint2(*(unsigned*)&a, *(unsigned*)&b);
    }
    if (out4) {
        int row = idx >> 4, q = idx & 15;
        out4[(size_t)row * 32 + q] = v;
    }
}

__device__ __forceinline__ void fma_h8(float* acc, uint4 p, float v) {
    __half2* h = (__half2*)&p;
    #pragma unroll
    for (int j = 0; j < 4; j++) {
        float2 f = __half22float2(h[j]);
        acc[2 * j]     += v * f.x;
        acc[2 * j + 1] += v * f.y;
    }
}

// Wave-per-row; 8 x 8-lane groups, each lane loads 16B -> one gather instruction
// covers 8 edges' full 128B rows. Unroll 4 => 32 edges/iter, 4 gathers in flight.
// Jacobi terms with exactly-zero coefficients are skipped (uniform branch).
__global__ __launch_bounds__(256) void spmm8_combine_f16_kernel(
        const int* __restrict__ row_ptr, const int2* __restrict__ sedges,
        const __half* __restrict__ xh,
        const float* __restrict__ ekm1, const float* __restrict__ ekm2,
        float t1, float t2, float t3,
        float* __restrict__ ek_out, __half* __restrict__ ekh_out) {
    int wid = (blockIdx.x * blockDim.x + threadIdx.x) >> 6;
    if (wid >= NALL) return;
    int lane = threadIdx.x & 63;
    int g = lane >> 3, l8 = lane & 7;
    int s = row_ptr[wid], e = row_ptr[wid + 1];
    const uint4* xv = (const uint4*)xh;          // 16B units; one row = 8 uint4
    float acc[8];
    #pragma unroll
    for (int j = 0; j < 8; j++) acc[j] = 0.f;
    int i = s + g;
    for (; i + 24 < e; i += 32) {
        int2 e0 = sedges[i],      e1 = sedges[i + 8];
        int2 e2 = sedges[i + 16], e3 = sedges[i + 24];
        uint4 p0 = xv[(size_t)(e0.x & COLMASK) * 8 + l8];
        uint4 p1 = xv[(size_t)(e1.x & COLMASK) * 8 + l8];
        uint4 p2 = xv[(size_t)(e2.x & COLMASK) * 8 + l8];
        uint4 p3 = xv[(size_t)(e3.x & COLMASK) * 8 + l8];
        fma_h8(acc, p0, __int_as_float(e0.y));
        fma_h8(acc, p1, __int_as_float(e1.y));
        fma_h8(acc, p2, __int_as_float(e2.y));
        fma_h8(acc, p3, __int_as_float(e3.y));
    }
    for (; i < e; i += 8) {
        int2 e0 = sedges[i];
        uint4 p0 = xv[(size_t)(e0.x & COLMASK) * 8 + l8];
        fma_h8(acc, p0, __int_as_float(e0.y));
    }
    #pragma unroll
    for (int off = 8; off < 64; off <<= 1) {
        #pragma unroll
        for (int j = 0; j < 8; j++) acc[j] += __shfl_xor(acc[j], off);
    }
    if (g == 0) {
        size_t o4 = (size_t)wid * 16 + l8 * 2;   // float4 index; lane covers dims [l8*8, l8*8+8)
        float4 ea, eb;
        ea.x = t1 * acc[0]; ea.y = t1 * acc[1]; ea.z = t1 * acc[2]; ea.w = t1 * acc[3];
        eb.x = t1 * acc[4]; eb.y = t1 * acc[5]; eb.z = t1 * acc[6]; eb.w = t1 * acc[7];
        if (t2 != 0.f) {                         // uniform; dead load skipped when A==B
            float4 m1a = ((const float4*)ekm1)[o4], m1b = ((const float4*)ekm1)[o4 + 1];
            ea.x += t2 * m1a.x; ea.y += t2 * m1a.y; ea.z += t2 * m1a.z; ea.w += t2 * m1a.w;
            eb.x += t2 * m1b.x; eb.y += t2 * m1b.y; eb.z += t2 * m1b.z; eb.w += t2 * m1b.w;
        }
        if (t3 != 0.f) {
            float4 m2a = ((const float4*)ekm2)[o4], m2b = ((const float4*)ekm2)[o4 + 1];
            ea.x -= t3 * m2a.x; ea.y -= t3 * m2a.y; ea.z -= t3 * m2a.z; ea.w -= t3 * m2a.w;
            eb.x -= t3 * m2b.x; eb.y -= t3 * m2b.y; eb.z -= t3 * m2b.z; eb.w -= t3 * m2b.w;
        }
        ((float4*)ek_out)[o4] = ea;
        ((float4*)ek_out)[o4 + 1] = eb;
        if (ekh_out) {
            __half2 h0 = __floats2half2_rn(ea.x, ea.y);
            __half2 h1 = __floats2half2_rn(ea.z, ea.w);
            __half2 h2 = __floats2half2_rn(eb.x, eb.y);
            __half2 h3 = __floats2half2_rn(eb.z, eb.w);
            uint4 ph;
            ph.x = *(unsigned*)&h0; ph.y = *(unsigned*)&h1;
            ph.z = *(unsigned*)&h2; ph.w = *(unsigned*)&h3;
            ((uint4*)ekh_out)[(size_t)wid * 8 + l8] = ph;
        }
    }
}

// Main-path finalize: bs = (e0+e1+e2+e3)/4 from fp32 buffers; bp = tanh(0.1*e0 - bs).
__global__ void finalize_split_kernel(const float4* __restrict__ u4, const float4* __restrict__ it4,
                                      const float4* __restrict__ e1, const float4* __restrict__ e2,
                                      const float4* __restrict__ e3, float4* __restrict__ out4) {
    int idx = blockIdx.x * blockDim.x + threadIdx.x;
    const int total4 = NALL * 16;
    if (idx >= total4) return;
    const int nu4 = NU * 16;
    float4 v = (idx < nu4) ? u4[idx] : it4[idx - nu4];
    float4 a = e1[idx], b = e2[idx], c = e3[idx];
    float4 bs, bp;
    bs.x = 0.25f * (v.x + a.x + b.x + c.x);
    bs.y = 0.25f * (v.y + a.y + b.y + c.y);
    bs.z = 0.25f * (v.z + a.z + b.z + c.z);
    bs.w = 0.25f * (v.w + a.w + b.w + c.w);
    bp.x = tanhf(0.1f * v.x - bs.x);
    bp.y = tanhf(0.1f * v.y - bs.y);
    bp.z = tanhf(0.1f * v.z - bs.z);
    bp.w = tanhf(0.1f * v.w - bs.w);
    int row = idx >> 4, q = idx & 15;
    out4[(size_t)row * 32 + q] = bs;
    out4[(size_t)row * 32 + 16 + q] = bp;
}

// ---------------- fallback kernels (ws-constrained paths) ----------------

__global__ void spmm_combine_kernel(const int* __restrict__ row_ptr,
                                    const int2* __restrict__ sedges,
                                    const float* __restrict__ x,
                                    const float* __restrict__ ekm1,
                                    const float* __restrict__ ekm2,
                                    float t1, float t2, float t3,
                                    float* __restrict__ ek_out,
                                    float* __restrict__ out) {
    int wid = (blockIdx.x * blockDim.x + threadIdx.x) >> 6;
    if (wid >= NALL) return;
    int lane = threadIdx.x & 63;
    int s = row_ptr[wid], e = row_ptr[wid + 1];
    float acc = 0.f;
    int i = s;
    for (; i + 4 <= e; i += 4) {
        int2 ea = sedges[i], eb = sedges[i + 1], ec = sedges[i + 2], ed = sedges[i + 3];
        acc += __int_as_float(ea.y) * x[(size_t)(ea.x & COLMASK) * DIM + lane];
        acc += __int_as_float(eb.y) * x[(size_t)(eb.x & COLMASK) * DIM + lane];
        acc += __int_as_float(ec.y) * x[(size_t)(ec.x & COLMASK) * DIM + lane];
        acc += __int_as_float(ed.y) * x[(size_t)(ed.x & COLMASK) * DIM + lane];
    }
    for (; i < e; ++i) {
        int2 ed = sedges[i];
        acc += __int_as_float(ed.y) * x[(size_t)(ed.x & COLMASK) * DIM + lane];
    }
    size_t o = (size_t)wid * DIM + lane;
    float ek = t1 * acc + t2 * ekm1[o] - t3 * ekm2[o];
    ek_out[o] = ek;
    out[(size_t)wid * 128 + lane] += ek;
}

__global__ void finalize_kernel(const float* __restrict__ u, const float* __restrict__ it,
                                float* __restrict__ out) {
    int idx = blockIdx.x * blockDim.x + threadIdx.x;
    const int total = NALL * DIM;
    if (idx >= total) return;
    const int nue = NU * DIM;
    float v = (idx < nue) ? u[idx] : it[idx - nue];
    int row = idx >> 6, d = idx & 63;
    size_t o = (size_t)row * 128 + d;
    float bs = out[o] * 0.25f;
    float bp = tanhf(0.1f * v - bs);
    out[o] = bs;
    out[o + DIM] = bp;
}

__global__ void spmm_atomic_kernel(const int* __restrict__ rows, const int* __restrict__ cols,
                                   const float* __restrict__ vals, const float* __restrict__ x,
                                   float* __restrict__ y) {
    int gid = blockIdx.x * blockDim.x + threadIdx.x;
    int e = gid >> 6;
    if (e >= NE) return;
    int lane = threadIdx.x & 63;
    atomicAdd(&y[(size_t)rows[e] * DIM + lane], vals[e] * x[(size_t)cols[e] * DIM + lane]);
}

__global__ void combine3_kernel(float* __restrict__ t, const float* __restrict__ ekm1,
                                const float* __restrict__ ekm2, float t1, float t2, float t3,
                                float* __restrict__ out) {
    int idx = blockIdx.x * blockDim.x + threadIdx.x;
    const int total = NALL * DIM;
    if (idx >= total) return;
    float ek = t1 * t[idx] + t2 * ekm1[idx] - t3 * ekm2[idx];
    t[idx] = ek;
    int row = idx >> 6, d = idx & 63;
    out[(size_t)row * 128 + d] += ek;
}

// ---------------- launch ----------------

extern "C" void kernel_launch(void* const* d_in, const int* in_sizes, int n_in,
                              void* d_out, int out_size, void* d_ws, size_t ws_size,
                              hipStream_t stream) {
    const float* user_emb = (const float*)d_in[0];
    const float* item_emb = (const float*)d_in[1];
    const int*   rows     = (const int*)d_in[2];
    const int*   cols     = (const int*)d_in[3];
    const float* vals     = (const float*)d_in[4];
    float* out = (float*)d_out;

    const size_t nbuf = (size_t)NALL * DIM;            // 9.6M floats = 38.4 MB
    float* W0 = (float*)d_ws;
    float* W1 = W0 + nbuf;
    float* W2 = W1 + nbuf;
    int2*  tmp     = (int2*)W1;                        // alias: dead before propagation
    int2*  sedges  = (int2*)(W2 + nbuf);               // NE * 8 B
    int*   row_ptr = (int*)(sedges + NE);              // NALL+1
    int*   bcnt    = row_ptr + (NALL + 1);             // NBUCK
    int*   bptr    = bcnt + NBUCK;                     // NBUCK+1
    int*   bfill   = bptr + (NBUCK + 1);               // NBUCK
    char*  pHA     = (char*)(bfill + NBUCK);
    pHA = (char*)(((uintptr_t)pHA + 255) & ~(uintptr_t)255);   // 256B-align mirrors
    __half* HA     = (__half*)pHA;                     // fp16 mirror A (nbuf halves)
    __half* HB     = HA + nbuf;                        // fp16 mirror B
    size_t need_basic = (size_t)((char*)HA - (char*)d_ws);
    size_t need_full  = (size_t)((char*)(HB + nbuf) - (char*)d_ws);

    // Jacobi coefficients (A=B=1 here, computed generically)
    const double A = 1.0, B = 1.0, ab = A + B;
    float c0 = (float)((A - B) / 2.0);
    float c1 = (float)((A + B) / 2.0);
    float th1[4], th2[4], th3[4];
    for (int k = 2; k <= 3; k++) {
        th1[k] = (float)((2.0*k+ab)*(2.0*k+ab-1.0)/((k+ab)*2.0*k));
        th2[k] = (float)((2.0*k+ab-1.0)*(A*A-B*B)/((2.0*k+ab-2.0)*(k+ab)*2.0*k));
        th3[k] = (float)((k+A-1.0)*(k+B-1.0)*(2.0*k+ab)/(k*(ab+k)*(2.0*k+ab-2.0)));
    }

    const int total = NALL * DIM;
    const int total4 = NALL * 16;
    dim3 blk(256);
    dim3 sblk(SBT);
    dim3 grdE((total + 255) / 256);
    dim3 grd4((total4 + 255) / 256);                   // float4-vectorized elementwise
    dim3 grdBin((NE + CHUNK - 1) / CHUNK);             // 1172
    dim3 grdBuck(NBUCK);                               // 1172
    dim3 grdRow((NALL * 64 + 255) / 256);              // wave-per-row

    const float4* u4  = (const float4*)user_emb;
    const float4* it4 = (const float4*)item_emb;

    if (ws_size >= need_basic) {
        // ---- edge sort ----
        hipMemsetAsync(bcnt, 0, NBUCK * sizeof(int), stream);
        hipMemsetAsync(bfill, 0, NBUCK * sizeof(int), stream);
        bucket_hist_kernel<<<grdBin, sblk, 0, stream>>>(rows, bcnt);
        bucket_scan_kernel<<<1, 1024, 0, stream>>>(bcnt, bptr);
        binned_scatter_kernel<<<grdBin, sblk, 0, stream>>>(rows, cols, vals, bptr, bfill, tmp);
        bucket_sort_kernel<<<grdBuck, sblk, 0, stream>>>(bptr, tmp, sedges, row_ptr);

        if (ws_size >= need_full) {
            // ---- fp16-gather path, 8-edges-per-instruction, deferred band-stop ----
            concat_init_kernel<<<grd4, blk, 0, stream>>>(u4, it4, (float4*)W0, (uint2*)HA, nullptr);
            spmm8_combine_f16_kernel<<<grdRow, blk, 0, stream>>>(row_ptr, sedges, HA, W0, W0,
                                                                 c1, c0, 0.0f, W1, HB);
            spmm8_combine_f16_kernel<<<grdRow, blk, 0, stream>>>(row_ptr, sedges, HB, W1, W0,
                                                                 th1[2], th2[2], th3[2], W2, HA);
            spmm8_combine_f16_kernel<<<grdRow, blk, 0, stream>>>(row_ptr, sedges, HA, W2, W1,
                                                                 th1[3], th2[3], th3[3], W0, nullptr);
            finalize_split_kernel<<<grd4, blk, 0, stream>>>(u4, it4, (const float4*)W1,
                                                            (const float4*)W2, (const float4*)W0,
                                                            (float4*)out);
        } else {
            // ---- exact fp32-gather path (legacy accumulate-into-out) ----
            concat_init_kernel<<<grd4, blk, 0, stream>>>(u4, it4, (float4*)W0, nullptr, (float4*)out);
            spmm_combine_kernel<<<grdRow, blk, 0, stream>>>(row_ptr, sedges, W0, W0, W0,
                                                            c1, c0, 0.0f, W1, out);
            spmm_combine_kernel<<<grdRow, blk, 0, stream>>>(row_ptr, sedges, W1, W1, W0,
                                                            th1[2], th2[2], th3[2], W2, out);
            spmm_combine_kernel<<<grdRow, blk, 0, stream>>>(row_ptr, sedges, W2, W2, W1,
                                                            th1[3], th2[3], th3[3], W0, out);
            finalize_kernel<<<grdE, blk, 0, stream>>>(user_emb, item_emb, out);
        }
    } else {
        // ---- fallback: atomic path ----
        long long spmm_threads = (long long)NE * 64;
        dim3 grdS((unsigned)((spmm_threads + 255) / 256));
        concat_init_kernel<<<grd4, blk, 0, stream>>>(u4, it4, (float4*)W0, nullptr, (float4*)out);
        hipMemsetAsync(W1, 0, nbuf * sizeof(float), stream);
        spmm_atomic_kernel<<<grdS, blk, 0, stream>>>(rows, cols, vals, W0, W1);
        combine3_kernel<<<grdE, blk, 0, stream>>>(W1, W0, W0, c1, c0, 0.0f, out);
        hipMemsetAsync(W2, 0, nbuf * sizeof(float), stream);
        spmm_atomic_kernel<<<grdS, blk, 0, stream>>>(rows, cols, vals, W1, W2);
        combine3_kernel<<<grdE, blk, 0, stream>>>(W2, W1, W0, th1[2], th2[2], th3[2], out);
        hipMemsetAsync(W0, 0, nbuf * sizeof(float), stream);
        spmm_atomic_kernel<<<grdS, blk, 0, stream>>>(rows, cols, vals, W2, W0);
        combine3_kernel<<<grdE, blk, 0, stream>>>(W0, W2, W1, th1[3], th2[3], th3[3], out);
        finalize_kernel<<<grdE, blk, 0, stream>>>(user_emb, item_emb, out);
    }
}

// Round 11
// 460.476 us; speedup vs baseline: 11.9009x; 1.0881x over previous
//
#include <hip/hip_runtime.h>
#include <hip/hip_fp16.h>
#include <cmath>
#include <cstdint>

#define NU 100000
#define NI 50000
#define NALL 150000
#define DIM 64
#define NE 4800000

#define BSH 7                 // bucket = row >> 7  (128 rows/bucket)
#define BROWS 128
#define NBUCK ((NALL + BROWS - 1) / BROWS)   // 1172
#define SBT 512               // sort-kernel block threads
#define EPT 8                 // edges per thread (512 * 8 = 4096 per block)
#define CHUNK (SBT * EPT)     // 4096 edges per binning block
#define COLMASK 0x3FFFF       // 18 bits, NALL < 2^18
#define BCAP 4608             // bucket capacity for staged sort (mean 4096 + 8 sigma)
#define SPT 9                 // staged regs per thread in bucket_sort (512*9=4608)

// ---------------- CSR build (round-10 proven path, unchanged) ----------------

__global__ __launch_bounds__(SBT) void bucket_hist_kernel(
        const int* __restrict__ rows, int* __restrict__ bcnt) {
    __shared__ int h[NBUCK];
    for (int i = threadIdx.x; i < NBUCK; i += SBT) h[i] = 0;
    __syncthreads();
    int base = blockIdx.x * CHUNK;
    #pragma unroll
    for (int i = 0; i < EPT; i++) {
        int e = base + threadIdx.x + i * SBT;
        if (e < NE) atomicAdd(&h[rows[e] >> BSH], 1);
    }
    __syncthreads();
    for (int i = threadIdx.x; i < NBUCK; i += SBT)
        if (h[i]) atomicAdd(&bcnt[i], h[i]);
}

__global__ void bucket_scan_kernel(const int* __restrict__ bcnt, int* __restrict__ bptr) {
    __shared__ int s[1024];
    int t = threadIdx.x;
    const int chunk = (NBUCK + 1023) / 1024;   // 2
    int lo = t * chunk, hi = lo + chunk;
    if (hi > NBUCK) hi = NBUCK;
    int sum = 0;
    for (int i = lo; i < hi; ++i) sum += bcnt[i];
    s[t] = sum;
    __syncthreads();
    for (int off = 1; off < 1024; off <<= 1) {
        int v = (t >= off) ? s[t - off] : 0;
        __syncthreads();
        s[t] += v;
        __syncthreads();
    }
    int run = s[t] - sum;
    for (int i = lo; i < hi; ++i) { bptr[i] = run; run += bcnt[i]; }
    if (t == 1023) bptr[NBUCK] = s[1023];
}

__global__ __launch_bounds__(SBT, 6) void binned_scatter_kernel(
        const int* __restrict__ rows, const int* __restrict__ cols,
        const float* __restrict__ vals, const int* __restrict__ bptr,
        int* __restrict__ bfill, int2* __restrict__ tmp) {
    __shared__ int2 eLDS[CHUNK];             // 32 KB
    __shared__ unsigned short bLDS[CHUNK];   // 8 KB bucket-id sidecar
    __shared__ int lcnt[NBUCK];              // ranks, then writeout delta
    __shared__ int lofs[NBUCK + 1];
    __shared__ int psum[SBT];
    int t = threadIdx.x;
    int base = blockIdx.x * CHUNK;
    int cnt = NE - base; if (cnt > CHUNK) cnt = CHUNK;
    for (int i = t; i < NBUCK; i += SBT) lcnt[i] = 0;
    __syncthreads();
    int2 ed[EPT]; int mcb[EPT]; int mrk[EPT];
    #pragma unroll
    for (int k = 0; k < EPT; k++) {
        int p = t + k * SBT;
        mcb[k] = -1;
        if (p < cnt) {
            int e = base + p;
            int r = rows[e];
            int cb = r >> BSH;
            mcb[k] = cb;
            mrk[k] = atomicAdd(&lcnt[cb], 1);
            ed[k] = make_int2(((r & (BROWS - 1)) << 18) | cols[e], __float_as_int(vals[e]));
        }
    }
    __syncthreads();
    const int cpt = (NBUCK + SBT - 1) / SBT;   // 3
    int lo = t * cpt, hi = lo + cpt;
    if (lo > NBUCK) lo = NBUCK;
    if (hi > NBUCK) hi = NBUCK;
    int s = 0;
    for (int i = lo; i < hi; ++i) s += lcnt[i];
    psum[t] = s;
    __syncthreads();
    for (int off = 1; off < SBT; off <<= 1) {
        int v = (t >= off) ? psum[t - off] : 0;
        __syncthreads();
        psum[t] += v;
        __syncthreads();
    }
    int run = psum[t] - s;
    for (int i = lo; i < hi; ++i) { lofs[i] = run; run += lcnt[i]; }
    if (t == SBT - 1) lofs[NBUCK] = cnt;
    __syncthreads();
    for (int i = t; i < NBUCK; i += SBT) {
        int c = lcnt[i];
        int g = c ? atomicAdd(&bfill[i], c) : 0;
        lcnt[i] = bptr[i] + g - lofs[i];
    }
    #pragma unroll
    for (int k = 0; k < EPT; k++)
        if (mcb[k] >= 0) {
            int pos = lofs[mcb[k]] + mrk[k];
            eLDS[pos] = ed[k];
            bLDS[pos] = (unsigned short)mcb[k];
        }
    __syncthreads();
    for (int p = t; p < cnt; p += SBT)
        tmp[lcnt[bLDS[p]] + p] = eLDS[p];
}

__global__ __launch_bounds__(SBT, 6) void bucket_sort_kernel(
        const int* __restrict__ bptr, const int2* __restrict__ tmp,
        int2* __restrict__ sedges, int* __restrict__ row_ptr) {
    __shared__ int2 eLDS[BCAP];           // 36.9 KB
    __shared__ int h[BROWS], sc[BROWS], f[BROWS];
    int b = blockIdx.x, t = threadIdx.x;
    int s0 = bptr[b], s1 = bptr[b + 1];
    int cnt = s1 - s0;
    if (t < BROWS) { h[t] = 0; f[t] = 0; }
    if (b == NBUCK - 1 && t == 0) row_ptr[NALL] = s1;
    __syncthreads();
    if (cnt <= BCAP) {
        int2 ed[SPT]; int mrl[SPT]; int mrk[SPT];
        #pragma unroll
        for (int k = 0; k < SPT; k++) {
            int p = t + k * SBT;
            mrl[k] = -1;
            if (p < cnt) {
                int2 E = tmp[s0 + p];
                int rl = E.x >> 18;
                mrl[k] = rl;
                mrk[k] = atomicAdd(&h[rl], 1);
                ed[k] = E;
            }
        }
        __syncthreads();
        if (t < BROWS) sc[t] = h[t];
        __syncthreads();
        for (int off = 1; off < BROWS; off <<= 1) {
            int v = 0;
            if (t < BROWS && t >= off) v = sc[t - off];
            __syncthreads();
            if (t < BROWS) sc[t] += v;
            __syncthreads();
        }
        if (t < BROWS) {
            int row = b * BROWS + t;
            if (row < NALL) row_ptr[row] = s0 + sc[t] - h[t];
        }
        __syncthreads();
        #pragma unroll
        for (int k = 0; k < SPT; k++)
            if (mrl[k] >= 0) eLDS[sc[mrl[k]] - h[mrl[k]] + mrk[k]] = ed[k];
        __syncthreads();
        for (int p = t; p < cnt; p += SBT) sedges[s0 + p] = eLDS[p];
    } else {
        for (int i = s0 + t; i < s1; i += SBT) atomicAdd(&h[tmp[i].x >> 18], 1);
        __syncthreads();
        if (t < BROWS) sc[t] = h[t];
        __syncthreads();
        for (int off = 1; off < BROWS; off <<= 1) {
            int v = 0;
            if (t < BROWS && t >= off) v = sc[t - off];
            __syncthreads();
            if (t < BROWS) sc[t] += v;
            __syncthreads();
        }
        if (t < BROWS) {
            int row = b * BROWS + t;
            if (row < NALL) row_ptr[row] = s0 + sc[t] - h[t];
        }
        __syncthreads();
        for (int i = s0 + t; i < s1; i += SBT) {
            int2 E = tmp[i];
            int rl = E.x >> 18;
            int r = atomicAdd(&f[rl], 1);
            sedges[s0 + sc[rl] - h[rl] + r] = E;
        }
    }
}

// ---------------- embedding passes ----------------

__global__ void concat_init_kernel(const float4* __restrict__ u4, const float4* __restrict__ it4,
                                   float4* __restrict__ w0, uint2* __restrict__ w0h,
                                   float4* __restrict__ out4) {
    int idx = blockIdx.x * blockDim.x + threadIdx.x;
    const int total4 = NALL * 16;
    if (idx >= total4) return;
    const int nu4 = NU * 16;
    float4 v = (idx < nu4) ? u4[idx] : it4[idx - nu4];
    if (w0) w0[idx] = v;
    if (w0h) {
        __half2 a = __floats2half2_rn(v.x, v.y), b = __floats2half2_rn(v.z, v.w);
        w0h[idx] = make_uint2(*(unsigned*)&a, *(unsigned*)&b);
    }
    if (out4) {
        int row = idx >> 4, q = idx & 15;
        out4[(size_t)row * 32 + q] = v;
    }
}

__device__ __forceinline__ void fma_h8(float* acc, uint4 p, float v) {
    __half2* h = (__half2*)&p;
    #pragma unroll
    for (int j = 0; j < 4; j++) {
        float2 f = __half22float2(h[j]);
        acc[2 * j]     += v * f.x;
        acc[2 * j + 1] += v * f.y;
    }
}

// load the float4 pair (dims [l8*8, l8*8+8)) of row `wid` from either a dense
// buffer or the concatenated inputs (embed == e0).
__device__ __forceinline__ void load_pair(const float4* __restrict__ buf, int embed,
                                          const float4* __restrict__ u4,
                                          const float4* __restrict__ it4,
                                          int wid, int l8, float4& a, float4& b) {
    const float4* q;
    if (embed) q = (wid < NU) ? (u4 + (size_t)wid * 16 + l8 * 2)
                              : (it4 + (size_t)(wid - NU) * 16 + l8 * 2);
    else       q = buf + (size_t)wid * 16 + l8 * 2;
    a = q[0]; b = q[1];
}

// Predicated full-width gather loop: every iteration issues 4 gathers (OOB slots
// clamp to the row's first edge in this group, value zeroed) -> all rows run at
// 4-deep MLP, no serial tail.
__device__ __forceinline__ void spmm_row_acc(const int* __restrict__ row_ptr,
                                             const int2* __restrict__ sedges,
                                             const uint4* __restrict__ xv,
                                             int wid, int g, int l8, float* acc) {
    int s = row_ptr[wid], e = row_ptr[wid + 1];
    for (int i = s + g; i < e; i += 32) {
        int i1 = i + 8, i2 = i + 16, i3 = i + 24;
        int2 E0 = sedges[i];
        int2 E1 = sedges[i1 < e ? i1 : i];
        int2 E2 = sedges[i2 < e ? i2 : i];
        int2 E3 = sedges[i3 < e ? i3 : i];
        uint4 p0 = xv[(size_t)(E0.x & COLMASK) * 8 + l8];
        uint4 p1 = xv[(size_t)(E1.x & COLMASK) * 8 + l8];
        uint4 p2 = xv[(size_t)(E2.x & COLMASK) * 8 + l8];
        uint4 p3 = xv[(size_t)(E3.x & COLMASK) * 8 + l8];
        fma_h8(acc, p0, __int_as_float(E0.y));
        fma_h8(acc, p1, i1 < e ? __int_as_float(E1.y) : 0.f);
        fma_h8(acc, p2, i2 < e ? __int_as_float(E2.y) : 0.f);
        fma_h8(acc, p3, i3 < e ? __int_as_float(E3.y) : 0.f);
    }
    #pragma unroll
    for (int off = 8; off < 64; off <<= 1) {
        #pragma unroll
        for (int j = 0; j < 8; j++) acc[j] += __shfl_xor(acc[j], off);
    }
}

// Passes 1..N-1: ek = t1*spmm(x) + t2*ekm1 - t3*ekm2; writes fp32 + fp16 mirror.
__global__ __launch_bounds__(256) void spmm8_combine_f16_kernel(
        const int* __restrict__ row_ptr, const int2* __restrict__ sedges,
        const __half* __restrict__ xh,
        const float* __restrict__ ekm1, int em1_embed,
        const float* __restrict__ ekm2, int em2_embed,
        const float4* __restrict__ u4, const float4* __restrict__ it4,
        float t1, float t2, float t3,
        float* __restrict__ ek_out, __half* __restrict__ ekh_out) {
    int wid = (blockIdx.x * blockDim.x + threadIdx.x) >> 6;
    if (wid >= NALL) return;
    int lane = threadIdx.x & 63;
    int g = lane >> 3, l8 = lane & 7;
    float acc[8];
    #pragma unroll
    for (int j = 0; j < 8; j++) acc[j] = 0.f;
    spmm_row_acc(row_ptr, sedges, (const uint4*)xh, wid, g, l8, acc);
    if (g == 0) {
        size_t o4 = (size_t)wid * 16 + l8 * 2;
        float4 ea, eb;
        ea.x = t1 * acc[0]; ea.y = t1 * acc[1]; ea.z = t1 * acc[2]; ea.w = t1 * acc[3];
        eb.x = t1 * acc[4]; eb.y = t1 * acc[5]; eb.z = t1 * acc[6]; eb.w = t1 * acc[7];
        if (t2 != 0.f) {
            float4 m1a, m1b;
            load_pair((const float4*)ekm1, em1_embed, u4, it4, wid, l8, m1a, m1b);
            ea.x += t2 * m1a.x; ea.y += t2 * m1a.y; ea.z += t2 * m1a.z; ea.w += t2 * m1a.w;
            eb.x += t2 * m1b.x; eb.y += t2 * m1b.y; eb.z += t2 * m1b.z; eb.w += t2 * m1b.w;
        }
        if (t3 != 0.f) {
            float4 m2a, m2b;
            load_pair((const float4*)ekm2, em2_embed, u4, it4, wid, l8, m2a, m2b);
            ea.x -= t3 * m2a.x; ea.y -= t3 * m2a.y; ea.z -= t3 * m2a.z; ea.w -= t3 * m2a.w;
            eb.x -= t3 * m2b.x; eb.y -= t3 * m2b.y; eb.z -= t3 * m2b.z; eb.w -= t3 * m2b.w;
        }
        ((float4*)ek_out)[o4] = ea;
        ((float4*)ek_out)[o4 + 1] = eb;
        if (ekh_out) {
            __half2 h0 = __floats2half2_rn(ea.x, ea.y);
            __half2 h1 = __floats2half2_rn(ea.z, ea.w);
            __half2 h2 = __floats2half2_rn(eb.x, eb.y);
            __half2 h3 = __floats2half2_rn(eb.z, eb.w);
            uint4 ph;
            ph.x = *(unsigned*)&h0; ph.y = *(unsigned*)&h1;
            ph.z = *(unsigned*)&h2; ph.w = *(unsigned*)&h3;
            ((uint4*)ekh_out)[(size_t)wid * 8 + l8] = ph;
        }
    }
}

// Final pass fused with finalize: e3 = t1*spmm(e2) + t2*e2 - t3*e1;
// bs = (e0+e1+e2+e3)/4; bp = tanh(0.1*e0 - bs); writes bs/bp directly to out.
__global__ __launch_bounds__(256) void spmm8_final_kernel(
        const int* __restrict__ row_ptr, const int2* __restrict__ sedges,
        const __half* __restrict__ xh,
        const float* __restrict__ e1buf, const float* __restrict__ e2buf,
        const float4* __restrict__ u4, const float4* __restrict__ it4,
        float t1, float t2, float t3,
        float4* __restrict__ out4) {
    int wid = (blockIdx.x * blockDim.x + threadIdx.x) >> 6;
    if (wid >= NALL) return;
    int lane = threadIdx.x & 63;
    int g = lane >> 3, l8 = lane & 7;
    float acc[8];
    #pragma unroll
    for (int j = 0; j < 8; j++) acc[j] = 0.f;
    spmm_row_acc(row_ptr, sedges, (const uint4*)xh, wid, g, l8, acc);
    if (g == 0) {
        float4 e0a, e0b, e1a, e1b, e2a, e2b;
        load_pair(nullptr, 1, u4, it4, wid, l8, e0a, e0b);
        load_pair((const float4*)e1buf, 0, u4, it4, wid, l8, e1a, e1b);
        load_pair((const float4*)e2buf, 0, u4, it4, wid, l8, e2a, e2b);
        float4 e3a, e3b;
        e3a.x = t1 * acc[0] + t2 * e2a.x - t3 * e1a.x;
        e3a.y = t1 * acc[1] + t2 * e2a.y - t3 * e1a.y;
        e3a.z = t1 * acc[2] + t2 * e2a.z - t3 * e1a.z;
        e3a.w = t1 * acc[3] + t2 * e2a.w - t3 * e1a.w;
        e3b.x = t1 * acc[4] + t2 * e2b.x - t3 * e1b.x;
        e3b.y = t1 * acc[5] + t2 * e2b.y - t3 * e1b.y;
        e3b.z = t1 * acc[6] + t2 * e2b.z - t3 * e1b.z;
        e3b.w = t1 * acc[7] + t2 * e2b.w - t3 * e1b.w;
        float4 bsa, bsb, bpa, bpb;
        bsa.x = 0.25f * (e0a.x + e1a.x + e2a.x + e3a.x);
        bsa.y = 0.25f * (e0a.y + e1a.y + e2a.y + e3a.y);
        bsa.z = 0.25f * (e0a.z + e1a.z + e2a.z + e3a.z);
        bsa.w = 0.25f * (e0a.w + e1a.w + e2a.w + e3a.w);
        bsb.x = 0.25f * (e0b.x + e1b.x + e2b.x + e3b.x);
        bsb.y = 0.25f * (e0b.y + e1b.y + e2b.y + e3b.y);
        bsb.z = 0.25f * (e0b.z + e1b.z + e2b.z + e3b.z);
        bsb.w = 0.25f * (e0b.w + e1b.w + e2b.w + e3b.w);
        bpa.x = tanhf(0.1f * e0a.x - bsa.x);
        bpa.y = tanhf(0.1f * e0a.y - bsa.y);
        bpa.z = tanhf(0.1f * e0a.z - bsa.z);
        bpa.w = tanhf(0.1f * e0a.w - bsa.w);
        bpb.x = tanhf(0.1f * e0b.x - bsb.x);
        bpb.y = tanhf(0.1f * e0b.y - bsb.y);
        bpb.z = tanhf(0.1f * e0b.z - bsb.z);
        bpb.w = tanhf(0.1f * e0b.w - bsb.w);
        size_t ob = (size_t)wid * 32 + l8 * 2;
        out4[ob] = bsa;
        out4[ob + 1] = bsb;
        out4[ob + 16] = bpa;
        out4[ob + 17] = bpb;
    }
}

// ---------------- fallback kernels (ws-constrained paths) ----------------

__global__ void spmm_combine_kernel(const int* __restrict__ row_ptr,
                                    const int2* __restrict__ sedges,
                                    const float* __restrict__ x,
                                    const float* __restrict__ ekm1,
                                    const float* __restrict__ ekm2,
                                    float t1, float t2, float t3,
                                    float* __restrict__ ek_out,
                                    float* __restrict__ out) {
    int wid = (blockIdx.x * blockDim.x + threadIdx.x) >> 6;
    if (wid >= NALL) return;
    int lane = threadIdx.x & 63;
    int s = row_ptr[wid], e = row_ptr[wid + 1];
    float acc = 0.f;
    int i = s;
    for (; i + 4 <= e; i += 4) {
        int2 ea = sedges[i], eb = sedges[i + 1], ec = sedges[i + 2], ed = sedges[i + 3];
        acc += __int_as_float(ea.y) * x[(size_t)(ea.x & COLMASK) * DIM + lane];
        acc += __int_as_float(eb.y) * x[(size_t)(eb.x & COLMASK) * DIM + lane];
        acc += __int_as_float(ec.y) * x[(size_t)(ec.x & COLMASK) * DIM + lane];
        acc += __int_as_float(ed.y) * x[(size_t)(ed.x & COLMASK) * DIM + lane];
    }
    for (; i < e; ++i) {
        int2 ed = sedges[i];
        acc += __int_as_float(ed.y) * x[(size_t)(ed.x & COLMASK) * DIM + lane];
    }
    size_t o = (size_t)wid * DIM + lane;
    float ek = t1 * acc + t2 * ekm1[o] - t3 * ekm2[o];
    ek_out[o] = ek;
    out[(size_t)wid * 128 + lane] += ek;
}

__global__ void finalize_kernel(const float* __restrict__ u, const float* __restrict__ it,
                                float* __restrict__ out) {
    int idx = blockIdx.x * blockDim.x + threadIdx.x;
    const int total = NALL * DIM;
    if (idx >= total) return;
    const int nue = NU * DIM;
    float v = (idx < nue) ? u[idx] : it[idx - nue];
    int row = idx >> 6, d = idx & 63;
    size_t o = (size_t)row * 128 + d;
    float bs = out[o] * 0.25f;
    float bp = tanhf(0.1f * v - bs);
    out[o] = bs;
    out[o + DIM] = bp;
}

__global__ void spmm_atomic_kernel(const int* __restrict__ rows, const int* __restrict__ cols,
                                   const float* __restrict__ vals, const float* __restrict__ x,
                                   float* __restrict__ y) {
    int gid = blockIdx.x * blockDim.x + threadIdx.x;
    int e = gid >> 6;
    if (e >= NE) return;
    int lane = threadIdx.x & 63;
    atomicAdd(&y[(size_t)rows[e] * DIM + lane], vals[e] * x[(size_t)cols[e] * DIM + lane]);
}

__global__ void combine3_kernel(float* __restrict__ t, const float* __restrict__ ekm1,
                                const float* __restrict__ ekm2, float t1, float t2, float t3,
                                float* __restrict__ out) {
    int idx = blockIdx.x * blockDim.x + threadIdx.x;
    const int total = NALL * DIM;
    if (idx >= total) return;
    float ek = t1 * t[idx] + t2 * ekm1[idx] - t3 * ekm2[idx];
    t[idx] = ek;
    int row = idx >> 6, d = idx & 63;
    out[(size_t)row * 128 + d] += ek;
}

// ---------------- launch ----------------

extern "C" void kernel_launch(void* const* d_in, const int* in_sizes, int n_in,
                              void* d_out, int out_size, void* d_ws, size_t ws_size,
                              hipStream_t stream) {
    const float* user_emb = (const float*)d_in[0];
    const float* item_emb = (const float*)d_in[1];
    const int*   rows     = (const int*)d_in[2];
    const int*   cols     = (const int*)d_in[3];
    const float* vals     = (const float*)d_in[4];
    float* out = (float*)d_out;

    const size_t nbuf = (size_t)NALL * DIM;            // 9.6M floats = 38.4 MB
    float* W0 = (float*)d_ws;
    float* W1 = W0 + nbuf;
    float* W2 = W1 + nbuf;
    int2*  tmp     = (int2*)W1;                        // alias: dead before propagation
    int2*  sedges  = (int2*)(W2 + nbuf);               // NE * 8 B
    int*   row_ptr = (int*)(sedges + NE);              // NALL+1
    int*   bcnt    = row_ptr + (NALL + 1);             // NBUCK
    int*   bptr    = bcnt + NBUCK;                     // NBUCK+1
    int*   bfill   = bptr + (NBUCK + 1);               // NBUCK
    char*  pHA     = (char*)(bfill + NBUCK);
    pHA = (char*)(((uintptr_t)pHA + 255) & ~(uintptr_t)255);   // 256B-align mirrors
    __half* HA     = (__half*)pHA;                     // fp16 mirror A (nbuf halves)
    __half* HB     = HA + nbuf;                        // fp16 mirror B
    size_t need_basic = (size_t)((char*)HA - (char*)d_ws);
    size_t need_full  = (size_t)((char*)(HB + nbuf) - (char*)d_ws);

    // Jacobi coefficients (A=B=1 here, computed generically)
    const double A = 1.0, B = 1.0, ab = A + B;
    float c0 = (float)((A - B) / 2.0);
    float c1 = (float)((A + B) / 2.0);
    float th1[4], th2[4], th3[4];
    for (int k = 2; k <= 3; k++) {
        th1[k] = (float)((2.0*k+ab)*(2.0*k+ab-1.0)/((k+ab)*2.0*k));
        th2[k] = (float)((2.0*k+ab-1.0)*(A*A-B*B)/((2.0*k+ab-2.0)*(k+ab)*2.0*k));
        th3[k] = (float)((k+A-1.0)*(k+B-1.0)*(2.0*k+ab)/(k*(ab+k)*(2.0*k+ab-2.0)));
    }

    const int total = NALL * DIM;
    const int total4 = NALL * 16;
    dim3 blk(256);
    dim3 sblk(SBT);
    dim3 grdE((total + 255) / 256);
    dim3 grd4((total4 + 255) / 256);                   // float4-vectorized elementwise
    dim3 grdBin((NE + CHUNK - 1) / CHUNK);             // 1172
    dim3 grdBuck(NBUCK);                               // 1172
    dim3 grdRow((NALL * 64 + 255) / 256);              // wave-per-row

    const float4* u4  = (const float4*)user_emb;
    const float4* it4 = (const float4*)item_emb;

    if (ws_size >= need_basic) {
        // ---- edge sort ----
        hipMemsetAsync(bcnt, 0, NBUCK * sizeof(int), stream);
        hipMemsetAsync(bfill, 0, NBUCK * sizeof(int), stream);
        bucket_hist_kernel<<<grdBin, sblk, 0, stream>>>(rows, bcnt);
        bucket_scan_kernel<<<1, 1024, 0, stream>>>(bcnt, bptr);
        binned_scatter_kernel<<<grdBin, sblk, 0, stream>>>(rows, cols, vals, bptr, bfill, tmp);
        bucket_sort_kernel<<<grdBuck, sblk, 0, stream>>>(bptr, tmp, sedges, row_ptr);

        if (ws_size >= need_full) {
            // ---- fp16-gather path; e0 read straight from inputs; fused final pass ----
            concat_init_kernel<<<grd4, blk, 0, stream>>>(u4, it4, nullptr, (uint2*)HA, nullptr);
            // e1 = c1*spmm(e0) + c0*e0
            spmm8_combine_f16_kernel<<<grdRow, blk, 0, stream>>>(row_ptr, sedges, HA,
                                                                 nullptr, 1, nullptr, 1,
                                                                 u4, it4, c1, c0, 0.0f, W1, HB);
            // e2 = th1*spmm(e1) + th2*e1 - th3*e0
            spmm8_combine_f16_kernel<<<grdRow, blk, 0, stream>>>(row_ptr, sedges, HB,
                                                                 W1, 0, nullptr, 1,
                                                                 u4, it4, th1[2], th2[2], th3[2],
                                                                 W2, HA);
            // e3 + band-stop + band-pass fused
            spmm8_final_kernel<<<grdRow, blk, 0, stream>>>(row_ptr, sedges, HA, W1, W2,
                                                           u4, it4, th1[3], th2[3], th3[3],
                                                           (float4*)out);
        } else {
            // ---- exact fp32-gather path (legacy accumulate-into-out) ----
            concat_init_kernel<<<grd4, blk, 0, stream>>>(u4, it4, (float4*)W0, nullptr, (float4*)out);
            spmm_combine_kernel<<<grdRow, blk, 0, stream>>>(row_ptr, sedges, W0, W0, W0,
                                                            c1, c0, 0.0f, W1, out);
            spmm_combine_kernel<<<grdRow, blk, 0, stream>>>(row_ptr, sedges, W1, W1, W0,
                                                            th1[2], th2[2], th3[2], W2, out);
            spmm_combine_kernel<<<grdRow, blk, 0, stream>>>(row_ptr, sedges, W2, W2, W1,
                                                            th1[3], th2[3], th3[3], W0, out);
            finalize_kernel<<<grdE, blk, 0, stream>>>(user_emb, item_emb, out);
        }
    } else {
        // ---- fallback: atomic path ----
        long long spmm_threads = (long long)NE * 64;
        dim3 grdS((unsigned)((spmm_threads + 255) / 256));
        concat_init_kernel<<<grd4, blk, 0, stream>>>(u4, it4, (float4*)W0, nullptr, (float4*)out);
        hipMemsetAsync(W1, 0, nbuf * sizeof(float), stream);
        spmm_atomic_kernel<<<grdS, blk, 0, stream>>>(rows, cols, vals, W0, W1);
        combine3_kernel<<<grdE, blk, 0, stream>>>(W1, W0, W0, c1, c0, 0.0f, out);
        hipMemsetAsync(W2, 0, nbuf * sizeof(float), stream);
        spmm_atomic_kernel<<<grdS, blk, 0, stream>>>(rows, cols, vals, W1, W2);
        combine3_kernel<<<grdE, blk, 0, stream>>>(W2, W1, W0, th1[2], th2[2], th3[2], out);
        hipMemsetAsync(W0, 0, nbuf * sizeof(float), stream);
        spmm_atomic_kernel<<<grdS, blk, 0, stream>>>(rows, cols, vals, W2, W0);
        combine3_kernel<<<grdE, blk, 0, stream>>>(W0, W2, W1, th1[3], th2[3], th3[3], out);
        finalize_kernel<<<grdE, blk, 0, stream>>>(user_emb, item_emb, out);
    }
}

// Round 12
// 443.028 us; speedup vs baseline: 12.3696x; 1.0394x over previous
//
#include <hip/hip_runtime.h>
#include <hip/hip_fp16.h>
#include <cmath>
#include <cstdint>

#define NU 100000
#define NI 50000
#define NALL 150000
#define DIM 64
#define NE 4800000

#define BSH 7                 // bucket = row >> 7  (128 rows/bucket)
#define BROWS 128
#define NBUCK ((NALL + BROWS - 1) / BROWS)   // 1172
#define SBT 512               // sort-kernel block threads
#define EPT 8                 // edges per thread (512 * 8 = 4096 per block)
#define CHUNK (SBT * EPT)     // 4096 edges per binning block
#define COLMASK 0x3FFFF       // 18 bits, NALL < 2^18
#define BCAP 4608             // bucket capacity for staged sort (mean 4096 + 8 sigma)
#define SPT 9                 // staged regs per thread in bucket_sort (512*9=4608)

// ---------------- CSR build (proven path, unchanged) ----------------

__global__ __launch_bounds__(SBT) void bucket_hist_kernel(
        const int* __restrict__ rows, int* __restrict__ bcnt) {
    __shared__ int h[NBUCK];
    for (int i = threadIdx.x; i < NBUCK; i += SBT) h[i] = 0;
    __syncthreads();
    int base = blockIdx.x * CHUNK;
    #pragma unroll
    for (int i = 0; i < EPT; i++) {
        int e = base + threadIdx.x + i * SBT;
        if (e < NE) atomicAdd(&h[rows[e] >> BSH], 1);
    }
    __syncthreads();
    for (int i = threadIdx.x; i < NBUCK; i += SBT)
        if (h[i]) atomicAdd(&bcnt[i], h[i]);
}

__global__ void bucket_scan_kernel(const int* __restrict__ bcnt, int* __restrict__ bptr) {
    __shared__ int s[1024];
    int t = threadIdx.x;
    const int chunk = (NBUCK + 1023) / 1024;   // 2
    int lo = t * chunk, hi = lo + chunk;
    if (hi > NBUCK) hi = NBUCK;
    int sum = 0;
    for (int i = lo; i < hi; ++i) sum += bcnt[i];
    s[t] = sum;
    __syncthreads();
    for (int off = 1; off < 1024; off <<= 1) {
        int v = (t >= off) ? s[t - off] : 0;
        __syncthreads();
        s[t] += v;
        __syncthreads();
    }
    int run = s[t] - sum;
    for (int i = lo; i < hi; ++i) { bptr[i] = run; run += bcnt[i]; }
    if (t == 1023) bptr[NBUCK] = s[1023];
}

__global__ __launch_bounds__(SBT, 6) void binned_scatter_kernel(
        const int* __restrict__ rows, const int* __restrict__ cols,
        const float* __restrict__ vals, const int* __restrict__ bptr,
        int* __restrict__ bfill, int2* __restrict__ tmp) {
    __shared__ int2 eLDS[CHUNK];             // 32 KB
    __shared__ unsigned short bLDS[CHUNK];   // 8 KB bucket-id sidecar
    __shared__ int lcnt[NBUCK];              // ranks, then writeout delta
    __shared__ int lofs[NBUCK + 1];
    __shared__ int psum[SBT];
    int t = threadIdx.x;
    int base = blockIdx.x * CHUNK;
    int cnt = NE - base; if (cnt > CHUNK) cnt = CHUNK;
    for (int i = t; i < NBUCK; i += SBT) lcnt[i] = 0;
    __syncthreads();
    int2 ed[EPT]; int mcb[EPT]; int mrk[EPT];
    #pragma unroll
    for (int k = 0; k < EPT; k++) {
        int p = t + k * SBT;
        mcb[k] = -1;
        if (p < cnt) {
            int e = base + p;
            int r = rows[e];
            int cb = r >> BSH;
            mcb[k] = cb;
            mrk[k] = atomicAdd(&lcnt[cb], 1);
            ed[k] = make_int2(((r & (BROWS - 1)) << 18) | cols[e], __float_as_int(vals[e]));
        }
    }
    __syncthreads();
    const int cpt = (NBUCK + SBT - 1) / SBT;   // 3
    int lo = t * cpt, hi = lo + cpt;
    if (lo > NBUCK) lo = NBUCK;
    if (hi > NBUCK) hi = NBUCK;
    int s = 0;
    for (int i = lo; i < hi; ++i) s += lcnt[i];
    psum[t] = s;
    __syncthreads();
    for (int off = 1; off < SBT; off <<= 1) {
        int v = (t >= off) ? psum[t - off] : 0;
        __syncthreads();
        psum[t] += v;
        __syncthreads();
    }
    int run = psum[t] - s;
    for (int i = lo; i < hi; ++i) { lofs[i] = run; run += lcnt[i]; }
    if (t == SBT - 1) lofs[NBUCK] = cnt;
    __syncthreads();
    for (int i = t; i < NBUCK; i += SBT) {
        int c = lcnt[i];
        int g = c ? atomicAdd(&bfill[i], c) : 0;
        lcnt[i] = bptr[i] + g - lofs[i];
    }
    #pragma unroll
    for (int k = 0; k < EPT; k++)
        if (mcb[k] >= 0) {
            int pos = lofs[mcb[k]] + mrk[k];
            eLDS[pos] = ed[k];
            bLDS[pos] = (unsigned short)mcb[k];
        }
    __syncthreads();
    for (int p = t; p < cnt; p += SBT)
        tmp[lcnt[bLDS[p]] + p] = eLDS[p];
}

__global__ __launch_bounds__(SBT, 6) void bucket_sort_kernel(
        const int* __restrict__ bptr, const int2* __restrict__ tmp,
        int2* __restrict__ sedges, int* __restrict__ row_ptr) {
    __shared__ int2 eLDS[BCAP];           // 36.9 KB
    __shared__ int h[BROWS], sc[BROWS], f[BROWS];
    int b = blockIdx.x, t = threadIdx.x;
    int s0 = bptr[b], s1 = bptr[b + 1];
    int cnt = s1 - s0;
    if (t < BROWS) { h[t] = 0; f[t] = 0; }
    if (b == NBUCK - 1 && t == 0) row_ptr[NALL] = s1;
    __syncthreads();
    if (cnt <= BCAP) {
        int2 ed[SPT]; int mrl[SPT]; int mrk[SPT];
        #pragma unroll
        for (int k = 0; k < SPT; k++) {
            int p = t + k * SBT;
            mrl[k] = -1;
            if (p < cnt) {
                int2 E = tmp[s0 + p];
                int rl = E.x >> 18;
                mrl[k] = rl;
                mrk[k] = atomicAdd(&h[rl], 1);
                ed[k] = E;
            }
        }
        __syncthreads();
        if (t < BROWS) sc[t] = h[t];
        __syncthreads();
        for (int off = 1; off < BROWS; off <<= 1) {
            int v = 0;
            if (t < BROWS && t >= off) v = sc[t - off];
            __syncthreads();
            if (t < BROWS) sc[t] += v;
            __syncthreads();
        }
        if (t < BROWS) {
            int row = b * BROWS + t;
            if (row < NALL) row_ptr[row] = s0 + sc[t] - h[t];
        }
        __syncthreads();
        #pragma unroll
        for (int k = 0; k < SPT; k++)
            if (mrl[k] >= 0) eLDS[sc[mrl[k]] - h[mrl[k]] + mrk[k]] = ed[k];
        __syncthreads();
        for (int p = t; p < cnt; p += SBT) sedges[s0 + p] = eLDS[p];
    } else {
        for (int i = s0 + t; i < s1; i += SBT) atomicAdd(&h[tmp[i].x >> 18], 1);
        __syncthreads();
        if (t < BROWS) sc[t] = h[t];
        __syncthreads();
        for (int off = 1; off < BROWS; off <<= 1) {
            int v = 0;
            if (t < BROWS && t >= off) v = sc[t - off];
            __syncthreads();
            if (t < BROWS) sc[t] += v;
            __syncthreads();
        }
        if (t < BROWS) {
            int row = b * BROWS + t;
            if (row < NALL) row_ptr[row] = s0 + sc[t] - h[t];
        }
        __syncthreads();
        for (int i = s0 + t; i < s1; i += SBT) {
            int2 E = tmp[i];
            int rl = E.x >> 18;
            int r = atomicAdd(&f[rl], 1);
            sedges[s0 + sc[rl] - h[rl] + r] = E;
        }
    }
}

// ---------------- embedding passes ----------------

__global__ void concat_init_kernel(const float4* __restrict__ u4, const float4* __restrict__ it4,
                                   float4* __restrict__ w0, uint2* __restrict__ w0h,
                                   float4* __restrict__ out4) {
    int idx = blockIdx.x * blockDim.x + threadIdx.x;
    const int total4 = NALL * 16;
    if (idx >= total4) return;
    const int nu4 = NU * 16;
    float4 v = (idx < nu4) ? u4[idx] : it4[idx - nu4];
    if (w0) w0[idx] = v;
    if (w0h) {
        __half2 a = __floats2half2_rn(v.x, v.y), b = __floats2half2_rn(v.z, v.w);
        w0h[idx] = make_uint2(*(unsigned*)&a, *(unsigned*)&b);
    }
    if (out4) {
        int row = idx >> 4, q = idx & 15;
        out4[(size_t)row * 32 + q] = v;
    }
}

__device__ __forceinline__ void fma_h8(float* acc, uint4 p, float v) {
    __half2* h = (__half2*)&p;
    #pragma unroll
    for (int j = 0; j < 4; j++) {
        float2 f = __half22float2(h[j]);
        acc[2 * j]     += v * f.x;
        acc[2 * j + 1] += v * f.y;
    }
}

// float4 pair (dims [l8*8, l8*8+8)) of row `wid` from the concatenated fp32 inputs.
__device__ __forceinline__ void load_pair_e0(const float4* __restrict__ u4,
                                             const float4* __restrict__ it4,
                                             int wid, int l8, float4& a, float4& b) {
    const float4* q = (wid < NU) ? (u4 + (size_t)wid * 16 + l8 * 2)
                                 : (it4 + (size_t)(wid - NU) * 16 + l8 * 2);
    a = q[0]; b = q[1];
}

// same pair from an fp16 mirror (one uint4 = 8 halves).
__device__ __forceinline__ void load_pair_h(const __half* __restrict__ h,
                                            int wid, int l8, float4& a, float4& b) {
    uint4 p = ((const uint4*)h)[(size_t)wid * 8 + l8];
    __half2* hp = (__half2*)&p;
    float2 f0 = __half22float2(hp[0]);
    float2 f1 = __half22float2(hp[1]);
    float2 f2 = __half22float2(hp[2]);
    float2 f3 = __half22float2(hp[3]);
    a = make_float4(f0.x, f0.y, f1.x, f1.y);
    b = make_float4(f2.x, f2.y, f3.x, f3.y);
}

__device__ __forceinline__ uint4 pack_h8(float4 a, float4 b) {
    __half2 h0 = __floats2half2_rn(a.x, a.y);
    __half2 h1 = __floats2half2_rn(a.z, a.w);
    __half2 h2 = __floats2half2_rn(b.x, b.y);
    __half2 h3 = __floats2half2_rn(b.z, b.w);
    uint4 ph;
    ph.x = *(unsigned*)&h0; ph.y = *(unsigned*)&h1;
    ph.z = *(unsigned*)&h2; ph.w = *(unsigned*)&h3;
    return ph;
}

// Predicated full-width gather loop: 4 gathers in flight every iteration
// (OOB slots clamp to the first edge, value zeroed) -> no serial tail.
__device__ __forceinline__ void spmm_row_acc(const int* __restrict__ row_ptr,
                                             const int2* __restrict__ sedges,
                                             const uint4* __restrict__ xv,
                                             int wid, int g, int l8, float* acc) {
    int s = row_ptr[wid], e = row_ptr[wid + 1];
    for (int i = s + g; i < e; i += 32) {
        int i1 = i + 8, i2 = i + 16, i3 = i + 24;
        int2 E0 = sedges[i];
        int2 E1 = sedges[i1 < e ? i1 : i];
        int2 E2 = sedges[i2 < e ? i2 : i];
        int2 E3 = sedges[i3 < e ? i3 : i];
        uint4 p0 = xv[(size_t)(E0.x & COLMASK) * 8 + l8];
        uint4 p1 = xv[(size_t)(E1.x & COLMASK) * 8 + l8];
        uint4 p2 = xv[(size_t)(E2.x & COLMASK) * 8 + l8];
        uint4 p3 = xv[(size_t)(E3.x & COLMASK) * 8 + l8];
        fma_h8(acc, p0, __int_as_float(E0.y));
        fma_h8(acc, p1, i1 < e ? __int_as_float(E1.y) : 0.f);
        fma_h8(acc, p2, i2 < e ? __int_as_float(E2.y) : 0.f);
        fma_h8(acc, p3, i3 < e ? __int_as_float(E3.y) : 0.f);
    }
    #pragma unroll
    for (int off = 8; off < 64; off <<= 1) {
        #pragma unroll
        for (int j = 0; j < 8; j++) acc[j] += __shfl_xor(acc[j], off);
    }
}

// Passes 1..N-1: ek = t1*spmm(x) + t2*ekm1 - t3*ekm2; result lives ONLY as fp16 mirror.
// ekm terms read from fp16 mirrors, or fp32 inputs when the operand is e0 (embed flag).
__global__ __launch_bounds__(256) void spmm8_combine_f16_kernel(
        const int* __restrict__ row_ptr, const int2* __restrict__ sedges,
        const __half* __restrict__ xh,
        const __half* __restrict__ em1h, int em1_embed,
        const __half* __restrict__ em2h, int em2_embed,
        const float4* __restrict__ u4, const float4* __restrict__ it4,
        float t1, float t2, float t3,
        __half* __restrict__ ekh_out) {
    int wid = (blockIdx.x * blockDim.x + threadIdx.x) >> 6;
    if (wid >= NALL) return;
    int lane = threadIdx.x & 63;
    int g = lane >> 3, l8 = lane & 7;
    float acc[8];
    #pragma unroll
    for (int j = 0; j < 8; j++) acc[j] = 0.f;
    spmm_row_acc(row_ptr, sedges, (const uint4*)xh, wid, g, l8, acc);
    if (g == 0) {
        float4 ea, eb;
        ea.x = t1 * acc[0]; ea.y = t1 * acc[1]; ea.z = t1 * acc[2]; ea.w = t1 * acc[3];
        eb.x = t1 * acc[4]; eb.y = t1 * acc[5]; eb.z = t1 * acc[6]; eb.w = t1 * acc[7];
        if (t2 != 0.f) {
            float4 m1a, m1b;
            if (em1_embed) load_pair_e0(u4, it4, wid, l8, m1a, m1b);
            else           load_pair_h(em1h, wid, l8, m1a, m1b);
            ea.x += t2 * m1a.x; ea.y += t2 * m1a.y; ea.z += t2 * m1a.z; ea.w += t2 * m1a.w;
            eb.x += t2 * m1b.x; eb.y += t2 * m1b.y; eb.z += t2 * m1b.z; eb.w += t2 * m1b.w;
        }
        if (t3 != 0.f) {
            float4 m2a, m2b;
            if (em2_embed) load_pair_e0(u4, it4, wid, l8, m2a, m2b);
            else           load_pair_h(em2h, wid, l8, m2a, m2b);
            ea.x -= t3 * m2a.x; ea.y -= t3 * m2a.y; ea.z -= t3 * m2a.z; ea.w -= t3 * m2a.w;
            eb.x -= t3 * m2b.x; eb.y -= t3 * m2b.y; eb.z -= t3 * m2b.z; eb.w -= t3 * m2b.w;
        }
        ((uint4*)ekh_out)[(size_t)wid * 8 + l8] = pack_h8(ea, eb);
    }
}

// Final pass fused with finalize: e3 = t1*spmm(e2) + t2*e2 - t3*e1;
// bs = (e0+e1+e2+e3)/4; bp = tanh(0.1*e0 - bs). e0 from fp32 inputs; e1,e2 fp16.
__global__ __launch_bounds__(256) void spmm8_final_kernel(
        const int* __restrict__ row_ptr, const int2* __restrict__ sedges,
        const __half* __restrict__ xh,
        const __half* __restrict__ e1h, const __half* __restrict__ e2h,
        const float4* __restrict__ u4, const float4* __restrict__ it4,
        float t1, float t2, float t3,
        float4* __restrict__ out4) {
    int wid = (blockIdx.x * blockDim.x + threadIdx.x) >> 6;
    if (wid >= NALL) return;
    int lane = threadIdx.x & 63;
    int g = lane >> 3, l8 = lane & 7;
    float acc[8];
    #pragma unroll
    for (int j = 0; j < 8; j++) acc[j] = 0.f;
    spmm_row_acc(row_ptr, sedges, (const uint4*)xh, wid, g, l8, acc);
    if (g == 0) {
        float4 e0a, e0b, e1a, e1b, e2a, e2b;
        load_pair_e0(u4, it4, wid, l8, e0a, e0b);
        load_pair_h(e1h, wid, l8, e1a, e1b);
        load_pair_h(e2h, wid, l8, e2a, e2b);
        float4 e3a, e3b;
        e3a.x = t1 * acc[0] + t2 * e2a.x - t3 * e1a.x;
        e3a.y = t1 * acc[1] + t2 * e2a.y - t3 * e1a.y;
        e3a.z = t1 * acc[2] + t2 * e2a.z - t3 * e1a.z;
        e3a.w = t1 * acc[3] + t2 * e2a.w - t3 * e1a.w;
        e3b.x = t1 * acc[4] + t2 * e2b.x - t3 * e1b.x;
        e3b.y = t1 * acc[5] + t2 * e2b.y - t3 * e1b.y;
        e3b.z = t1 * acc[6] + t2 * e2b.z - t3 * e1b.z;
        e3b.w = t1 * acc[7] + t2 * e2b.w - t3 * e1b.w;
        float4 bsa, bsb, bpa, bpb;
        bsa.x = 0.25f * (e0a.x + e1a.x + e2a.x + e3a.x);
        bsa.y = 0.25f * (e0a.y + e1a.y + e2a.y + e3a.y);
        bsa.z = 0.25f * (e0a.z + e1a.z + e2a.z + e3a.z);
        bsa.w = 0.25f * (e0a.w + e1a.w + e2a.w + e3a.w);
        bsb.x = 0.25f * (e0b.x + e1b.x + e2b.x + e3b.x);
        bsb.y = 0.25f * (e0b.y + e1b.y + e2b.y + e3b.y);
        bsb.z = 0.25f * (e0b.z + e1b.z + e2b.z + e3b.z);
        bsb.w = 0.25f * (e0b.w + e1b.w + e2b.w + e3b.w);
        bpa.x = tanhf(0.1f * e0a.x - bsa.x);
        bpa.y = tanhf(0.1f * e0a.y - bsa.y);
        bpa.z = tanhf(0.1f * e0a.z - bsa.z);
        bpa.w = tanhf(0.1f * e0a.w - bsa.w);
        bpb.x = tanhf(0.1f * e0b.x - bsb.x);
        bpb.y = tanhf(0.1f * e0b.y - bsb.y);
        bpb.z = tanhf(0.1f * e0b.z - bsb.z);
        bpb.w = tanhf(0.1f * e0b.w - bsb.w);
        size_t ob = (size_t)wid * 32 + l8 * 2;
        out4[ob] = bsa;
        out4[ob + 1] = bsb;
        out4[ob + 16] = bpa;
        out4[ob + 17] = bpb;
    }
}

// ---------------- fallback kernels (ws-constrained paths) ----------------

__global__ void spmm_combine_kernel(const int* __restrict__ row_ptr,
                                    const int2* __restrict__ sedges,
                                    const float* __restrict__ x,
                                    const float* __restrict__ ekm1,
                                    const float* __restrict__ ekm2,
                                    float t1, float t2, float t3,
                                    float* __restrict__ ek_out,
                                    float* __restrict__ out) {
    int wid = (blockIdx.x * blockDim.x + threadIdx.x) >> 6;
    if (wid >= NALL) return;
    int lane = threadIdx.x & 63;
    int s = row_ptr[wid], e = row_ptr[wid + 1];
    float acc = 0.f;
    int i = s;
    for (; i + 4 <= e; i += 4) {
        int2 ea = sedges[i], eb = sedges[i + 1], ec = sedges[i + 2], ed = sedges[i + 3];
        acc += __int_as_float(ea.y) * x[(size_t)(ea.x & COLMASK) * DIM + lane];
        acc += __int_as_float(eb.y) * x[(size_t)(eb.x & COLMASK) * DIM + lane];
        acc += __int_as_float(ec.y) * x[(size_t)(ec.x & COLMASK) * DIM + lane];
        acc += __int_as_float(ed.y) * x[(size_t)(ed.x & COLMASK) * DIM + lane];
    }
    for (; i < e; ++i) {
        int2 ed = sedges[i];
        acc += __int_as_float(ed.y) * x[(size_t)(ed.x & COLMASK) * DIM + lane];
    }
    size_t o = (size_t)wid * DIM + lane;
    float ek = t1 * acc + t2 * ekm1[o] - t3 * ekm2[o];
    ek_out[o] = ek;
    out[(size_t)wid * 128 + lane] += ek;
}

__global__ void finalize_kernel(const float* __restrict__ u, const float* __restrict__ it,
                                float* __restrict__ out) {
    int idx = blockIdx.x * blockDim.x + threadIdx.x;
    const int total = NALL * DIM;
    if (idx >= total) return;
    const int nue = NU * DIM;
    float v = (idx < nue) ? u[idx] : it[idx - nue];
    int row = idx >> 6, d = idx & 63;
    size_t o = (size_t)row * 128 + d;
    float bs = out[o] * 0.25f;
    float bp = tanhf(0.1f * v - bs);
    out[o] = bs;
    out[o + DIM] = bp;
}

__global__ void spmm_atomic_kernel(const int* __restrict__ rows, const int* __restrict__ cols,
                                   const float* __restrict__ vals, const float* __restrict__ x,
                                   float* __restrict__ y) {
    int gid = blockIdx.x * blockDim.x + threadIdx.x;
    int e = gid >> 6;
    if (e >= NE) return;
    int lane = threadIdx.x & 63;
    atomicAdd(&y[(size_t)rows[e] * DIM + lane], vals[e] * x[(size_t)cols[e] * DIM + lane]);
}

__global__ void combine3_kernel(float* __restrict__ t, const float* __restrict__ ekm1,
                                const float* __restrict__ ekm2, float t1, float t2, float t3,
                                float* __restrict__ out) {
    int idx = blockIdx.x * blockDim.x + threadIdx.x;
    const int total = NALL * DIM;
    if (idx >= total) return;
    float ek = t1 * t[idx] + t2 * ekm1[idx] - t3 * ekm2[idx];
    t[idx] = ek;
    int row = idx >> 6, d = idx & 63;
    out[(size_t)row * 128 + d] += ek;
}

// ---------------- launch ----------------

extern "C" void kernel_launch(void* const* d_in, const int* in_sizes, int n_in,
                              void* d_out, int out_size, void* d_ws, size_t ws_size,
                              hipStream_t stream) {
    const float* user_emb = (const float*)d_in[0];
    const float* item_emb = (const float*)d_in[1];
    const int*   rows     = (const int*)d_in[2];
    const int*   cols     = (const int*)d_in[3];
    const float* vals     = (const float*)d_in[4];
    float* out = (float*)d_out;

    const size_t nbuf = (size_t)NALL * DIM;            // 9.6M elements
    float* W0 = (float*)d_ws;
    float* W1 = W0 + nbuf;
    float* W2 = W1 + nbuf;
    int2*  tmp     = (int2*)W1;                        // alias: dead before propagation
    int2*  sedges  = (int2*)(W2 + nbuf);               // NE * 8 B
    int*   row_ptr = (int*)(sedges + NE);              // NALL+1
    int*   bcnt    = row_ptr + (NALL + 1);             // NBUCK
    int*   bptr    = bcnt + NBUCK;                     // NBUCK+1
    int*   bfill   = bptr + (NBUCK + 1);               // NBUCK
    char*  pHA     = (char*)(bfill + NBUCK);
    pHA = (char*)(((uintptr_t)pHA + 255) & ~(uintptr_t)255);   // 256B-align mirrors
    __half* HA     = (__half*)pHA;                     // fp16 e0 mirror
    __half* HB     = HA + nbuf;                        // fp16 e1 mirror
    __half* HC     = HB + nbuf;                        // fp16 e2 mirror
    size_t need_basic = (size_t)((char*)HA - (char*)d_ws);
    size_t need_full  = (size_t)((char*)(HC + nbuf) - (char*)d_ws);

    // Jacobi coefficients (A=B=1 here, computed generically)
    const double A = 1.0, B = 1.0, ab = A + B;
    float c0 = (float)((A - B) / 2.0);
    float c1 = (float)((A + B) / 2.0);
    float th1[4], th2[4], th3[4];
    for (int k = 2; k <= 3; k++) {
        th1[k] = (float)((2.0*k+ab)*(2.0*k+ab-1.0)/((k+ab)*2.0*k));
        th2[k] = (float)((2.0*k+ab-1.0)*(A*A-B*B)/((2.0*k+ab-2.0)*(k+ab)*2.0*k));
        th3[k] = (float)((k+A-1.0)*(k+B-1.0)*(2.0*k+ab)/(k*(ab+k)*(2.0*k+ab-2.0)));
    }

    const int total = NALL * DIM;
    const int total4 = NALL * 16;
    dim3 blk(256);
    dim3 sblk(SBT);
    dim3 grdE((total + 255) / 256);
    dim3 grd4((total4 + 255) / 256);
    dim3 grdBin((NE + CHUNK - 1) / CHUNK);             // 1172
    dim3 grdBuck(NBUCK);                               // 1172
    dim3 grdRow((NALL * 64 + 255) / 256);              // wave-per-row

    const float4* u4  = (const float4*)user_emb;
    const float4* it4 = (const float4*)item_emb;

    if (ws_size >= need_basic) {
        // ---- edge sort ----
        hipMemsetAsync(bcnt, 0, NBUCK * sizeof(int), stream);
        hipMemsetAsync(bfill, 0, NBUCK * sizeof(int), stream);
        bucket_hist_kernel<<<grdBin, sblk, 0, stream>>>(rows, bcnt);
        bucket_scan_kernel<<<1, 1024, 0, stream>>>(bcnt, bptr);
        binned_scatter_kernel<<<grdBin, sblk, 0, stream>>>(rows, cols, vals, bptr, bfill, tmp);
        bucket_sort_kernel<<<grdBuck, sblk, 0, stream>>>(bptr, tmp, sedges, row_ptr);

        if (ws_size >= need_full) {
            // ---- fp16-mirror-only pipeline ----
            concat_init_kernel<<<grd4, blk, 0, stream>>>(u4, it4, nullptr, (uint2*)HA, nullptr);
            // e1 = c1*spmm(e0) + c0*e0            -> HB
            spmm8_combine_f16_kernel<<<grdRow, blk, 0, stream>>>(row_ptr, sedges, HA,
                                                                 nullptr, 1, nullptr, 1,
                                                                 u4, it4, c1, c0, 0.0f, HB);
            // e2 = th1*spmm(e1) + th2*e1 - th3*e0 -> HC
            spmm8_combine_f16_kernel<<<grdRow, blk, 0, stream>>>(row_ptr, sedges, HB,
                                                                 HB, 0, nullptr, 1,
                                                                 u4, it4, th1[2], th2[2], th3[2],
                                                                 HC);
            // e3 + band-stop + band-pass fused    -> out
            spmm8_final_kernel<<<grdRow, blk, 0, stream>>>(row_ptr, sedges, HC, HB, HC,
                                                           u4, it4, th1[3], th2[3], th3[3],
                                                           (float4*)out);
        } else {
            // ---- exact fp32-gather path (legacy accumulate-into-out) ----
            concat_init_kernel<<<grd4, blk, 0, stream>>>(u4, it4, (float4*)W0, nullptr, (float4*)out);
            spmm_combine_kernel<<<grdRow, blk, 0, stream>>>(row_ptr, sedges, W0, W0, W0,
                                                            c1, c0, 0.0f, W1, out);
            spmm_combine_kernel<<<grdRow, blk, 0, stream>>>(row_ptr, sedges, W1, W1, W0,
                                                            th1[2], th2[2], th3[2], W2, out);
            spmm_combine_kernel<<<grdRow, blk, 0, stream>>>(row_ptr, sedges, W2, W2, W1,
                                                            th1[3], th2[3], th3[3], W0, out);
            finalize_kernel<<<grdE, blk, 0, stream>>>(user_emb, item_emb, out);
        }
    } else {
        // ---- fallback: atomic path ----
        long long spmm_threads = (long long)NE * 64;
        dim3 grdS((unsigned)((spmm_threads + 255) / 256));
        concat_init_kernel<<<grd4, blk, 0, stream>>>(u4, it4, (float4*)W0, nullptr, (float4*)out);
        hipMemsetAsync(W1, 0, nbuf * sizeof(float), stream);
        spmm_atomic_kernel<<<grdS, blk, 0, stream>>>(rows, cols, vals, W0, W1);
        combine3_kernel<<<grdE, blk, 0, stream>>>(W1, W0, W0, c1, c0, 0.0f, out);
        hipMemsetAsync(W2, 0, nbuf * sizeof(float), stream);
        spmm_atomic_kernel<<<grdS, blk, 0, stream>>>(rows, cols, vals, W1, W2);
        combine3_kernel<<<grdE, blk, 0, stream>>>(W2, W1, W0, th1[2], th2[2], th3[2], out);
        hipMemsetAsync(W0, 0, nbuf * sizeof(float), stream);
        spmm_atomic_kernel<<<grdS, blk, 0, stream>>>(rows, cols, vals, W2, W0);
        combine3_kernel<<<grdE, blk, 0, stream>>>(W0, W2, W1, th1[3], th2[3], th3[3], out);
        finalize_kernel<<<grdE, blk, 0, stream>>>(user_emb, item_emb, out);
    }
}